// Round 3
// baseline (1356.962 us; speedup 1.0000x reference)
//
#include <hip/hip_runtime.h>
#include <hip/hip_bf16.h>

#define NN 50000
#define NE 500000
#define D 64
#define IND 11
#define EDD 4
#define NOD 5
#define NL 4
#define K1 132   // 2D + ED
#define KU 128   // 2D
#define EPSB 1e-5f

#define LDA1 168  // K-stride (bf16) for msg1 tiles: 160 used + 8 pad
#define LDA2 72   // K=64 + 8
#define LDA3 136  // K=128 + 8

#define NBLK1 196  // ceil(50000/256) scan chunks

typedef __hip_bfloat16 bf16;
typedef __attribute__((ext_vector_type(8))) __bf16 bf16x8;
typedef __attribute__((ext_vector_type(4))) float f32x4;

__device__ __forceinline__ ushort f2u(float f) {
    __hip_bfloat16 h = __float2bfloat16(f);
    return __builtin_bit_cast(ushort, h);
}
__device__ __forceinline__ float u2f(ushort u) {
    uint v = (uint)u << 16;
    return __builtin_bit_cast(float, v);
}

// ---------------------------------------------------------------------------
// Edge sort by dst: histogram -> scan -> scatter (reused by all 4 layers)
// ---------------------------------------------------------------------------
__global__ __launch_bounds__(256) void k_hist(const int* __restrict__ dst, int* __restrict__ cnt)
{
    const int e = blockIdx.x * 256 + threadIdx.x;
    if (e < NE) atomicAdd(&cnt[dst[e]], 1);
}

__global__ __launch_bounds__(256) void k_scan1(const int* __restrict__ cnt,
                                               int* __restrict__ rowstart, int* __restrict__ bsum)
{
    __shared__ int s[256];
    const int tid = threadIdx.x;
    const int i = blockIdx.x * 256 + tid;
    const int v = (i < NN) ? cnt[i] : 0;
    s[tid] = v;
    __syncthreads();
    for (int off = 1; off < 256; off <<= 1) {
        const int t = (tid >= off) ? s[tid - off] : 0;
        __syncthreads();
        s[tid] += t;
        __syncthreads();
    }
    if (i < NN) rowstart[i] = s[tid] - v;       // exclusive within chunk
    if (tid == 255) bsum[blockIdx.x] = s[255];  // chunk total
}

__global__ __launch_bounds__(256) void k_scan2(int* __restrict__ bsum)
{
    __shared__ int s[256];
    const int tid = threadIdx.x;
    const int v = (tid < NBLK1) ? bsum[tid] : 0;
    s[tid] = v;
    __syncthreads();
    for (int off = 1; off < 256; off <<= 1) {
        const int t = (tid >= off) ? s[tid - off] : 0;
        __syncthreads();
        s[tid] += t;
        __syncthreads();
    }
    if (tid < NBLK1) bsum[tid] = s[tid] - v;    // exclusive block offsets
}

__global__ __launch_bounds__(256) void k_scan3(int* __restrict__ rowstart,
                                               const int* __restrict__ bsum,
                                               int* __restrict__ cursor)
{
    const int i = blockIdx.x * 256 + threadIdx.x;
    if (i < NN) {
        const int rs = rowstart[i] + bsum[i >> 8];
        rowstart[i] = rs;
        cursor[i] = rs;
    }
    if (i == 0) rowstart[NN] = NE;
}

__global__ __launch_bounds__(256) void k_scatter(
    const int* __restrict__ src, const int* __restrict__ dst, const float* __restrict__ ea,
    int* __restrict__ cursor, uint* __restrict__ sd, uint2* __restrict__ eab)
{
    const int e = blockIdx.x * 256 + threadIdx.x;
    if (e < NE) {
        const int d = dst[e];
        const int p = atomicAdd(&cursor[d], 1);
        sd[p] = (uint)src[e] | ((uint)d << 16);
        const float4 t = *(const float4*)&ea[(size_t)e * EDD];
        uint2 pk;
        pk.x = (uint)f2u(t.x) | ((uint)f2u(t.y) << 16);
        pk.y = (uint)f2u(t.z) | ((uint)f2u(t.w) << 16);
        eab[p] = pk;
    }
}

// ---------------------------------------------------------------------------
// h = relu(x @ lin_in_w + b + prev_h @ hist_w + b) ; hb = bf16(h)
// ---------------------------------------------------------------------------
__global__ __launch_bounds__(256) void k_input(
    const float* __restrict__ x, const float* __restrict__ prev_h,
    const float* __restrict__ w_in, const float* __restrict__ b_in,
    const float* __restrict__ w_h, const float* __restrict__ b_h,
    float* __restrict__ h, ushort* __restrict__ hb)
{
    __shared__ float sW1[IND * D];
    __shared__ float sW2[D * D];
    __shared__ float sb[D];
    __shared__ float sx[4][IND];
    __shared__ float sp[4][D];
    const int tid = threadIdx.x;
    for (int i = tid; i < IND * D; i += 256) sW1[i] = w_in[i];
    for (int i = tid; i < D * D; i += 256) sW2[i] = w_h[i];
    if (tid < D) sb[tid] = b_in[tid] + b_h[tid];
    const int j = tid & 63, r = tid >> 6;
    for (int n0 = blockIdx.x * 4; n0 < NN; n0 += gridDim.x * 4) {
        __syncthreads();
        const int n = n0 + r;
        if (n < NN) {
            sp[r][j] = prev_h[n * D + j];
            if (j < IND) sx[r][j] = x[n * IND + j];
        }
        __syncthreads();
        if (n < NN) {
            float acc = sb[j];
#pragma unroll
            for (int k = 0; k < IND; ++k) acc += sx[r][k] * sW1[k * D + j];
#pragma unroll 8
            for (int k = 0; k < D; ++k) acc += sp[r][k] * sW2[k * D + j];
            const float v = fmaxf(acc, 0.0f);
            h[n * D + j] = v;
            hb[n * D + j] = f2u(v);
        }
    }
}

// ---------------------------------------------------------------------------
// y[p] = cat(hb[dst], hb[src], ea) @ W + b over SORTED edges (MFMA) + stats
// ---------------------------------------------------------------------------
__global__ __launch_bounds__(256, 2) void k_msg1(
    const ushort* __restrict__ hb, const uint* __restrict__ sd, const uint2* __restrict__ eab,
    const float* __restrict__ W, const float* __restrict__ b,
    ushort* __restrict__ y, float* __restrict__ st)
{
    __shared__ __align__(16) ushort xs[64][LDA1];
    __shared__ __align__(16) ushort wt[64][LDA1];
    __shared__ float sred[4][2][64];
    const int tid = threadIdx.x;
    const int lane = tid & 63, w = tid >> 6;
    const int fn = lane & 15, quad = lane >> 4;

    // one-time: zero wt, stage W^T (bf16), zero xs K-pad region [128..LDA1)
    for (int i = tid; i < 64 * LDA1; i += 256) ((ushort*)wt)[i] = 0;
    for (int i = tid; i < 64 * (LDA1 - 128); i += 256) {
        const int r = i / (LDA1 - 128), k = 128 + i % (LDA1 - 128);
        xs[r][k] = 0;
    }
    __syncthreads();
    for (int i = tid; i < K1 * D; i += 256) {
        const int k = i >> 6, n = i & 63;
        wt[n][k] = f2u(W[i]);
    }
    __syncthreads();

    bf16x8 Bf[5][4];
#pragma unroll
    for (int s = 0; s < 5; ++s)
#pragma unroll
        for (int c = 0; c < 4; ++c)
            Bf[s][c] = *(const bf16x8*)&wt[c * 16 + fn][s * 32 + quad * 8];
    float bj[4];
#pragma unroll
    for (int c = 0; c < 4; ++c) bj[c] = b[c * 16 + fn];

    float ps[4] = {0, 0, 0, 0}, pq[4] = {0, 0, 0, 0};
    const int r = tid >> 2, q = tid & 3;   // staging: row r, col-chunk q*16
    const int ntiles = (NE + 63) >> 6;

    for (int t = blockIdx.x; t < ntiles; t += gridDim.x) {
        const int e0 = t << 6;
        __syncthreads();
        const int e = e0 + r;
        if (e < NE) {
            const uint sdv = sd[e];
            const int si = (int)(sdv & 0xffffu), di = (int)(sdv >> 16);
            const uint4 a0 = *(const uint4*)&hb[(size_t)di * D + q * 16];
            const uint4 a1 = *(const uint4*)&hb[(size_t)di * D + q * 16 + 8];
            const uint4 b0 = *(const uint4*)&hb[(size_t)si * D + q * 16];
            const uint4 b1 = *(const uint4*)&hb[(size_t)si * D + q * 16 + 8];
            *(uint4*)&xs[r][q * 16] = a0;
            *(uint4*)&xs[r][q * 16 + 8] = a1;
            *(uint4*)&xs[r][64 + q * 16] = b0;
            *(uint4*)&xs[r][64 + q * 16 + 8] = b1;
            if (q == 0) *(uint2*)&xs[r][128] = eab[e];
        } else {
            const uint4 z4 = {0, 0, 0, 0};
            *(uint4*)&xs[r][q * 16] = z4;
            *(uint4*)&xs[r][q * 16 + 8] = z4;
            *(uint4*)&xs[r][64 + q * 16] = z4;
            *(uint4*)&xs[r][64 + q * 16 + 8] = z4;
            if (q == 0) { const uint2 z2 = {0, 0}; *(uint2*)&xs[r][128] = z2; }
        }
        __syncthreads();

        f32x4 acc[4];
#pragma unroll
        for (int c = 0; c < 4; ++c) acc[c] = (f32x4){bj[c], bj[c], bj[c], bj[c]};
        const ushort* arow = xs[w * 16 + fn];
#pragma unroll
        for (int s = 0; s < 5; ++s) {
            const bf16x8 a = *(const bf16x8*)&arow[s * 32 + quad * 8];
            acc[0] = __builtin_amdgcn_mfma_f32_16x16x32_bf16(a, Bf[s][0], acc[0], 0, 0, 0);
            acc[1] = __builtin_amdgcn_mfma_f32_16x16x32_bf16(a, Bf[s][1], acc[1], 0, 0, 0);
            acc[2] = __builtin_amdgcn_mfma_f32_16x16x32_bf16(a, Bf[s][2], acc[2], 0, 0, 0);
            acc[3] = __builtin_amdgcn_mfma_f32_16x16x32_bf16(a, Bf[s][3], acc[3], 0, 0, 0);
        }
        const int row0 = e0 + w * 16 + quad * 4;
#pragma unroll
        for (int reg = 0; reg < 4; ++reg) {
            const int er = row0 + reg;
            if (er < NE) {
#pragma unroll
                for (int c = 0; c < 4; ++c) {
                    const ushort ub = f2u(acc[c][reg]);
                    y[(size_t)er * D + c * 16 + fn] = ub;
                    const float f = u2f(ub);
                    ps[c] += f; pq[c] += f * f;
                }
            }
        }
    }
    __syncthreads();
#pragma unroll
    for (int c = 0; c < 4; ++c) {
        ps[c] += __shfl_xor(ps[c], 16, 64); ps[c] += __shfl_xor(ps[c], 32, 64);
        pq[c] += __shfl_xor(pq[c], 16, 64); pq[c] += __shfl_xor(pq[c], 32, 64);
    }
    if (quad == 0) {
#pragma unroll
        for (int c = 0; c < 4; ++c) {
            sred[w][0][c * 16 + fn] = ps[c];
            sred[w][1][c * 16 + fn] = pq[c];
        }
    }
    __syncthreads();
    if (tid < 128) {
        const int col = tid & 63, which = tid >> 6;
        const float s = sred[0][which][col] + sred[1][which][col] +
                        sred[2][which][col] + sred[3][which][col];
        atomicAdd(&st[which * 64 + col], s);
    }
}

// ---------------------------------------------------------------------------
// yout = relu(BN(yin)) @ W + b   (MFMA, bf16 in/out, in-place safe) + stats
// ---------------------------------------------------------------------------
__global__ __launch_bounds__(256, 2) void k_mlp2b(
    const ushort* __restrict__ yin, ushort* __restrict__ yout,
    const float* __restrict__ W, const float* __restrict__ b,
    const float* __restrict__ gg, const float* __restrict__ be,
    const float* __restrict__ st_in, float* __restrict__ st_out,
    const int nrows, const float inv_rows)
{
    __shared__ __align__(16) ushort xs[64][LDA2];
    __shared__ __align__(16) ushort wt[64][LDA2];
    __shared__ float sal[64], sbe[64];
    __shared__ float sred[4][2][64];
    const int tid = threadIdx.x;
    const int lane = tid & 63, w = tid >> 6;
    const int fn = lane & 15, quad = lane >> 4;

    if (tid < 64) {
        const float m = st_in[tid] * inv_rows;
        const float v = st_in[64 + tid] * inv_rows - m * m;
        const float a = rsqrtf(v + EPSB) * gg[tid];
        sal[tid] = a;
        sbe[tid] = be[tid] - m * a;
    }
    for (int i = tid; i < D * D; i += 256) {
        const int k = i >> 6, n = i & 63;
        wt[n][k] = f2u(W[i]);
    }
    __syncthreads();

    bf16x8 Bf[2][4];
#pragma unroll
    for (int s = 0; s < 2; ++s)
#pragma unroll
        for (int c = 0; c < 4; ++c)
            Bf[s][c] = *(const bf16x8*)&wt[c * 16 + fn][s * 32 + quad * 8];
    float bj[4];
#pragma unroll
    for (int c = 0; c < 4; ++c) bj[c] = b[c * 16 + fn];

    const int r = tid >> 2, q = tid & 3;  // staging: row r, cols q*16..q*16+15
    float al16[16], be16[16];
#pragma unroll
    for (int i = 0; i < 16; ++i) { al16[i] = sal[q * 16 + i]; be16[i] = sbe[q * 16 + i]; }

    float ps[4] = {0, 0, 0, 0}, pq[4] = {0, 0, 0, 0};
    const int ntiles = (nrows + 63) >> 6;

    for (int t = blockIdx.x; t < ntiles; t += gridDim.x) {
        const int r0 = t << 6;
        __syncthreads();
        const int row = r0 + r;
        if (row < nrows) {
            const uint4 u0 = *(const uint4*)&yin[(size_t)row * D + q * 16];
            const uint4 u1 = *(const uint4*)&yin[(size_t)row * D + q * 16 + 8];
            uint res0[4], res1[4];
#pragma unroll
            for (int p = 0; p < 4; ++p) {
                const uint uu = ((const uint*)&u0)[p];
                float f0 = u2f((ushort)(uu & 0xffffu));
                float f1 = u2f((ushort)(uu >> 16));
                f0 = fmaxf(fmaf(f0, al16[2 * p], be16[2 * p]), 0.f);
                f1 = fmaxf(fmaf(f1, al16[2 * p + 1], be16[2 * p + 1]), 0.f);
                res0[p] = (uint)f2u(f0) | ((uint)f2u(f1) << 16);
            }
#pragma unroll
            for (int p = 0; p < 4; ++p) {
                const uint uu = ((const uint*)&u1)[p];
                float f0 = u2f((ushort)(uu & 0xffffu));
                float f1 = u2f((ushort)(uu >> 16));
                f0 = fmaxf(fmaf(f0, al16[8 + 2 * p], be16[8 + 2 * p]), 0.f);
                f1 = fmaxf(fmaf(f1, al16[8 + 2 * p + 1], be16[8 + 2 * p + 1]), 0.f);
                res1[p] = (uint)f2u(f0) | ((uint)f2u(f1) << 16);
            }
            *(uint4*)&xs[r][q * 16] = *(uint4*)res0;
            *(uint4*)&xs[r][q * 16 + 8] = *(uint4*)res1;
        } else {
            const uint4 z4 = {0, 0, 0, 0};
            *(uint4*)&xs[r][q * 16] = z4;
            *(uint4*)&xs[r][q * 16 + 8] = z4;
        }
        __syncthreads();

        f32x4 acc[4];
#pragma unroll
        for (int c = 0; c < 4; ++c) acc[c] = (f32x4){bj[c], bj[c], bj[c], bj[c]};
        const ushort* arow = xs[w * 16 + fn];
#pragma unroll
        for (int s = 0; s < 2; ++s) {
            const bf16x8 a = *(const bf16x8*)&arow[s * 32 + quad * 8];
            acc[0] = __builtin_amdgcn_mfma_f32_16x16x32_bf16(a, Bf[s][0], acc[0], 0, 0, 0);
            acc[1] = __builtin_amdgcn_mfma_f32_16x16x32_bf16(a, Bf[s][1], acc[1], 0, 0, 0);
            acc[2] = __builtin_amdgcn_mfma_f32_16x16x32_bf16(a, Bf[s][2], acc[2], 0, 0, 0);
            acc[3] = __builtin_amdgcn_mfma_f32_16x16x32_bf16(a, Bf[s][3], acc[3], 0, 0, 0);
        }
        const int row0 = r0 + w * 16 + quad * 4;
#pragma unroll
        for (int reg = 0; reg < 4; ++reg) {
            const int er = row0 + reg;
            if (er < nrows) {
#pragma unroll
                for (int c = 0; c < 4; ++c) {
                    const ushort ub = f2u(acc[c][reg]);
                    yout[(size_t)er * D + c * 16 + fn] = ub;
                    const float f = u2f(ub);
                    ps[c] += f; pq[c] += f * f;
                }
            }
        }
    }
    __syncthreads();
#pragma unroll
    for (int c = 0; c < 4; ++c) {
        ps[c] += __shfl_xor(ps[c], 16, 64); ps[c] += __shfl_xor(ps[c], 32, 64);
        pq[c] += __shfl_xor(pq[c], 16, 64); pq[c] += __shfl_xor(pq[c], 32, 64);
    }
    if (quad == 0) {
#pragma unroll
        for (int c = 0; c < 4; ++c) {
            sred[w][0][c * 16 + fn] = ps[c];
            sred[w][1][c * 16 + fn] = pq[c];
        }
    }
    __syncthreads();
    if (tid < 128) {
        const int col = tid & 63, which = tid >> 6;
        const float s = sred[0][which][col] + sred[1][which][col] +
                        sred[2][which][col] + sred[3][which][col];
        atomicAdd(&st_out[which * 64 + col], s);
    }
}

// ---------------------------------------------------------------------------
// aggrb[n] = sum over sorted segment of relu(BN2(y[p]))  — streaming, no atomics
// ---------------------------------------------------------------------------
__global__ __launch_bounds__(256) void k_aggr2(
    const ushort* __restrict__ y, const int* __restrict__ rowstart,
    const float* __restrict__ gg, const float* __restrict__ be,
    const float* __restrict__ st, ushort* __restrict__ aggrb)
{
    __shared__ float sal[D], sbe[D];
    const int tid = threadIdx.x;
    if (tid < D) {
        const float m = st[tid] * (1.f / NE);
        const float v = st[D + tid] * (1.f / NE) - m * m;
        const float a = rsqrtf(v + EPSB) * gg[tid];
        sal[tid] = a;
        sbe[tid] = be[tid] - m * a;
    }
    __syncthreads();
    const int lane = tid & 63, w = tid >> 6;
    const float al = sal[lane], bt = sbe[lane];
    const int stride = gridDim.x * 4;
    for (int n = blockIdx.x * 4 + w; n < NN; n += stride) {
        const int j0 = rowstart[n], j1 = rowstart[n + 1];
        float acc = 0.f;
        for (int j = j0; j < j1; ++j)
            acc += fmaxf(fmaf(u2f(y[(size_t)j * D + lane]), al, bt), 0.f);
        aggrb[(size_t)n * D + lane] = f2u(acc);
    }
}

// ---------------------------------------------------------------------------
// z = cat(hb, aggrb) @ W + b   (MFMA, bf16 staging) + stats
// ---------------------------------------------------------------------------
__global__ __launch_bounds__(256, 2) void k_upd1(
    const ushort* __restrict__ hb, const ushort* __restrict__ aggrb,
    const float* __restrict__ W, const float* __restrict__ b,
    ushort* __restrict__ z, float* __restrict__ st)
{
    __shared__ __align__(16) ushort xs[64][LDA3];
    __shared__ __align__(16) ushort wt[64][LDA3];
    __shared__ float sred[4][2][64];
    const int tid = threadIdx.x;
    const int lane = tid & 63, w = tid >> 6;
    const int fn = lane & 15, quad = lane >> 4;

    for (int i = tid; i < KU * D; i += 256) {
        const int k = i >> 6, n = i & 63;
        wt[n][k] = f2u(W[i]);
    }
    __syncthreads();

    bf16x8 Bf[4][4];
#pragma unroll
    for (int s = 0; s < 4; ++s)
#pragma unroll
        for (int c = 0; c < 4; ++c)
            Bf[s][c] = *(const bf16x8*)&wt[c * 16 + fn][s * 32 + quad * 8];
    float bj[4];
#pragma unroll
    for (int c = 0; c < 4; ++c) bj[c] = b[c * 16 + fn];

    const int r = tid >> 2, q = tid & 3;
    float ps[4] = {0, 0, 0, 0}, pq[4] = {0, 0, 0, 0};
    const int ntiles = (NN + 63) >> 6;

    for (int t = blockIdx.x; t < ntiles; t += gridDim.x) {
        const int n0 = t << 6;
        __syncthreads();
        const int n = n0 + r;
        if (n < NN) {
            *(uint4*)&xs[r][q * 16]          = *(const uint4*)&hb[(size_t)n * D + q * 16];
            *(uint4*)&xs[r][q * 16 + 8]      = *(const uint4*)&hb[(size_t)n * D + q * 16 + 8];
            *(uint4*)&xs[r][64 + q * 16]     = *(const uint4*)&aggrb[(size_t)n * D + q * 16];
            *(uint4*)&xs[r][64 + q * 16 + 8] = *(const uint4*)&aggrb[(size_t)n * D + q * 16 + 8];
        } else {
            const uint4 z4 = {0, 0, 0, 0};
            *(uint4*)&xs[r][q * 16] = z4;
            *(uint4*)&xs[r][q * 16 + 8] = z4;
            *(uint4*)&xs[r][64 + q * 16] = z4;
            *(uint4*)&xs[r][64 + q * 16 + 8] = z4;
        }
        __syncthreads();

        f32x4 acc[4];
#pragma unroll
        for (int c = 0; c < 4; ++c) acc[c] = (f32x4){bj[c], bj[c], bj[c], bj[c]};
        const ushort* arow = xs[w * 16 + fn];
#pragma unroll
        for (int s = 0; s < 4; ++s) {
            const bf16x8 a = *(const bf16x8*)&arow[s * 32 + quad * 8];
            acc[0] = __builtin_amdgcn_mfma_f32_16x16x32_bf16(a, Bf[s][0], acc[0], 0, 0, 0);
            acc[1] = __builtin_amdgcn_mfma_f32_16x16x32_bf16(a, Bf[s][1], acc[1], 0, 0, 0);
            acc[2] = __builtin_amdgcn_mfma_f32_16x16x32_bf16(a, Bf[s][2], acc[2], 0, 0, 0);
            acc[3] = __builtin_amdgcn_mfma_f32_16x16x32_bf16(a, Bf[s][3], acc[3], 0, 0, 0);
        }
        const int row0 = n0 + w * 16 + quad * 4;
#pragma unroll
        for (int reg = 0; reg < 4; ++reg) {
            const int er = row0 + reg;
            if (er < NN) {
#pragma unroll
                for (int c = 0; c < 4; ++c) {
                    const ushort ub = f2u(acc[c][reg]);
                    z[(size_t)er * D + c * 16 + fn] = ub;
                    const float f = u2f(ub);
                    ps[c] += f; pq[c] += f * f;
                }
            }
        }
    }
    __syncthreads();
#pragma unroll
    for (int c = 0; c < 4; ++c) {
        ps[c] += __shfl_xor(ps[c], 16, 64); ps[c] += __shfl_xor(ps[c], 32, 64);
        pq[c] += __shfl_xor(pq[c], 16, 64); pq[c] += __shfl_xor(pq[c], 32, 64);
    }
    if (quad == 0) {
#pragma unroll
        for (int c = 0; c < 4; ++c) {
            sred[w][0][c * 16 + fn] = ps[c];
            sred[w][1][c * 16 + fn] = pq[c];
        }
    }
    __syncthreads();
    if (tid < 128) {
        const int col = tid & 63, which = tid >> 6;
        const float s = sred[0][which][col] + sred[1][which][col] +
                        sred[2][which][col] + sred[3][which][col];
        atomicAdd(&st[which * 64 + col], s);
    }
}

// ---------------------------------------------------------------------------
// h += relu(BN(z)) ; hb = bf16(h)
// ---------------------------------------------------------------------------
__global__ __launch_bounds__(256) void k_upd3(
    const ushort* __restrict__ z, const float* __restrict__ gg, const float* __restrict__ be,
    const float* __restrict__ st, float* __restrict__ h, ushort* __restrict__ hb)
{
    __shared__ float sal[D], sbe[D];
    const int tid = threadIdx.x;
    if (tid < D) {
        const float m = st[tid] * (1.f / NN);
        const float v = st[D + tid] * (1.f / NN) - m * m;
        const float a = rsqrtf(v + EPSB) * gg[tid];
        sal[tid] = a;
        sbe[tid] = be[tid] - m * a;
    }
    __syncthreads();
    const int j = tid & 63;
    const float al = sal[j], bt = sbe[j];
    for (int i = blockIdx.x * 256 + tid; i < NN * D; i += gridDim.x * 256) {
        const float v = h[i] + fmaxf(fmaf(u2f(z[i]), al, bt), 0.f);
        h[i] = v;
        hb[i] = f2u(v);
    }
}

// ---------------------------------------------------------------------------
// node_out = h @ node_w + node_b ; hsum += column sums of h ; copy h to d_out
// ---------------------------------------------------------------------------
__global__ __launch_bounds__(256) void k_nodeout(
    const float* __restrict__ h, const float* __restrict__ nw, const float* __restrict__ nb,
    float* __restrict__ node_out, float* __restrict__ h_out, float* __restrict__ hsum)
{
    __shared__ float hs[64][65];
    __shared__ float snw[D * NOD];
    __shared__ float snb[NOD];
    __shared__ float red[4][D];
    const int tid = threadIdx.x;
    for (int i = tid; i < D * NOD; i += 256) snw[i] = nw[i];
    if (tid < NOD) snb[tid] = nb[tid];
    const int j = tid & 63, g = tid >> 6;
    float cs = 0.f;
    for (int n0 = blockIdx.x * 64; n0 < NN; n0 += gridDim.x * 64) {
        __syncthreads();
        for (int r = g; r < 64; r += 4) {
            const int n = n0 + r;
            float v = 0.f;
            if (n < NN) { v = h[n * D + j]; h_out[n * D + j] = v; }
            hs[r][j] = v;
        }
        __syncthreads();
        for (int r = g; r < 64; r += 4) cs += hs[r][j];
        for (int it = tid; it < 64 * NOD; it += 256) {
            const int r = it / NOD, c = it - r * NOD;
            const int n = n0 + r;
            if (n < NN) {
                float a = snb[c];
#pragma unroll 16
                for (int k = 0; k < D; ++k) a += hs[r][k] * snw[k * NOD + c];
                node_out[n * NOD + c] = a;
            }
        }
    }
    red[g][j] = cs;
    __syncthreads();
    if (tid < D) atomicAdd(&hsum[tid], red[0][tid] + red[1][tid] + red[2][tid] + red[3][tid]);
}

__global__ void k_graphout(const float* __restrict__ hsum, const float* __restrict__ gw,
                           const float* __restrict__ gb, float* __restrict__ out)
{
    const int j = threadIdx.x;  // 64 threads
    float v = hsum[j] * (1.f / NN) * gw[j];
#pragma unroll
    for (int off = 32; off > 0; off >>= 1) v += __shfl_down(v, off, 64);
    if (j == 0) out[0] = v + gb[0];
}

// ---------------------------------------------------------------------------
extern "C" void kernel_launch(void* const* d_in, const int* in_sizes, int n_in,
                              void* d_out, int out_size, void* d_ws, size_t ws_size,
                              hipStream_t stream)
{
    (void)in_sizes; (void)n_in; (void)out_size; (void)ws_size;
    const float* x        = (const float*)d_in[0];
    const int*   ei       = (const int*)  d_in[1];
    const float* ea       = (const float*)d_in[2];
    const float* prev_h   = (const float*)d_in[3];
    const float* lin_in_w = (const float*)d_in[4];
    const float* lin_in_b = (const float*)d_in[5];
    const float* hist_w   = (const float*)d_in[6];
    const float* hist_b   = (const float*)d_in[7];
    const float* msg_w1   = (const float*)d_in[8];
    const float* msg_b1   = (const float*)d_in[9];
    const float* msg_g1   = (const float*)d_in[10];
    const float* msg_be1  = (const float*)d_in[11];
    const float* msg_w2   = (const float*)d_in[12];
    const float* msg_b2   = (const float*)d_in[13];
    const float* msg_g2   = (const float*)d_in[14];
    const float* msg_be2  = (const float*)d_in[15];
    const float* upd_w1   = (const float*)d_in[16];
    const float* upd_b1   = (const float*)d_in[17];
    const float* upd_g1   = (const float*)d_in[18];
    const float* upd_be1  = (const float*)d_in[19];
    const float* upd_w2   = (const float*)d_in[20];
    const float* upd_b2   = (const float*)d_in[21];
    const float* upd_g2   = (const float*)d_in[22];
    const float* upd_be2  = (const float*)d_in[23];
    const float* graph_w  = (const float*)d_in[24];
    const float* graph_b  = (const float*)d_in[25];
    const float* node_w   = (const float*)d_in[26];
    const float* node_b   = (const float*)d_in[27];

    const int* src = ei;        // edge_index[0]
    const int* dst = ei + NE;   // edge_index[1]

    float* out       = (float*)d_out;
    float* graph_out = out;                  // [1]
    float* node_out  = out + 1;              // [N*NO]
    float* h_out     = out + 1 + NN * NOD;   // [N*D]

    char* ws = (char*)d_ws;
    size_t off = 0;
    ushort* y     = (ushort*)(ws + off); off += (size_t)NE * D * sizeof(ushort);  // 64 MB
    ushort* z     = y;   // aliases y: z's lifetime (upd1..upd3) disjoint from y's (msg1..aggr2)
    ushort* aggrb = (ushort*)(ws + off); off += (size_t)NN * D * sizeof(ushort);  // 6.4 MB
    float*  h     = (float*) (ws + off); off += (size_t)NN * D * sizeof(float);   // 12.8 MB
    ushort* hb    = (ushort*)(ws + off); off += (size_t)NN * D * sizeof(ushort);  // 6.4 MB
    uint*   sd    = (uint*)  (ws + off); off += (size_t)NE * sizeof(uint);        // 2 MB
    uint2*  eab   = (uint2*) (ws + off); off += (size_t)NE * sizeof(uint2);       // 4 MB
    int* rowstart = (int*)   (ws + off); off += (size_t)(NN + 1) * sizeof(int);
    int* cnt      = (int*)   (ws + off); off += (size_t)NN * sizeof(int);         // also reused as cursor
    int* bsum     = (int*)   (ws + off); off += (size_t)256 * sizeof(int);
    float* stats  = (float*) (ws + off); off += (size_t)(NL * 4 * 2 * D) * sizeof(float);
    float* hsum   = (float*) (ws + off); off += (size_t)D * sizeof(float);
    int* cursor   = cnt;  // cnt dead after k_scan1; k_scan3 rewrites as cursor

    hipMemsetAsync(cnt, 0, (size_t)NN * sizeof(int), stream);
    hipMemsetAsync(stats, 0, (size_t)(NL * 4 * 2 * D + D) * sizeof(float), stream);

    // edge sort (reused across all layers)
    k_hist<<<(NE + 255) / 256, 256, 0, stream>>>(dst, cnt);
    k_scan1<<<NBLK1, 256, 0, stream>>>(cnt, rowstart, bsum);
    k_scan2<<<1, 256, 0, stream>>>(bsum);
    k_scan3<<<NBLK1, 256, 0, stream>>>(rowstart, bsum, cursor);
    k_scatter<<<(NE + 255) / 256, 256, 0, stream>>>(src, dst, ea, cursor, sd, eab);

    k_input<<<512, 256, 0, stream>>>(x, prev_h, lin_in_w, lin_in_b, hist_w, hist_b, h, hb);

    for (int l = 0; l < NL; ++l) {
        float* st_m1 = stats + (l * 4 + 0) * 2 * D;
        float* st_m2 = stats + (l * 4 + 1) * 2 * D;
        float* st_u1 = stats + (l * 4 + 2) * 2 * D;
        float* st_u2 = stats + (l * 4 + 3) * 2 * D;
        k_msg1<<<1024, 256, 0, stream>>>(hb, sd, eab,
                                         msg_w1 + (size_t)l * K1 * D, msg_b1 + l * D, y, st_m1);
        k_mlp2b<<<1024, 256, 0, stream>>>(y, y,
                                          msg_w2 + (size_t)l * D * D, msg_b2 + l * D,
                                          msg_g1 + l * D, msg_be1 + l * D,
                                          st_m1, st_m2, NE, 1.f / NE);
        k_aggr2<<<512, 256, 0, stream>>>(y, rowstart, msg_g2 + l * D, msg_be2 + l * D,
                                         st_m2, aggrb);
        k_upd1<<<782, 256, 0, stream>>>(hb, aggrb,
                                        upd_w1 + (size_t)l * KU * D, upd_b1 + l * D, z, st_u1);
        k_mlp2b<<<782, 256, 0, stream>>>(z, z,
                                         upd_w2 + (size_t)l * D * D, upd_b2 + l * D,
                                         upd_g1 + l * D, upd_be1 + l * D,
                                         st_u1, st_u2, NN, 1.f / NN);
        k_upd3<<<1024, 256, 0, stream>>>(z, upd_g2 + l * D, upd_be2 + l * D, st_u2, h, hb);
    }

    k_nodeout<<<782, 256, 0, stream>>>(h, node_w, node_b, node_out, h_out, hsum);
    k_graphout<<<1, 64, 0, stream>>>(hsum, graph_w, graph_b, graph_out);
}

// Round 4
// 1091.361 us; speedup vs baseline: 1.2434x; 1.2434x over previous
//
#include <hip/hip_runtime.h>
#include <hip/hip_bf16.h>

#define NN 50000
#define NE 500000
#define D 64
#define IND 11
#define EDD 4
#define NOD 5
#define NL 4
#define K1 132   // 2D + ED
#define KU 128   // 2D
#define EPSB 1e-5f

#define LDA1 168  // K-stride (bf16) for msg1 tiles: 160 used + 8 pad
#define LDA2 72   // K=64 + 8
#define LDA3 136  // K=128 + 8

#define NBLK1 196  // ceil(50000/256) scan chunks

typedef __hip_bfloat16 bf16;
typedef __attribute__((ext_vector_type(8))) __bf16 bf16x8;
typedef __attribute__((ext_vector_type(4))) float f32x4;

__device__ __forceinline__ ushort f2u(float f) {
    __hip_bfloat16 h = __float2bfloat16(f);
    return __builtin_bit_cast(ushort, h);
}
__device__ __forceinline__ float u2f(ushort u) {
    uint v = (uint)u << 16;
    return __builtin_bit_cast(float, v);
}

// ---------------------------------------------------------------------------
// Edge sort by dst: histogram -> scan -> scatter (reused by all 4 layers)
// ---------------------------------------------------------------------------
__global__ __launch_bounds__(256) void k_hist(const int* __restrict__ dst, int* __restrict__ cnt)
{
    const int e = blockIdx.x * 256 + threadIdx.x;
    if (e < NE) atomicAdd(&cnt[dst[e]], 1);
}

__global__ __launch_bounds__(256) void k_scan1(const int* __restrict__ cnt,
                                               int* __restrict__ rowstart, int* __restrict__ bsum)
{
    __shared__ int s[256];
    const int tid = threadIdx.x;
    const int i = blockIdx.x * 256 + tid;
    const int v = (i < NN) ? cnt[i] : 0;
    s[tid] = v;
    __syncthreads();
    for (int off = 1; off < 256; off <<= 1) {
        const int t = (tid >= off) ? s[tid - off] : 0;
        __syncthreads();
        s[tid] += t;
        __syncthreads();
    }
    if (i < NN) rowstart[i] = s[tid] - v;       // exclusive within chunk
    if (tid == 255) bsum[blockIdx.x] = s[255];  // chunk total
}

__global__ __launch_bounds__(256) void k_scan2(int* __restrict__ bsum)
{
    __shared__ int s[256];
    const int tid = threadIdx.x;
    const int v = (tid < NBLK1) ? bsum[tid] : 0;
    s[tid] = v;
    __syncthreads();
    for (int off = 1; off < 256; off <<= 1) {
        const int t = (tid >= off) ? s[tid - off] : 0;
        __syncthreads();
        s[tid] += t;
        __syncthreads();
    }
    if (tid < NBLK1) bsum[tid] = s[tid] - v;    // exclusive block offsets
}

__global__ __launch_bounds__(256) void k_scan3(int* __restrict__ rowstart,
                                               const int* __restrict__ bsum,
                                               int* __restrict__ cursor)
{
    const int i = blockIdx.x * 256 + threadIdx.x;
    if (i < NN) {
        const int rs = rowstart[i] + bsum[i >> 8];
        rowstart[i] = rs;
        cursor[i] = rs;
    }
    if (i == 0) rowstart[NN] = NE;
}

__global__ __launch_bounds__(256) void k_scatter(
    const int* __restrict__ src, const int* __restrict__ dst, const float* __restrict__ ea,
    int* __restrict__ cursor, uint* __restrict__ sd, uint2* __restrict__ eab)
{
    const int e = blockIdx.x * 256 + threadIdx.x;
    if (e < NE) {
        const int d = dst[e];
        const int p = atomicAdd(&cursor[d], 1);
        sd[p] = (uint)src[e] | ((uint)d << 16);
        const float4 t = *(const float4*)&ea[(size_t)e * EDD];
        uint2 pk;
        pk.x = (uint)f2u(t.x) | ((uint)f2u(t.y) << 16);
        pk.y = (uint)f2u(t.z) | ((uint)f2u(t.w) << 16);
        eab[p] = pk;
    }
}

// ---------------------------------------------------------------------------
// h = relu(x @ lin_in_w + b + prev_h @ hist_w + b) ; hb = bf16(h)
// ---------------------------------------------------------------------------
__global__ __launch_bounds__(256) void k_input(
    const float* __restrict__ x, const float* __restrict__ prev_h,
    const float* __restrict__ w_in, const float* __restrict__ b_in,
    const float* __restrict__ w_h, const float* __restrict__ b_h,
    float* __restrict__ h, ushort* __restrict__ hb)
{
    __shared__ float sW1[IND * D];
    __shared__ float sW2[D * D];
    __shared__ float sb[D];
    __shared__ float sx[4][IND];
    __shared__ float sp[4][D];
    const int tid = threadIdx.x;
    for (int i = tid; i < IND * D; i += 256) sW1[i] = w_in[i];
    for (int i = tid; i < D * D; i += 256) sW2[i] = w_h[i];
    if (tid < D) sb[tid] = b_in[tid] + b_h[tid];
    const int j = tid & 63, r = tid >> 6;
    for (int n0 = blockIdx.x * 4; n0 < NN; n0 += gridDim.x * 4) {
        __syncthreads();
        const int n = n0 + r;
        if (n < NN) {
            sp[r][j] = prev_h[n * D + j];
            if (j < IND) sx[r][j] = x[n * IND + j];
        }
        __syncthreads();
        if (n < NN) {
            float acc = sb[j];
#pragma unroll
            for (int k = 0; k < IND; ++k) acc += sx[r][k] * sW1[k * D + j];
#pragma unroll 8
            for (int k = 0; k < D; ++k) acc += sp[r][k] * sW2[k * D + j];
            const float v = fmaxf(acc, 0.0f);
            h[n * D + j] = v;
            hb[n * D + j] = f2u(v);
        }
    }
}

// ---------------------------------------------------------------------------
// y[p] = cat(hb[dst], hb[src], ea) @ W + b over SORTED edges (MFMA) + stats
// ---------------------------------------------------------------------------
__global__ __launch_bounds__(256, 2) void k_msg1(
    const ushort* __restrict__ hb, const uint* __restrict__ sd, const uint2* __restrict__ eab,
    const float* __restrict__ W, const float* __restrict__ b,
    ushort* __restrict__ y, float* __restrict__ st)
{
    __shared__ __align__(16) ushort xs[64][LDA1];
    __shared__ __align__(16) ushort wt[64][LDA1];
    __shared__ float sred[4][2][64];
    const int tid = threadIdx.x;
    const int lane = tid & 63, w = tid >> 6;
    const int fn = lane & 15, quad = lane >> 4;

    // one-time: zero wt, stage W^T (bf16), zero xs K-pad region [128..LDA1)
    for (int i = tid; i < 64 * LDA1; i += 256) ((ushort*)wt)[i] = 0;
    for (int i = tid; i < 64 * (LDA1 - 128); i += 256) {
        const int r = i / (LDA1 - 128), k = 128 + i % (LDA1 - 128);
        xs[r][k] = 0;
    }
    __syncthreads();
    for (int i = tid; i < K1 * D; i += 256) {
        const int k = i >> 6, n = i & 63;
        wt[n][k] = f2u(W[i]);
    }
    __syncthreads();

    bf16x8 Bf[5][4];
#pragma unroll
    for (int s = 0; s < 5; ++s)
#pragma unroll
        for (int c = 0; c < 4; ++c)
            Bf[s][c] = *(const bf16x8*)&wt[c * 16 + fn][s * 32 + quad * 8];
    float bj[4];
#pragma unroll
    for (int c = 0; c < 4; ++c) bj[c] = b[c * 16 + fn];

    float ps[4] = {0, 0, 0, 0}, pq[4] = {0, 0, 0, 0};
    const int r = tid >> 2, q = tid & 3;   // staging: row r, col-chunk q*16
    const int ntiles = (NE + 63) >> 6;

    for (int t = blockIdx.x; t < ntiles; t += gridDim.x) {
        const int e0 = t << 6;
        __syncthreads();
        const int e = e0 + r;
        if (e < NE) {
            const uint sdv = sd[e];
            const int si = (int)(sdv & 0xffffu), di = (int)(sdv >> 16);
            const uint4 a0 = *(const uint4*)&hb[(size_t)di * D + q * 16];
            const uint4 a1 = *(const uint4*)&hb[(size_t)di * D + q * 16 + 8];
            const uint4 b0 = *(const uint4*)&hb[(size_t)si * D + q * 16];
            const uint4 b1 = *(const uint4*)&hb[(size_t)si * D + q * 16 + 8];
            *(uint4*)&xs[r][q * 16] = a0;
            *(uint4*)&xs[r][q * 16 + 8] = a1;
            *(uint4*)&xs[r][64 + q * 16] = b0;
            *(uint4*)&xs[r][64 + q * 16 + 8] = b1;
            if (q == 0) *(uint2*)&xs[r][128] = eab[e];
        } else {
            const uint4 z4 = {0, 0, 0, 0};
            *(uint4*)&xs[r][q * 16] = z4;
            *(uint4*)&xs[r][q * 16 + 8] = z4;
            *(uint4*)&xs[r][64 + q * 16] = z4;
            *(uint4*)&xs[r][64 + q * 16 + 8] = z4;
            if (q == 0) { const uint2 z2 = {0, 0}; *(uint2*)&xs[r][128] = z2; }
        }
        __syncthreads();

        f32x4 acc[4];
#pragma unroll
        for (int c = 0; c < 4; ++c) acc[c] = (f32x4){bj[c], bj[c], bj[c], bj[c]};
        const ushort* arow = xs[w * 16 + fn];
#pragma unroll
        for (int s = 0; s < 5; ++s) {
            const bf16x8 a = *(const bf16x8*)&arow[s * 32 + quad * 8];
            acc[0] = __builtin_amdgcn_mfma_f32_16x16x32_bf16(a, Bf[s][0], acc[0], 0, 0, 0);
            acc[1] = __builtin_amdgcn_mfma_f32_16x16x32_bf16(a, Bf[s][1], acc[1], 0, 0, 0);
            acc[2] = __builtin_amdgcn_mfma_f32_16x16x32_bf16(a, Bf[s][2], acc[2], 0, 0, 0);
            acc[3] = __builtin_amdgcn_mfma_f32_16x16x32_bf16(a, Bf[s][3], acc[3], 0, 0, 0);
        }
        const int row0 = e0 + w * 16 + quad * 4;
#pragma unroll
        for (int reg = 0; reg < 4; ++reg) {
            const int er = row0 + reg;
            if (er < NE) {
#pragma unroll
                for (int c = 0; c < 4; ++c) {
                    const ushort ub = f2u(acc[c][reg]);
                    y[(size_t)er * D + c * 16 + fn] = ub;
                    const float f = u2f(ub);
                    ps[c] += f; pq[c] += f * f;
                }
            }
        }
    }
    __syncthreads();
#pragma unroll
    for (int c = 0; c < 4; ++c) {
        ps[c] += __shfl_xor(ps[c], 16, 64); ps[c] += __shfl_xor(ps[c], 32, 64);
        pq[c] += __shfl_xor(pq[c], 16, 64); pq[c] += __shfl_xor(pq[c], 32, 64);
    }
    if (quad == 0) {
#pragma unroll
        for (int c = 0; c < 4; ++c) {
            sred[w][0][c * 16 + fn] = ps[c];
            sred[w][1][c * 16 + fn] = pq[c];
        }
    }
    __syncthreads();
    if (tid < 128) {
        const int col = tid & 63, which = tid >> 6;
        const float s = sred[0][which][col] + sred[1][which][col] +
                        sred[2][which][col] + sred[3][which][col];
        atomicAdd(&st[which * 64 + col], s);
    }
}

// ---------------------------------------------------------------------------
// yout = relu(BN(yin)) @ W + b   (MFMA, bf16 in/out, in-place safe) + stats
// ---------------------------------------------------------------------------
__global__ __launch_bounds__(256, 2) void k_mlp2b(
    const ushort* __restrict__ yin, ushort* __restrict__ yout,
    const float* __restrict__ W, const float* __restrict__ b,
    const float* __restrict__ gg, const float* __restrict__ be,
    const float* __restrict__ st_in, float* __restrict__ st_out,
    const int nrows, const float inv_rows)
{
    __shared__ __align__(16) ushort xs[64][LDA2];
    __shared__ __align__(16) ushort wt[64][LDA2];
    __shared__ float sal[64], sbe[64];
    __shared__ float sred[4][2][64];
    const int tid = threadIdx.x;
    const int lane = tid & 63, w = tid >> 6;
    const int fn = lane & 15, quad = lane >> 4;

    if (tid < 64) {
        const float m = st_in[tid] * inv_rows;
        const float v = st_in[64 + tid] * inv_rows - m * m;
        const float a = rsqrtf(v + EPSB) * gg[tid];
        sal[tid] = a;
        sbe[tid] = be[tid] - m * a;
    }
    for (int i = tid; i < D * D; i += 256) {
        const int k = i >> 6, n = i & 63;
        wt[n][k] = f2u(W[i]);
    }
    __syncthreads();

    bf16x8 Bf[2][4];
#pragma unroll
    for (int s = 0; s < 2; ++s)
#pragma unroll
        for (int c = 0; c < 4; ++c)
            Bf[s][c] = *(const bf16x8*)&wt[c * 16 + fn][s * 32 + quad * 8];
    float bj[4];
#pragma unroll
    for (int c = 0; c < 4; ++c) bj[c] = b[c * 16 + fn];

    const int r = tid >> 2, q = tid & 3;  // staging: row r, cols q*16..q*16+15
    float al16[16], be16[16];
#pragma unroll
    for (int i = 0; i < 16; ++i) { al16[i] = sal[q * 16 + i]; be16[i] = sbe[q * 16 + i]; }

    float ps[4] = {0, 0, 0, 0}, pq[4] = {0, 0, 0, 0};
    const int ntiles = (nrows + 63) >> 6;

    for (int t = blockIdx.x; t < ntiles; t += gridDim.x) {
        const int r0 = t << 6;
        __syncthreads();
        const int row = r0 + r;
        if (row < nrows) {
            const uint4 u0 = *(const uint4*)&yin[(size_t)row * D + q * 16];
            const uint4 u1 = *(const uint4*)&yin[(size_t)row * D + q * 16 + 8];
            uint res0[4], res1[4];
#pragma unroll
            for (int p = 0; p < 4; ++p) {
                const uint uu = ((const uint*)&u0)[p];
                float f0 = u2f((ushort)(uu & 0xffffu));
                float f1 = u2f((ushort)(uu >> 16));
                f0 = fmaxf(fmaf(f0, al16[2 * p], be16[2 * p]), 0.f);
                f1 = fmaxf(fmaf(f1, al16[2 * p + 1], be16[2 * p + 1]), 0.f);
                res0[p] = (uint)f2u(f0) | ((uint)f2u(f1) << 16);
            }
#pragma unroll
            for (int p = 0; p < 4; ++p) {
                const uint uu = ((const uint*)&u1)[p];
                float f0 = u2f((ushort)(uu & 0xffffu));
                float f1 = u2f((ushort)(uu >> 16));
                f0 = fmaxf(fmaf(f0, al16[8 + 2 * p], be16[8 + 2 * p]), 0.f);
                f1 = fmaxf(fmaf(f1, al16[8 + 2 * p + 1], be16[8 + 2 * p + 1]), 0.f);
                res1[p] = (uint)f2u(f0) | ((uint)f2u(f1) << 16);
            }
            *(uint4*)&xs[r][q * 16] = *(uint4*)res0;
            *(uint4*)&xs[r][q * 16 + 8] = *(uint4*)res1;
        } else {
            const uint4 z4 = {0, 0, 0, 0};
            *(uint4*)&xs[r][q * 16] = z4;
            *(uint4*)&xs[r][q * 16 + 8] = z4;
        }
        __syncthreads();

        f32x4 acc[4];
#pragma unroll
        for (int c = 0; c < 4; ++c) acc[c] = (f32x4){bj[c], bj[c], bj[c], bj[c]};
        const ushort* arow = xs[w * 16 + fn];
#pragma unroll
        for (int s = 0; s < 2; ++s) {
            const bf16x8 a = *(const bf16x8*)&arow[s * 32 + quad * 8];
            acc[0] = __builtin_amdgcn_mfma_f32_16x16x32_bf16(a, Bf[s][0], acc[0], 0, 0, 0);
            acc[1] = __builtin_amdgcn_mfma_f32_16x16x32_bf16(a, Bf[s][1], acc[1], 0, 0, 0);
            acc[2] = __builtin_amdgcn_mfma_f32_16x16x32_bf16(a, Bf[s][2], acc[2], 0, 0, 0);
            acc[3] = __builtin_amdgcn_mfma_f32_16x16x32_bf16(a, Bf[s][3], acc[3], 0, 0, 0);
        }
        const int row0 = r0 + w * 16 + quad * 4;
#pragma unroll
        for (int reg = 0; reg < 4; ++reg) {
            const int er = row0 + reg;
            if (er < nrows) {
#pragma unroll
                for (int c = 0; c < 4; ++c) {
                    const ushort ub = f2u(acc[c][reg]);
                    yout[(size_t)er * D + c * 16 + fn] = ub;
                    const float f = u2f(ub);
                    ps[c] += f; pq[c] += f * f;
                }
            }
        }
    }
    __syncthreads();
#pragma unroll
    for (int c = 0; c < 4; ++c) {
        ps[c] += __shfl_xor(ps[c], 16, 64); ps[c] += __shfl_xor(ps[c], 32, 64);
        pq[c] += __shfl_xor(pq[c], 16, 64); pq[c] += __shfl_xor(pq[c], 32, 64);
    }
    if (quad == 0) {
#pragma unroll
        for (int c = 0; c < 4; ++c) {
            sred[w][0][c * 16 + fn] = ps[c];
            sred[w][1][c * 16 + fn] = pq[c];
        }
    }
    __syncthreads();
    if (tid < 128) {
        const int col = tid & 63, which = tid >> 6;
        const float s = sred[0][which][col] + sred[1][which][col] +
                        sred[2][which][col] + sred[3][which][col];
        atomicAdd(&st_out[which * 64 + col], s);
    }
}

// ---------------------------------------------------------------------------
// aggr (fp32, pre-zeroed) += segment sums of relu(BN2(y))
// one block per 64-edge tile of the SORTED edge list; LDS-staged; coalesced
// fp32 atomics only at node granularity (adjacent-block contention only)
// ---------------------------------------------------------------------------
__global__ __launch_bounds__(256) void k_aggr3(
    const ushort* __restrict__ y, const int* __restrict__ rowstart,
    const uint* __restrict__ sd,
    const float* __restrict__ gg, const float* __restrict__ be,
    const float* __restrict__ st, float* __restrict__ aggr)
{
    __shared__ float ys[64][68];   // stride 68: uniform 8-phase b128 LDS access
    __shared__ float sal[D], sbe[D];
    const int tid = threadIdx.x;
    if (tid < D) {
        const float m = st[tid] * (1.f / NE);
        const float v = st[D + tid] * (1.f / NE) - m * m;
        const float a = rsqrtf(v + EPSB) * gg[tid];
        sal[tid] = a;
        sbe[tid] = be[tid] - m * a;
    }
    __syncthreads();

    const int e0 = blockIdx.x << 6;
    const int e1 = min(e0 + 64, NE);

    // stage + BN + relu: thread t -> row t/4, cols (t&3)*16 .. +15
    const int r = tid >> 2, c0 = (tid & 3) << 4;
    const int e = e0 + r;
    if (e < NE) {
        const uint4 u0 = *(const uint4*)&y[(size_t)e * D + c0];
        const uint4 u1 = *(const uint4*)&y[(size_t)e * D + c0 + 8];
#pragma unroll
        for (int p = 0; p < 4; ++p) {
            const uint uu = ((const uint*)&u0)[p];
            const int cc = c0 + 2 * p;
            ys[r][cc]     = fmaxf(fmaf(u2f((ushort)(uu & 0xffffu)), sal[cc], sbe[cc]), 0.f);
            ys[r][cc + 1] = fmaxf(fmaf(u2f((ushort)(uu >> 16)), sal[cc + 1], sbe[cc + 1]), 0.f);
        }
#pragma unroll
        for (int p = 0; p < 4; ++p) {
            const uint uu = ((const uint*)&u1)[p];
            const int cc = c0 + 8 + 2 * p;
            ys[r][cc]     = fmaxf(fmaf(u2f((ushort)(uu & 0xffffu)), sal[cc], sbe[cc]), 0.f);
            ys[r][cc + 1] = fmaxf(fmaf(u2f((ushort)(uu >> 16)), sal[cc + 1], sbe[cc + 1]), 0.f);
        }
    }
    __syncthreads();

    // segment sums: wave w handles nodes n0+w, n0+w+4, ... intersecting window
    const int lane = tid & 63, w = tid >> 6;
    int n = (int)(sd[e0] >> 16) + w;   // dst of first edge in window
    while (n < NN) {
        const int rs = rowstart[n];
        if (rs >= e1) break;
        const int re = rowstart[n + 1];
        const int j0 = max(rs, e0), j1 = min(re, e1);
        if (j1 > j0) {
            float s = 0.f;
            for (int j = j0; j < j1; ++j) s += ys[j - e0][lane];
            atomicAdd(&aggr[(size_t)n * D + lane], s);
        }
        n += 4;
    }
}

// ---------------------------------------------------------------------------
// z = cat(hb, aggr_f32) @ W + b   (MFMA, bf16 staging) + stats
// ---------------------------------------------------------------------------
__global__ __launch_bounds__(256, 2) void k_upd1(
    const ushort* __restrict__ hb, const float* __restrict__ aggr,
    const float* __restrict__ W, const float* __restrict__ b,
    ushort* __restrict__ z, float* __restrict__ st)
{
    __shared__ __align__(16) ushort xs[64][LDA3];
    __shared__ __align__(16) ushort wt[64][LDA3];
    __shared__ float sred[4][2][64];
    const int tid = threadIdx.x;
    const int lane = tid & 63, w = tid >> 6;
    const int fn = lane & 15, quad = lane >> 4;

    for (int i = tid; i < KU * D; i += 256) {
        const int k = i >> 6, n = i & 63;
        wt[n][k] = f2u(W[i]);
    }
    __syncthreads();

    bf16x8 Bf[4][4];
#pragma unroll
    for (int s = 0; s < 4; ++s)
#pragma unroll
        for (int c = 0; c < 4; ++c)
            Bf[s][c] = *(const bf16x8*)&wt[c * 16 + fn][s * 32 + quad * 8];
    float bj[4];
#pragma unroll
    for (int c = 0; c < 4; ++c) bj[c] = b[c * 16 + fn];

    const int r = tid >> 2, q = tid & 3;
    float ps[4] = {0, 0, 0, 0}, pq[4] = {0, 0, 0, 0};
    const int ntiles = (NN + 63) >> 6;

    for (int t = blockIdx.x; t < ntiles; t += gridDim.x) {
        const int n0 = t << 6;
        __syncthreads();
        const int n = n0 + r;
        if (n < NN) {
            *(uint4*)&xs[r][q * 16]     = *(const uint4*)&hb[(size_t)n * D + q * 16];
            *(uint4*)&xs[r][q * 16 + 8] = *(const uint4*)&hb[(size_t)n * D + q * 16 + 8];
            uint out2[4], out3[4];
#pragma unroll
            for (int p = 0; p < 4; ++p) {
                const float4 av = *(const float4*)&aggr[(size_t)n * D + q * 16 + p * 4];
                ((uint*)(p < 2 ? out2 : out3))[(p & 1) * 2 + 0] =
                    (uint)f2u(av.x) | ((uint)f2u(av.y) << 16);
                ((uint*)(p < 2 ? out2 : out3))[(p & 1) * 2 + 1] =
                    (uint)f2u(av.z) | ((uint)f2u(av.w) << 16);
            }
            *(uint4*)&xs[r][64 + q * 16]     = *(uint4*)out2;
            *(uint4*)&xs[r][64 + q * 16 + 8] = *(uint4*)out3;
        } else {
            const uint4 z4 = {0, 0, 0, 0};
            *(uint4*)&xs[r][q * 16] = z4;
            *(uint4*)&xs[r][q * 16 + 8] = z4;
            *(uint4*)&xs[r][64 + q * 16] = z4;
            *(uint4*)&xs[r][64 + q * 16 + 8] = z4;
        }
        __syncthreads();

        f32x4 acc[4];
#pragma unroll
        for (int c = 0; c < 4; ++c) acc[c] = (f32x4){bj[c], bj[c], bj[c], bj[c]};
        const ushort* arow = xs[w * 16 + fn];
#pragma unroll
        for (int s = 0; s < 4; ++s) {
            const bf16x8 a = *(const bf16x8*)&arow[s * 32 + quad * 8];
            acc[0] = __builtin_amdgcn_mfma_f32_16x16x32_bf16(a, Bf[s][0], acc[0], 0, 0, 0);
            acc[1] = __builtin_amdgcn_mfma_f32_16x16x32_bf16(a, Bf[s][1], acc[1], 0, 0, 0);
            acc[2] = __builtin_amdgcn_mfma_f32_16x16x32_bf16(a, Bf[s][2], acc[2], 0, 0, 0);
            acc[3] = __builtin_amdgcn_mfma_f32_16x16x32_bf16(a, Bf[s][3], acc[3], 0, 0, 0);
        }
        const int row0 = n0 + w * 16 + quad * 4;
#pragma unroll
        for (int reg = 0; reg < 4; ++reg) {
            const int er = row0 + reg;
            if (er < NN) {
#pragma unroll
                for (int c = 0; c < 4; ++c) {
                    const ushort ub = f2u(acc[c][reg]);
                    z[(size_t)er * D + c * 16 + fn] = ub;
                    const float f = u2f(ub);
                    ps[c] += f; pq[c] += f * f;
                }
            }
        }
    }
    __syncthreads();
#pragma unroll
    for (int c = 0; c < 4; ++c) {
        ps[c] += __shfl_xor(ps[c], 16, 64); ps[c] += __shfl_xor(ps[c], 32, 64);
        pq[c] += __shfl_xor(pq[c], 16, 64); pq[c] += __shfl_xor(pq[c], 32, 64);
    }
    if (quad == 0) {
#pragma unroll
        for (int c = 0; c < 4; ++c) {
            sred[w][0][c * 16 + fn] = ps[c];
            sred[w][1][c * 16 + fn] = pq[c];
        }
    }
    __syncthreads();
    if (tid < 128) {
        const int col = tid & 63, which = tid >> 6;
        const float s = sred[0][which][col] + sred[1][which][col] +
                        sred[2][which][col] + sred[3][which][col];
        atomicAdd(&st[which * 64 + col], s);
    }
}

// ---------------------------------------------------------------------------
// h += relu(BN(z)) ; hb = bf16(h)
// ---------------------------------------------------------------------------
__global__ __launch_bounds__(256) void k_upd3(
    const ushort* __restrict__ z, const float* __restrict__ gg, const float* __restrict__ be,
    const float* __restrict__ st, float* __restrict__ h, ushort* __restrict__ hb)
{
    __shared__ float sal[D], sbe[D];
    const int tid = threadIdx.x;
    if (tid < D) {
        const float m = st[tid] * (1.f / NN);
        const float v = st[D + tid] * (1.f / NN) - m * m;
        const float a = rsqrtf(v + EPSB) * gg[tid];
        sal[tid] = a;
        sbe[tid] = be[tid] - m * a;
    }
    __syncthreads();
    const int j = tid & 63;
    const float al = sal[j], bt = sbe[j];
    for (int i = blockIdx.x * 256 + tid; i < NN * D; i += gridDim.x * 256) {
        const float v = h[i] + fmaxf(fmaf(u2f(z[i]), al, bt), 0.f);
        h[i] = v;
        hb[i] = f2u(v);
    }
}

// ---------------------------------------------------------------------------
// node_out = h @ node_w + node_b ; hsum += column sums of h ; copy h to d_out
// ---------------------------------------------------------------------------
__global__ __launch_bounds__(256) void k_nodeout(
    const float* __restrict__ h, const float* __restrict__ nw, const float* __restrict__ nb,
    float* __restrict__ node_out, float* __restrict__ h_out, float* __restrict__ hsum)
{
    __shared__ float hs[64][65];
    __shared__ float snw[D * NOD];
    __shared__ float snb[NOD];
    __shared__ float red[4][D];
    const int tid = threadIdx.x;
    for (int i = tid; i < D * NOD; i += 256) snw[i] = nw[i];
    if (tid < NOD) snb[tid] = nb[tid];
    const int j = tid & 63, g = tid >> 6;
    float cs = 0.f;
    for (int n0 = blockIdx.x * 64; n0 < NN; n0 += gridDim.x * 64) {
        __syncthreads();
        for (int r = g; r < 64; r += 4) {
            const int n = n0 + r;
            float v = 0.f;
            if (n < NN) { v = h[n * D + j]; h_out[n * D + j] = v; }
            hs[r][j] = v;
        }
        __syncthreads();
        for (int r = g; r < 64; r += 4) cs += hs[r][j];
        for (int it = tid; it < 64 * NOD; it += 256) {
            const int r = it / NOD, c = it - r * NOD;
            const int n = n0 + r;
            if (n < NN) {
                float a = snb[c];
#pragma unroll 16
                for (int k = 0; k < D; ++k) a += hs[r][k] * snw[k * NOD + c];
                node_out[n * NOD + c] = a;
            }
        }
    }
    red[g][j] = cs;
    __syncthreads();
    if (tid < D) atomicAdd(&hsum[tid], red[0][tid] + red[1][tid] + red[2][tid] + red[3][tid]);
}

__global__ void k_graphout(const float* __restrict__ hsum, const float* __restrict__ gw,
                           const float* __restrict__ gb, float* __restrict__ out)
{
    const int j = threadIdx.x;  // 64 threads
    float v = hsum[j] * (1.f / NN) * gw[j];
#pragma unroll
    for (int off = 32; off > 0; off >>= 1) v += __shfl_down(v, off, 64);
    if (j == 0) out[0] = v + gb[0];
}

// ---------------------------------------------------------------------------
extern "C" void kernel_launch(void* const* d_in, const int* in_sizes, int n_in,
                              void* d_out, int out_size, void* d_ws, size_t ws_size,
                              hipStream_t stream)
{
    (void)in_sizes; (void)n_in; (void)out_size; (void)ws_size;
    const float* x        = (const float*)d_in[0];
    const int*   ei       = (const int*)  d_in[1];
    const float* ea       = (const float*)d_in[2];
    const float* prev_h   = (const float*)d_in[3];
    const float* lin_in_w = (const float*)d_in[4];
    const float* lin_in_b = (const float*)d_in[5];
    const float* hist_w   = (const float*)d_in[6];
    const float* hist_b   = (const float*)d_in[7];
    const float* msg_w1   = (const float*)d_in[8];
    const float* msg_b1   = (const float*)d_in[9];
    const float* msg_g1   = (const float*)d_in[10];
    const float* msg_be1  = (const float*)d_in[11];
    const float* msg_w2   = (const float*)d_in[12];
    const float* msg_b2   = (const float*)d_in[13];
    const float* msg_g2   = (const float*)d_in[14];
    const float* msg_be2  = (const float*)d_in[15];
    const float* upd_w1   = (const float*)d_in[16];
    const float* upd_b1   = (const float*)d_in[17];
    const float* upd_g1   = (const float*)d_in[18];
    const float* upd_be1  = (const float*)d_in[19];
    const float* upd_w2   = (const float*)d_in[20];
    const float* upd_b2   = (const float*)d_in[21];
    const float* upd_g2   = (const float*)d_in[22];
    const float* upd_be2  = (const float*)d_in[23];
    const float* graph_w  = (const float*)d_in[24];
    const float* graph_b  = (const float*)d_in[25];
    const float* node_w   = (const float*)d_in[26];
    const float* node_b   = (const float*)d_in[27];

    const int* src = ei;        // edge_index[0]
    const int* dst = ei + NE;   // edge_index[1]

    float* out       = (float*)d_out;
    float* graph_out = out;                  // [1]
    float* node_out  = out + 1;              // [N*NO]
    float* h_out     = out + 1 + NN * NOD;   // [N*D]

    char* ws = (char*)d_ws;
    size_t off = 0;
    ushort* y     = (ushort*)(ws + off); off += (size_t)NE * D * sizeof(ushort);  // 64 MB
    ushort* z     = y;   // aliases y: z's lifetime (upd1..upd3) disjoint from y's (msg1..aggr3)
    float*  aggr  = (float*) (ws + off); off += (size_t)NN * D * sizeof(float);   // 12.8 MB
    float*  h     = (float*) (ws + off); off += (size_t)NN * D * sizeof(float);   // 12.8 MB
    ushort* hb    = (ushort*)(ws + off); off += (size_t)NN * D * sizeof(ushort);  // 6.4 MB
    uint*   sd    = (uint*)  (ws + off); off += (size_t)NE * sizeof(uint);        // 2 MB
    uint2*  eab   = (uint2*) (ws + off); off += (size_t)NE * sizeof(uint2);       // 4 MB
    int* rowstart = (int*)   (ws + off); off += (size_t)(NN + 1) * sizeof(int);
    int* cnt      = (int*)   (ws + off); off += (size_t)NN * sizeof(int);         // reused as cursor
    int* bsum     = (int*)   (ws + off); off += (size_t)256 * sizeof(int);
    float* stats  = (float*) (ws + off); off += (size_t)(NL * 4 * 2 * D) * sizeof(float);
    float* hsum   = (float*) (ws + off); off += (size_t)D * sizeof(float);
    int* cursor   = cnt;  // cnt dead after k_scan1; k_scan3 rewrites as cursor

    hipMemsetAsync(cnt, 0, (size_t)NN * sizeof(int), stream);
    hipMemsetAsync(stats, 0, (size_t)(NL * 4 * 2 * D + D) * sizeof(float), stream);

    // edge sort (reused across all layers)
    k_hist<<<(NE + 255) / 256, 256, 0, stream>>>(dst, cnt);
    k_scan1<<<NBLK1, 256, 0, stream>>>(cnt, rowstart, bsum);
    k_scan2<<<1, 256, 0, stream>>>(bsum);
    k_scan3<<<NBLK1, 256, 0, stream>>>(rowstart, bsum, cursor);
    k_scatter<<<(NE + 255) / 256, 256, 0, stream>>>(src, dst, ea, cursor, sd, eab);

    k_input<<<512, 256, 0, stream>>>(x, prev_h, lin_in_w, lin_in_b, hist_w, hist_b, h, hb);

    for (int l = 0; l < NL; ++l) {
        float* st_m1 = stats + (l * 4 + 0) * 2 * D;
        float* st_m2 = stats + (l * 4 + 1) * 2 * D;
        float* st_u1 = stats + (l * 4 + 2) * 2 * D;
        float* st_u2 = stats + (l * 4 + 3) * 2 * D;
        k_msg1<<<1024, 256, 0, stream>>>(hb, sd, eab,
                                         msg_w1 + (size_t)l * K1 * D, msg_b1 + l * D, y, st_m1);
        k_mlp2b<<<1024, 256, 0, stream>>>(y, y,
                                          msg_w2 + (size_t)l * D * D, msg_b2 + l * D,
                                          msg_g1 + l * D, msg_be1 + l * D,
                                          st_m1, st_m2, NE, 1.f / NE);
        hipMemsetAsync(aggr, 0, (size_t)NN * D * sizeof(float), stream);
        k_aggr3<<<(NE + 63) / 64, 256, 0, stream>>>(y, rowstart, sd,
                                                    msg_g2 + l * D, msg_be2 + l * D,
                                                    st_m2, aggr);
        k_upd1<<<782, 256, 0, stream>>>(hb, aggr,
                                        upd_w1 + (size_t)l * KU * D, upd_b1 + l * D, z, st_u1);
        k_mlp2b<<<782, 256, 0, stream>>>(z, z,
                                         upd_w2 + (size_t)l * D * D, upd_b2 + l * D,
                                         upd_g1 + l * D, upd_be1 + l * D,
                                         st_u1, st_u2, NN, 1.f / NN);
        k_upd3<<<1024, 256, 0, stream>>>(z, upd_g2 + l * D, upd_be2 + l * D, st_u2, h, hb);
    }

    k_nodeout<<<782, 256, 0, stream>>>(h, node_w, node_b, node_out, h_out, hsum);
    k_graphout<<<1, 64, 0, stream>>>(hsum, graph_w, graph_b, graph_out);
}

// Round 5
// 1080.929 us; speedup vs baseline: 1.2554x; 1.0097x over previous
//
#include <hip/hip_runtime.h>
#include <hip/hip_bf16.h>

#define NN 50000
#define NE 500000
#define D 64
#define IND 11
#define EDD 4
#define NOD 5
#define NL 4
#define K1 132   // 2D + ED
#define KU 128   // 2D
#define EPSB 1e-5f

#define LDA1 168  // K-stride (bf16) for msg1 tiles: 160 used + 8 pad
#define LDA2 72   // K=64 + 8
#define LDA3 136  // K=128 + 8

#define NBLK1 196  // ceil(50000/256) scan chunks

typedef __hip_bfloat16 bf16;
typedef __attribute__((ext_vector_type(8))) __bf16 bf16x8;
typedef __attribute__((ext_vector_type(4))) float f32x4;

__device__ __forceinline__ ushort f2u(float f) {
    __hip_bfloat16 h = __float2bfloat16(f);
    return __builtin_bit_cast(ushort, h);
}
__device__ __forceinline__ float u2f(ushort u) {
    uint v = (uint)u << 16;
    return __builtin_bit_cast(float, v);
}

// ---------------------------------------------------------------------------
// Edge sort by dst: histogram -> scan -> scatter (reused by all 4 layers)
// ---------------------------------------------------------------------------
__global__ __launch_bounds__(256) void k_hist(const int* __restrict__ dst, int* __restrict__ cnt)
{
    const int e = blockIdx.x * 256 + threadIdx.x;
    if (e < NE) atomicAdd(&cnt[dst[e]], 1);
}

__global__ __launch_bounds__(256) void k_scan1(const int* __restrict__ cnt,
                                               int* __restrict__ rowstart, int* __restrict__ bsum)
{
    __shared__ int s[256];
    const int tid = threadIdx.x;
    const int i = blockIdx.x * 256 + tid;
    const int v = (i < NN) ? cnt[i] : 0;
    s[tid] = v;
    __syncthreads();
    for (int off = 1; off < 256; off <<= 1) {
        const int t = (tid >= off) ? s[tid - off] : 0;
        __syncthreads();
        s[tid] += t;
        __syncthreads();
    }
    if (i < NN) rowstart[i] = s[tid] - v;       // exclusive within chunk
    if (tid == 255) bsum[blockIdx.x] = s[255];  // chunk total
}

__global__ __launch_bounds__(256) void k_scan2(int* __restrict__ bsum)
{
    __shared__ int s[256];
    const int tid = threadIdx.x;
    const int v = (tid < NBLK1) ? bsum[tid] : 0;
    s[tid] = v;
    __syncthreads();
    for (int off = 1; off < 256; off <<= 1) {
        const int t = (tid >= off) ? s[tid - off] : 0;
        __syncthreads();
        s[tid] += t;
        __syncthreads();
    }
    if (tid < NBLK1) bsum[tid] = s[tid] - v;    // exclusive block offsets
}

__global__ __launch_bounds__(256) void k_scan3(int* __restrict__ rowstart,
                                               const int* __restrict__ bsum,
                                               int* __restrict__ cursor)
{
    const int i = blockIdx.x * 256 + threadIdx.x;
    if (i < NN) {
        const int rs = rowstart[i] + bsum[i >> 8];
        rowstart[i] = rs;
        cursor[i] = rs;
    }
    if (i == 0) rowstart[NN] = NE;
}

__global__ __launch_bounds__(256) void k_scatter(
    const int* __restrict__ src, const int* __restrict__ dst, const float* __restrict__ ea,
    int* __restrict__ cursor, uint* __restrict__ sd, uint2* __restrict__ eab)
{
    const int e = blockIdx.x * 256 + threadIdx.x;
    if (e < NE) {
        const int d = dst[e];
        const int p = atomicAdd(&cursor[d], 1);
        sd[p] = (uint)src[e] | ((uint)d << 16);   // N=50000 < 2^16: packs
        const float4 t = *(const float4*)&ea[(size_t)e * EDD];
        uint2 pk;
        pk.x = (uint)f2u(t.x) | ((uint)f2u(t.y) << 16);
        pk.y = (uint)f2u(t.z) | ((uint)f2u(t.w) << 16);
        eab[p] = pk;
    }
}

// ---------------------------------------------------------------------------
// h = relu(x @ lin_in_w + b + prev_h @ hist_w + b) ; hb = bf16(h)
// ---------------------------------------------------------------------------
__global__ __launch_bounds__(256) void k_input(
    const float* __restrict__ x, const float* __restrict__ prev_h,
    const float* __restrict__ w_in, const float* __restrict__ b_in,
    const float* __restrict__ w_h, const float* __restrict__ b_h,
    float* __restrict__ h, ushort* __restrict__ hb)
{
    __shared__ float sW1[IND * D];
    __shared__ float sW2[D * D];
    __shared__ float sb[D];
    __shared__ float sx[4][IND];
    __shared__ float sp[4][D];
    const int tid = threadIdx.x;
    for (int i = tid; i < IND * D; i += 256) sW1[i] = w_in[i];
    for (int i = tid; i < D * D; i += 256) sW2[i] = w_h[i];
    if (tid < D) sb[tid] = b_in[tid] + b_h[tid];
    const int j = tid & 63, r = tid >> 6;
    for (int n0 = blockIdx.x * 4; n0 < NN; n0 += gridDim.x * 4) {
        __syncthreads();
        const int n = n0 + r;
        if (n < NN) {
            sp[r][j] = prev_h[n * D + j];
            if (j < IND) sx[r][j] = x[n * IND + j];
        }
        __syncthreads();
        if (n < NN) {
            float acc = sb[j];
#pragma unroll
            for (int k = 0; k < IND; ++k) acc += sx[r][k] * sW1[k * D + j];
#pragma unroll 8
            for (int k = 0; k < D; ++k) acc += sp[r][k] * sW2[k * D + j];
            const float v = fmaxf(acc, 0.0f);
            h[n * D + j] = v;
            hb[n * D + j] = f2u(v);
        }
    }
}

// ---------------------------------------------------------------------------
// y[p] = cat(hb[dst], hb[src], ea) @ W + b over SORTED edges (MFMA) + stats
// Register-prefetch pipeline: sd 2 tiles ahead, payload 1 tile ahead.
// B fragments forced into VGPRs (staged via xs then xs is overwritten).
// ---------------------------------------------------------------------------
__global__ __launch_bounds__(256, 3) void k_msg1(
    const ushort* __restrict__ hb, const uint* __restrict__ sd, const uint2* __restrict__ eab,
    const float* __restrict__ W, const float* __restrict__ b,
    ushort* __restrict__ y, float* __restrict__ st)
{
    __shared__ __align__(16) ushort xs[64][LDA1];
    __shared__ float sred[4][2][64];
    const int tid = threadIdx.x;
    const int lane = tid & 63, w = tid >> 6;
    const int fn = lane & 15, quad = lane >> 4;
    const int r = tid >> 2, q = tid & 3;   // staging: row r, col-chunk q*16

    // one-time: zero K-pad cols [132..168), stage W^T into xs cols [0..132)
    for (int i = tid; i < 64 * 36; i += 256) {
        const int rr = i / 36, k = 132 + (i - rr * 36);
        xs[rr][k] = 0;
    }
    for (int i = tid; i < K1 * D; i += 256) {
        const int k = i >> 6, n = i & 63;
        xs[n][k] = f2u(W[i]);
    }
    __syncthreads();

    // B fragments to registers (xs mutates afterwards -> compiler must keep them)
    bf16x8 Bf[5][4];
#pragma unroll
    for (int s = 0; s < 5; ++s)
#pragma unroll
        for (int c = 0; c < 4; ++c)
            Bf[s][c] = *(const bf16x8*)&xs[c * 16 + fn][s * 32 + quad * 8];
    float bj[4];
#pragma unroll
    for (int c = 0; c < 4; ++c) bj[c] = b[c * 16 + fn];

    const int g = gridDim.x;
    const int ntiles = (NE + 63) >> 6;

    // preload tile t0 and sd for t0+g
    uint4 pa0 = {0,0,0,0}, pa1 = {0,0,0,0}, pb0 = {0,0,0,0}, pb1 = {0,0,0,0};
    uint2 pe = {0, 0};
    uint sdA = 0;
    int t = blockIdx.x;
    {
        const int e = t * 64 + r;
        if (e < NE) {
            const uint sdv = sd[e];
            const int si = (int)(sdv & 0xffffu), di = (int)(sdv >> 16);
            pa0 = *(const uint4*)&hb[(size_t)di * D + q * 16];
            pa1 = *(const uint4*)&hb[(size_t)di * D + q * 16 + 8];
            pb0 = *(const uint4*)&hb[(size_t)si * D + q * 16];
            pb1 = *(const uint4*)&hb[(size_t)si * D + q * 16 + 8];
            if (q == 0) pe = eab[e];
        }
        const int e2 = (t + g) * 64 + r;
        if (t + g < ntiles && e2 < NE) sdA = sd[e2];
    }

    float ps[4] = {0, 0, 0, 0}, pq[4] = {0, 0, 0, 0};

    for (; t < ntiles; t += g) {
        __syncthreads();                       // prior MFMA reads of xs done
        *(uint4*)&xs[r][q * 16]          = pa0;
        *(uint4*)&xs[r][q * 16 + 8]      = pa1;
        *(uint4*)&xs[r][64 + q * 16]     = pb0;
        *(uint4*)&xs[r][64 + q * 16 + 8] = pb1;
        if (q == 0) *(uint2*)&xs[r][128] = pe;
        __syncthreads();                       // staging visible

        // prefetch: sd for t+2g, payload for t+g (overlaps MFMA below)
        const int tn = t + g, tnn = t + 2 * g;
        uint sdB = 0;
        {
            const int e2 = tnn * 64 + r;
            if (tnn < ntiles && e2 < NE) sdB = sd[e2];
        }
        if (tn < ntiles) {
            const int e = tn * 64 + r;
            if (e < NE) {
                const int si = (int)(sdA & 0xffffu), di = (int)(sdA >> 16);
                pa0 = *(const uint4*)&hb[(size_t)di * D + q * 16];
                pa1 = *(const uint4*)&hb[(size_t)di * D + q * 16 + 8];
                pb0 = *(const uint4*)&hb[(size_t)si * D + q * 16];
                pb1 = *(const uint4*)&hb[(size_t)si * D + q * 16 + 8];
                if (q == 0) pe = eab[e];
            } else {
                const uint4 z4 = {0, 0, 0, 0};
                pa0 = z4; pa1 = z4; pb0 = z4; pb1 = z4;
                const uint2 z2 = {0, 0};
                pe = z2;
            }
        }

        f32x4 acc[4];
#pragma unroll
        for (int c = 0; c < 4; ++c) acc[c] = (f32x4){bj[c], bj[c], bj[c], bj[c]};
        const ushort* arow = xs[w * 16 + fn];
#pragma unroll
        for (int s = 0; s < 5; ++s) {
            const bf16x8 a = *(const bf16x8*)&arow[s * 32 + quad * 8];
            acc[0] = __builtin_amdgcn_mfma_f32_16x16x32_bf16(a, Bf[s][0], acc[0], 0, 0, 0);
            acc[1] = __builtin_amdgcn_mfma_f32_16x16x32_bf16(a, Bf[s][1], acc[1], 0, 0, 0);
            acc[2] = __builtin_amdgcn_mfma_f32_16x16x32_bf16(a, Bf[s][2], acc[2], 0, 0, 0);
            acc[3] = __builtin_amdgcn_mfma_f32_16x16x32_bf16(a, Bf[s][3], acc[3], 0, 0, 0);
        }
        const int row0 = t * 64 + w * 16 + quad * 4;
#pragma unroll
        for (int reg = 0; reg < 4; ++reg) {
            const int er = row0 + reg;
            if (er < NE) {
#pragma unroll
                for (int c = 0; c < 4; ++c) {
                    const ushort ub = f2u(acc[c][reg]);
                    y[(size_t)er * D + c * 16 + fn] = ub;
                    const float f = u2f(ub);
                    ps[c] += f; pq[c] += f * f;
                }
            }
        }
        sdA = sdB;
    }
    __syncthreads();
#pragma unroll
    for (int c = 0; c < 4; ++c) {
        ps[c] += __shfl_xor(ps[c], 16, 64); ps[c] += __shfl_xor(ps[c], 32, 64);
        pq[c] += __shfl_xor(pq[c], 16, 64); pq[c] += __shfl_xor(pq[c], 32, 64);
    }
    if (quad == 0) {
#pragma unroll
        for (int c = 0; c < 4; ++c) {
            sred[w][0][c * 16 + fn] = ps[c];
            sred[w][1][c * 16 + fn] = pq[c];
        }
    }
    __syncthreads();
    if (tid < 128) {
        const int col = tid & 63, which = tid >> 6;
        const float s = sred[0][which][col] + sred[1][which][col] +
                        sred[2][which][col] + sred[3][which][col];
        atomicAdd(&st[which * 64 + col], s);
    }
}

// ---------------------------------------------------------------------------
// yout = relu(BN(yin)) @ W + b  (MFMA, bf16 in/out, in-place safe) + stats
// Register-prefetch pipeline; B fragments in VGPRs.
// ---------------------------------------------------------------------------
__global__ __launch_bounds__(256, 4) void k_mlp2b(
    const ushort* __restrict__ yin, ushort* __restrict__ yout,
    const float* __restrict__ W, const float* __restrict__ b,
    const float* __restrict__ gg, const float* __restrict__ be,
    const float* __restrict__ st_in, float* __restrict__ st_out,
    const int nrows, const float inv_rows)
{
    __shared__ __align__(16) ushort xs[64][LDA2];
    __shared__ float sal[64], sbe[64];
    __shared__ float sred[4][2][64];
    const int tid = threadIdx.x;
    const int lane = tid & 63, w = tid >> 6;
    const int fn = lane & 15, quad = lane >> 4;
    const int r = tid >> 2, q = tid & 3;

    if (tid < 64) {
        const float m = st_in[tid] * inv_rows;
        const float v = st_in[64 + tid] * inv_rows - m * m;
        const float a = rsqrtf(v + EPSB) * gg[tid];
        sal[tid] = a;
        sbe[tid] = be[tid] - m * a;
    }
    for (int i = tid; i < D * D; i += 256) {
        const int k = i >> 6, n = i & 63;
        xs[n][k] = f2u(W[i]);
    }
    __syncthreads();

    bf16x8 Bf[2][4];
#pragma unroll
    for (int s = 0; s < 2; ++s)
#pragma unroll
        for (int c = 0; c < 4; ++c)
            Bf[s][c] = *(const bf16x8*)&xs[c * 16 + fn][s * 32 + quad * 8];
    float bj[4];
#pragma unroll
    for (int c = 0; c < 4; ++c) bj[c] = b[c * 16 + fn];
    float al16[16], be16[16];
#pragma unroll
    for (int i = 0; i < 16; ++i) { al16[i] = sal[q * 16 + i]; be16[i] = sbe[q * 16 + i]; }

    const int g = gridDim.x;
    const int ntiles = (nrows + 63) >> 6;

    uint4 u0 = {0,0,0,0}, u1 = {0,0,0,0};
    int t = blockIdx.x;
    {
        const int row = t * 64 + r;
        if (row < nrows) {
            u0 = *(const uint4*)&yin[(size_t)row * D + q * 16];
            u1 = *(const uint4*)&yin[(size_t)row * D + q * 16 + 8];
        }
    }

    float ps[4] = {0, 0, 0, 0}, pq[4] = {0, 0, 0, 0};

    for (; t < ntiles; t += g) {
        __syncthreads();
        const int row = t * 64 + r;
        if (row < nrows) {
            uint res0[4], res1[4];
#pragma unroll
            for (int p = 0; p < 4; ++p) {
                const uint uu = ((const uint*)&u0)[p];
                float f0 = u2f((ushort)(uu & 0xffffu));
                float f1 = u2f((ushort)(uu >> 16));
                f0 = fmaxf(fmaf(f0, al16[2 * p], be16[2 * p]), 0.f);
                f1 = fmaxf(fmaf(f1, al16[2 * p + 1], be16[2 * p + 1]), 0.f);
                res0[p] = (uint)f2u(f0) | ((uint)f2u(f1) << 16);
            }
#pragma unroll
            for (int p = 0; p < 4; ++p) {
                const uint uu = ((const uint*)&u1)[p];
                float f0 = u2f((ushort)(uu & 0xffffu));
                float f1 = u2f((ushort)(uu >> 16));
                f0 = fmaxf(fmaf(f0, al16[8 + 2 * p], be16[8 + 2 * p]), 0.f);
                f1 = fmaxf(fmaf(f1, al16[8 + 2 * p + 1], be16[8 + 2 * p + 1]), 0.f);
                res1[p] = (uint)f2u(f0) | ((uint)f2u(f1) << 16);
            }
            *(uint4*)&xs[r][q * 16] = *(uint4*)res0;
            *(uint4*)&xs[r][q * 16 + 8] = *(uint4*)res1;
        } else {
            const uint4 z4 = {0, 0, 0, 0};
            *(uint4*)&xs[r][q * 16] = z4;
            *(uint4*)&xs[r][q * 16 + 8] = z4;
        }
        __syncthreads();

        // prefetch next tile (overlaps MFMA)
        const int tn = t + g;
        if (tn < ntiles) {
            const int rown = tn * 64 + r;
            if (rown < nrows) {
                u0 = *(const uint4*)&yin[(size_t)rown * D + q * 16];
                u1 = *(const uint4*)&yin[(size_t)rown * D + q * 16 + 8];
            } else {
                const uint4 z4 = {0, 0, 0, 0};
                u0 = z4; u1 = z4;
            }
        }

        f32x4 acc[4];
#pragma unroll
        for (int c = 0; c < 4; ++c) acc[c] = (f32x4){bj[c], bj[c], bj[c], bj[c]};
        const ushort* arow = xs[w * 16 + fn];
#pragma unroll
        for (int s = 0; s < 2; ++s) {
            const bf16x8 a = *(const bf16x8*)&arow[s * 32 + quad * 8];
            acc[0] = __builtin_amdgcn_mfma_f32_16x16x32_bf16(a, Bf[s][0], acc[0], 0, 0, 0);
            acc[1] = __builtin_amdgcn_mfma_f32_16x16x32_bf16(a, Bf[s][1], acc[1], 0, 0, 0);
            acc[2] = __builtin_amdgcn_mfma_f32_16x16x32_bf16(a, Bf[s][2], acc[2], 0, 0, 0);
            acc[3] = __builtin_amdgcn_mfma_f32_16x16x32_bf16(a, Bf[s][3], acc[3], 0, 0, 0);
        }
        const int row0 = t * 64 + w * 16 + quad * 4;
#pragma unroll
        for (int reg = 0; reg < 4; ++reg) {
            const int er = row0 + reg;
            if (er < nrows) {
#pragma unroll
                for (int c = 0; c < 4; ++c) {
                    const ushort ub = f2u(acc[c][reg]);
                    yout[(size_t)er * D + c * 16 + fn] = ub;
                    const float f = u2f(ub);
                    ps[c] += f; pq[c] += f * f;
                }
            }
        }
    }
    __syncthreads();
#pragma unroll
    for (int c = 0; c < 4; ++c) {
        ps[c] += __shfl_xor(ps[c], 16, 64); ps[c] += __shfl_xor(ps[c], 32, 64);
        pq[c] += __shfl_xor(pq[c], 16, 64); pq[c] += __shfl_xor(pq[c], 32, 64);
    }
    if (quad == 0) {
#pragma unroll
        for (int c = 0; c < 4; ++c) {
            sred[w][0][c * 16 + fn] = ps[c];
            sred[w][1][c * 16 + fn] = pq[c];
        }
    }
    __syncthreads();
    if (tid < 128) {
        const int col = tid & 63, which = tid >> 6;
        const float s = sred[0][which][col] + sred[1][which][col] +
                        sred[2][which][col] + sred[3][which][col];
        atomicAdd(&st_out[which * 64 + col], s);
    }
}

// ---------------------------------------------------------------------------
// aggr (fp32, pre-zeroed) += segment sums of relu(BN2(y))
// one block per 64-edge tile of the SORTED edge list; LDS-staged; coalesced
// fp32 atomics only at node granularity (adjacent-block contention only)
// ---------------------------------------------------------------------------
__global__ __launch_bounds__(256) void k_aggr3(
    const ushort* __restrict__ y, const int* __restrict__ rowstart,
    const uint* __restrict__ sd,
    const float* __restrict__ gg, const float* __restrict__ be,
    const float* __restrict__ st, float* __restrict__ aggr)
{
    __shared__ float ys[64][68];   // stride 68: uniform 8-phase b128 LDS access
    __shared__ float sal[D], sbe[D];
    const int tid = threadIdx.x;
    if (tid < D) {
        const float m = st[tid] * (1.f / NE);
        const float v = st[D + tid] * (1.f / NE) - m * m;
        const float a = rsqrtf(v + EPSB) * gg[tid];
        sal[tid] = a;
        sbe[tid] = be[tid] - m * a;
    }
    __syncthreads();

    const int e0 = blockIdx.x << 6;
    const int e1 = min(e0 + 64, NE);

    // stage + BN + relu: thread t -> row t/4, cols (t&3)*16 .. +15
    const int r = tid >> 2, c0 = (tid & 3) << 4;
    const int e = e0 + r;
    if (e < NE) {
        const uint4 u0 = *(const uint4*)&y[(size_t)e * D + c0];
        const uint4 u1 = *(const uint4*)&y[(size_t)e * D + c0 + 8];
#pragma unroll
        for (int p = 0; p < 4; ++p) {
            const uint uu = ((const uint*)&u0)[p];
            const int cc = c0 + 2 * p;
            ys[r][cc]     = fmaxf(fmaf(u2f((ushort)(uu & 0xffffu)), sal[cc], sbe[cc]), 0.f);
            ys[r][cc + 1] = fmaxf(fmaf(u2f((ushort)(uu >> 16)), sal[cc + 1], sbe[cc + 1]), 0.f);
        }
#pragma unroll
        for (int p = 0; p < 4; ++p) {
            const uint uu = ((const uint*)&u1)[p];
            const int cc = c0 + 8 + 2 * p;
            ys[r][cc]     = fmaxf(fmaf(u2f((ushort)(uu & 0xffffu)), sal[cc], sbe[cc]), 0.f);
            ys[r][cc + 1] = fmaxf(fmaf(u2f((ushort)(uu >> 16)), sal[cc + 1], sbe[cc + 1]), 0.f);
        }
    }
    __syncthreads();

    // segment sums: wave w handles nodes n0+w, n0+w+4, ... intersecting window
    const int lane = tid & 63, w = tid >> 6;
    int n = (int)(sd[e0] >> 16) + w;   // dst of first edge in window
    while (n < NN) {
        const int rs = rowstart[n];
        if (rs >= e1) break;
        const int re = rowstart[n + 1];
        const int j0 = max(rs, e0), j1 = min(re, e1);
        if (j1 > j0) {
            float s = 0.f;
            for (int j = j0; j < j1; ++j) s += ys[j - e0][lane];
            atomicAdd(&aggr[(size_t)n * D + lane], s);
        }
        n += 4;
    }
}

// ---------------------------------------------------------------------------
// z = cat(hb, aggr_f32) @ W + b   (MFMA, bf16 staging) + stats
// ---------------------------------------------------------------------------
__global__ __launch_bounds__(256, 3) void k_upd1(
    const ushort* __restrict__ hb, const float* __restrict__ aggr,
    const float* __restrict__ W, const float* __restrict__ b,
    ushort* __restrict__ z, float* __restrict__ st)
{
    __shared__ __align__(16) ushort xs[64][LDA3];
    __shared__ float sred[4][2][64];
    const int tid = threadIdx.x;
    const int lane = tid & 63, w = tid >> 6;
    const int fn = lane & 15, quad = lane >> 4;

    for (int i = tid; i < KU * D; i += 256) {
        const int k = i >> 6, n = i & 63;
        xs[n][k] = f2u(W[i]);
    }
    __syncthreads();

    bf16x8 Bf[4][4];
#pragma unroll
    for (int s = 0; s < 4; ++s)
#pragma unroll
        for (int c = 0; c < 4; ++c)
            Bf[s][c] = *(const bf16x8*)&xs[c * 16 + fn][s * 32 + quad * 8];
    float bj[4];
#pragma unroll
    for (int c = 0; c < 4; ++c) bj[c] = b[c * 16 + fn];

    const int r = tid >> 2, q = tid & 3;
    float ps[4] = {0, 0, 0, 0}, pq[4] = {0, 0, 0, 0};
    const int ntiles = (NN + 63) >> 6;

    for (int t = blockIdx.x; t < ntiles; t += gridDim.x) {
        const int n0 = t << 6;
        __syncthreads();
        const int n = n0 + r;
        if (n < NN) {
            *(uint4*)&xs[r][q * 16]     = *(const uint4*)&hb[(size_t)n * D + q * 16];
            *(uint4*)&xs[r][q * 16 + 8] = *(const uint4*)&hb[(size_t)n * D + q * 16 + 8];
            uint out2[4], out3[4];
#pragma unroll
            for (int p = 0; p < 4; ++p) {
                const float4 av = *(const float4*)&aggr[(size_t)n * D + q * 16 + p * 4];
                ((uint*)(p < 2 ? out2 : out3))[(p & 1) * 2 + 0] =
                    (uint)f2u(av.x) | ((uint)f2u(av.y) << 16);
                ((uint*)(p < 2 ? out2 : out3))[(p & 1) * 2 + 1] =
                    (uint)f2u(av.z) | ((uint)f2u(av.w) << 16);
            }
            *(uint4*)&xs[r][64 + q * 16]     = *(uint4*)out2;
            *(uint4*)&xs[r][64 + q * 16 + 8] = *(uint4*)out3;
        } else {
            const uint4 z4 = {0, 0, 0, 0};
            *(uint4*)&xs[r][q * 16] = z4;
            *(uint4*)&xs[r][q * 16 + 8] = z4;
            *(uint4*)&xs[r][64 + q * 16] = z4;
            *(uint4*)&xs[r][64 + q * 16 + 8] = z4;
        }
        __syncthreads();

        f32x4 acc[4];
#pragma unroll
        for (int c = 0; c < 4; ++c) acc[c] = (f32x4){bj[c], bj[c], bj[c], bj[c]};
        const ushort* arow = xs[w * 16 + fn];
#pragma unroll
        for (int s = 0; s < 4; ++s) {
            const bf16x8 a = *(const bf16x8*)&arow[s * 32 + quad * 8];
            acc[0] = __builtin_amdgcn_mfma_f32_16x16x32_bf16(a, Bf[s][0], acc[0], 0, 0, 0);
            acc[1] = __builtin_amdgcn_mfma_f32_16x16x32_bf16(a, Bf[s][1], acc[1], 0, 0, 0);
            acc[2] = __builtin_amdgcn_mfma_f32_16x16x32_bf16(a, Bf[s][2], acc[2], 0, 0, 0);
            acc[3] = __builtin_amdgcn_mfma_f32_16x16x32_bf16(a, Bf[s][3], acc[3], 0, 0, 0);
        }
        const int row0 = n0 + w * 16 + quad * 4;
#pragma unroll
        for (int reg = 0; reg < 4; ++reg) {
            const int er = row0 + reg;
            if (er < NN) {
#pragma unroll
                for (int c = 0; c < 4; ++c) {
                    const ushort ub = f2u(acc[c][reg]);
                    z[(size_t)er * D + c * 16 + fn] = ub;
                    const float f = u2f(ub);
                    ps[c] += f; pq[c] += f * f;
                }
            }
        }
    }
    __syncthreads();
#pragma unroll
    for (int c = 0; c < 4; ++c) {
        ps[c] += __shfl_xor(ps[c], 16, 64); ps[c] += __shfl_xor(ps[c], 32, 64);
        pq[c] += __shfl_xor(pq[c], 16, 64); pq[c] += __shfl_xor(pq[c], 32, 64);
    }
    if (quad == 0) {
#pragma unroll
        for (int c = 0; c < 4; ++c) {
            sred[w][0][c * 16 + fn] = ps[c];
            sred[w][1][c * 16 + fn] = pq[c];
        }
    }
    __syncthreads();
    if (tid < 128) {
        const int col = tid & 63, which = tid >> 6;
        const float s = sred[0][which][col] + sred[1][which][col] +
                        sred[2][which][col] + sred[3][which][col];
        atomicAdd(&st[which * 64 + col], s);
    }
}

// ---------------------------------------------------------------------------
// h += relu(BN(z)) ; hb = bf16(h)
// ---------------------------------------------------------------------------
__global__ __launch_bounds__(256) void k_upd3(
    const ushort* __restrict__ z, const float* __restrict__ gg, const float* __restrict__ be,
    const float* __restrict__ st, float* __restrict__ h, ushort* __restrict__ hb)
{
    __shared__ float sal[D], sbe[D];
    const int tid = threadIdx.x;
    if (tid < D) {
        const float m = st[tid] * (1.f / NN);
        const float v = st[D + tid] * (1.f / NN) - m * m;
        const float a = rsqrtf(v + EPSB) * gg[tid];
        sal[tid] = a;
        sbe[tid] = be[tid] - m * a;
    }
    __syncthreads();
    const int j = tid & 63;
    const float al = sal[j], bt = sbe[j];
    for (int i = blockIdx.x * 256 + tid; i < NN * D; i += gridDim.x * 256) {
        const float v = h[i] + fmaxf(fmaf(u2f(z[i]), al, bt), 0.f);
        h[i] = v;
        hb[i] = f2u(v);
    }
}

// ---------------------------------------------------------------------------
// node_out = h @ node_w + node_b ; hsum += column sums of h ; copy h to d_out
// ---------------------------------------------------------------------------
__global__ __launch_bounds__(256) void k_nodeout(
    const float* __restrict__ h, const float* __restrict__ nw, const float* __restrict__ nb,
    float* __restrict__ node_out, float* __restrict__ h_out, float* __restrict__ hsum)
{
    __shared__ float hs[64][65];
    __shared__ float snw[D * NOD];
    __shared__ float snb[NOD];
    __shared__ float red[4][D];
    const int tid = threadIdx.x;
    for (int i = tid; i < D * NOD; i += 256) snw[i] = nw[i];
    if (tid < NOD) snb[tid] = nb[tid];
    const int j = tid & 63, g = tid >> 6;
    float cs = 0.f;
    for (int n0 = blockIdx.x * 64; n0 < NN; n0 += gridDim.x * 64) {
        __syncthreads();
        for (int r = g; r < 64; r += 4) {
            const int n = n0 + r;
            float v = 0.f;
            if (n < NN) { v = h[n * D + j]; h_out[n * D + j] = v; }
            hs[r][j] = v;
        }
        __syncthreads();
        for (int r = g; r < 64; r += 4) cs += hs[r][j];
        for (int it = tid; it < 64 * NOD; it += 256) {
            const int r = it / NOD, c = it - r * NOD;
            const int n = n0 + r;
            if (n < NN) {
                float a = snb[c];
#pragma unroll 16
                for (int k = 0; k < D; ++k) a += hs[r][k] * snw[k * NOD + c];
                node_out[n * NOD + c] = a;
            }
        }
    }
    red[g][j] = cs;
    __syncthreads();
    if (tid < D) atomicAdd(&hsum[tid], red[0][tid] + red[1][tid] + red[2][tid] + red[3][tid]);
}

__global__ void k_graphout(const float* __restrict__ hsum, const float* __restrict__ gw,
                           const float* __restrict__ gb, float* __restrict__ out)
{
    const int j = threadIdx.x;  // 64 threads
    float v = hsum[j] * (1.f / NN) * gw[j];
#pragma unroll
    for (int off = 32; off > 0; off >>= 1) v += __shfl_down(v, off, 64);
    if (j == 0) out[0] = v + gb[0];
}

// ---------------------------------------------------------------------------
extern "C" void kernel_launch(void* const* d_in, const int* in_sizes, int n_in,
                              void* d_out, int out_size, void* d_ws, size_t ws_size,
                              hipStream_t stream)
{
    (void)in_sizes; (void)n_in; (void)out_size; (void)ws_size;
    const float* x        = (const float*)d_in[0];
    const int*   ei       = (const int*)  d_in[1];
    const float* ea       = (const float*)d_in[2];
    const float* prev_h   = (const float*)d_in[3];
    const float* lin_in_w = (const float*)d_in[4];
    const float* lin_in_b = (const float*)d_in[5];
    const float* hist_w   = (const float*)d_in[6];
    const float* hist_b   = (const float*)d_in[7];
    const float* msg_w1   = (const float*)d_in[8];
    const float* msg_b1   = (const float*)d_in[9];
    const float* msg_g1   = (const float*)d_in[10];
    const float* msg_be1  = (const float*)d_in[11];
    const float* msg_w2   = (const float*)d_in[12];
    const float* msg_b2   = (const float*)d_in[13];
    const float* msg_g2   = (const float*)d_in[14];
    const float* msg_be2  = (const float*)d_in[15];
    const float* upd_w1   = (const float*)d_in[16];
    const float* upd_b1   = (const float*)d_in[17];
    const float* upd_g1   = (const float*)d_in[18];
    const float* upd_be1  = (const float*)d_in[19];
    const float* upd_w2   = (const float*)d_in[20];
    const float* upd_b2   = (const float*)d_in[21];
    const float* upd_g2   = (const float*)d_in[22];
    const float* upd_be2  = (const float*)d_in[23];
    const float* graph_w  = (const float*)d_in[24];
    const float* graph_b  = (const float*)d_in[25];
    const float* node_w   = (const float*)d_in[26];
    const float* node_b   = (const float*)d_in[27];

    const int* src = ei;        // edge_index[0]
    const int* dst = ei + NE;   // edge_index[1]

    float* out       = (float*)d_out;
    float* graph_out = out;                  // [1]
    float* node_out  = out + 1;              // [N*NO]
    float* h_out     = out + 1 + NN * NOD;   // [N*D]

    char* ws = (char*)d_ws;
    size_t off = 0;
    ushort* y     = (ushort*)(ws + off); off += (size_t)NE * D * sizeof(ushort);  // 64 MB
    ushort* z     = y;   // aliases y: z's lifetime (upd1..upd3) disjoint from y's (msg1..aggr3)
    float*  aggr  = (float*) (ws + off); off += (size_t)NN * D * sizeof(float);   // 12.8 MB
    float*  h     = (float*) (ws + off); off += (size_t)NN * D * sizeof(float);   // 12.8 MB
    ushort* hb    = (ushort*)(ws + off); off += (size_t)NN * D * sizeof(ushort);  // 6.4 MB
    uint*   sd    = (uint*)  (ws + off); off += (size_t)NE * sizeof(uint);        // 2 MB
    uint2*  eab   = (uint2*) (ws + off); off += (size_t)NE * sizeof(uint2);       // 4 MB
    int* rowstart = (int*)   (ws + off); off += (size_t)(NN + 1) * sizeof(int);
    int* cnt      = (int*)   (ws + off); off += (size_t)NN * sizeof(int);         // reused as cursor
    int* bsum     = (int*)   (ws + off); off += (size_t)256 * sizeof(int);
    float* stats  = (float*) (ws + off); off += (size_t)(NL * 4 * 2 * D) * sizeof(float);
    float* hsum   = (float*) (ws + off); off += (size_t)D * sizeof(float);
    int* cursor   = cnt;  // cnt dead after k_scan1; k_scan3 rewrites as cursor

    hipMemsetAsync(cnt, 0, (size_t)NN * sizeof(int), stream);
    hipMemsetAsync(stats, 0, (size_t)(NL * 4 * 2 * D + D) * sizeof(float), stream);

    // edge sort (reused across all layers)
    k_hist<<<(NE + 255) / 256, 256, 0, stream>>>(dst, cnt);
    k_scan1<<<NBLK1, 256, 0, stream>>>(cnt, rowstart, bsum);
    k_scan2<<<1, 256, 0, stream>>>(bsum);
    k_scan3<<<NBLK1, 256, 0, stream>>>(rowstart, bsum, cursor);
    k_scatter<<<(NE + 255) / 256, 256, 0, stream>>>(src, dst, ea, cursor, sd, eab);

    k_input<<<512, 256, 0, stream>>>(x, prev_h, lin_in_w, lin_in_b, hist_w, hist_b, h, hb);

    for (int l = 0; l < NL; ++l) {
        float* st_m1 = stats + (l * 4 + 0) * 2 * D;
        float* st_m2 = stats + (l * 4 + 1) * 2 * D;
        float* st_u1 = stats + (l * 4 + 2) * 2 * D;
        float* st_u2 = stats + (l * 4 + 3) * 2 * D;
        k_msg1<<<768, 256, 0, stream>>>(hb, sd, eab,
                                        msg_w1 + (size_t)l * K1 * D, msg_b1 + l * D, y, st_m1);
        k_mlp2b<<<1024, 256, 0, stream>>>(y, y,
                                          msg_w2 + (size_t)l * D * D, msg_b2 + l * D,
                                          msg_g1 + l * D, msg_be1 + l * D,
                                          st_m1, st_m2, NE, 1.f / NE);
        hipMemsetAsync(aggr, 0, (size_t)NN * D * sizeof(float), stream);
        k_aggr3<<<(NE + 63) / 64, 256, 0, stream>>>(y, rowstart, sd,
                                                    msg_g2 + l * D, msg_be2 + l * D,
                                                    st_m2, aggr);
        k_upd1<<<782, 256, 0, stream>>>(hb, aggr,
                                        upd_w1 + (size_t)l * KU * D, upd_b1 + l * D, z, st_u1);
        k_mlp2b<<<782, 256, 0, stream>>>(z, z,
                                         upd_w2 + (size_t)l * D * D, upd_b2 + l * D,
                                         upd_g1 + l * D, upd_be1 + l * D,
                                         st_u1, st_u2, NN, 1.f / NN);
        k_upd3<<<1024, 256, 0, stream>>>(z, upd_g2 + l * D, upd_be2 + l * D, st_u2, h, hb);
    }

    k_nodeout<<<782, 256, 0, stream>>>(h, node_w, node_b, node_out, h_out, hsum);
    k_graphout<<<1, 64, 0, stream>>>(hsum, graph_w, graph_b, graph_out);
}

// Round 6
// 1078.808 us; speedup vs baseline: 1.2578x; 1.0020x over previous
//
#include <hip/hip_runtime.h>
#include <hip/hip_bf16.h>

#define NN 50000
#define NE 500000
#define D 64
#define IND 11
#define EDD 4
#define NOD 5
#define NL 4
#define K1 132   // 2D + ED
#define KU 128   // 2D
#define EPSB 1e-5f

#define NBLK1 196  // ceil(50000/256) scan chunks

typedef __hip_bfloat16 bf16;
typedef __attribute__((ext_vector_type(8))) __bf16 bf16x8;
typedef __attribute__((ext_vector_type(4))) float f32x4;

__device__ __forceinline__ ushort f2u(float f) {
    __hip_bfloat16 h = __float2bfloat16(f);
    return __builtin_bit_cast(ushort, h);
}
__device__ __forceinline__ float u2f(ushort u) {
    uint v = (uint)u << 16;
    return __builtin_bit_cast(float, v);
}
// BN+relu two packed bf16 -> packed bf16
__device__ __forceinline__ uint bnpack(uint uu, float a0, float b0, float a1, float b1) {
    const float f0 = fmaxf(fmaf(u2f((ushort)(uu & 0xffffu)), a0, b0), 0.f);
    const float f1 = fmaxf(fmaf(u2f((ushort)(uu >> 16)), a1, b1), 0.f);
    return (uint)f2u(f0) | ((uint)f2u(f1) << 16);
}
__device__ __forceinline__ bf16x8 packf8(float4 lo, float4 hi) {
    uint4 u;
    u.x = (uint)f2u(lo.x) | ((uint)f2u(lo.y) << 16);
    u.y = (uint)f2u(lo.z) | ((uint)f2u(lo.w) << 16);
    u.z = (uint)f2u(hi.x) | ((uint)f2u(hi.y) << 16);
    u.w = (uint)f2u(hi.z) | ((uint)f2u(hi.w) << 16);
    return __builtin_bit_cast(bf16x8, u);
}

// ---------------------------------------------------------------------------
// Edge sort by dst: histogram -> scan -> scatter (reused by all 4 layers)
// ---------------------------------------------------------------------------
__global__ __launch_bounds__(256) void k_hist(const int* __restrict__ dst, int* __restrict__ cnt)
{
    const int e = blockIdx.x * 256 + threadIdx.x;
    if (e < NE) atomicAdd(&cnt[dst[e]], 1);
}

__global__ __launch_bounds__(256) void k_scan1(const int* __restrict__ cnt,
                                               int* __restrict__ rowstart, int* __restrict__ bsum)
{
    __shared__ int s[256];
    const int tid = threadIdx.x;
    const int i = blockIdx.x * 256 + tid;
    const int v = (i < NN) ? cnt[i] : 0;
    s[tid] = v;
    __syncthreads();
    for (int off = 1; off < 256; off <<= 1) {
        const int t = (tid >= off) ? s[tid - off] : 0;
        __syncthreads();
        s[tid] += t;
        __syncthreads();
    }
    if (i < NN) rowstart[i] = s[tid] - v;
    if (tid == 255) bsum[blockIdx.x] = s[255];
}

__global__ __launch_bounds__(256) void k_scan2(int* __restrict__ bsum)
{
    __shared__ int s[256];
    const int tid = threadIdx.x;
    const int v = (tid < NBLK1) ? bsum[tid] : 0;
    s[tid] = v;
    __syncthreads();
    for (int off = 1; off < 256; off <<= 1) {
        const int t = (tid >= off) ? s[tid - off] : 0;
        __syncthreads();
        s[tid] += t;
        __syncthreads();
    }
    if (tid < NBLK1) bsum[tid] = s[tid] - v;
}

__global__ __launch_bounds__(256) void k_scan3(int* __restrict__ rowstart,
                                               const int* __restrict__ bsum,
                                               int* __restrict__ cursor)
{
    const int i = blockIdx.x * 256 + threadIdx.x;
    if (i < NN) {
        const int rs = rowstart[i] + bsum[i >> 8];
        rowstart[i] = rs;
        cursor[i] = rs;
    }
    if (i == 0) rowstart[NN] = NE;
}

__global__ __launch_bounds__(256) void k_scatter(
    const int* __restrict__ src, const int* __restrict__ dst, const float* __restrict__ ea,
    int* __restrict__ cursor, uint* __restrict__ sd, uint2* __restrict__ eab)
{
    const int e = blockIdx.x * 256 + threadIdx.x;
    if (e < NE) {
        const int d = dst[e];
        const int p = atomicAdd(&cursor[d], 1);
        sd[p] = (uint)src[e] | ((uint)d << 16);   // N=50000 < 2^16: packs
        const float4 t = *(const float4*)&ea[(size_t)e * EDD];
        uint2 pk;
        pk.x = (uint)f2u(t.x) | ((uint)f2u(t.y) << 16);
        pk.y = (uint)f2u(t.z) | ((uint)f2u(t.w) << 16);
        eab[p] = pk;
    }
}

// ---------------------------------------------------------------------------
// h = relu(x @ lin_in_w + b + prev_h @ hist_w + b) ; hb = bf16(h)
// ---------------------------------------------------------------------------
__global__ __launch_bounds__(256) void k_input(
    const float* __restrict__ x, const float* __restrict__ prev_h,
    const float* __restrict__ w_in, const float* __restrict__ b_in,
    const float* __restrict__ w_h, const float* __restrict__ b_h,
    float* __restrict__ h, ushort* __restrict__ hb)
{
    __shared__ float sW1[IND * D];
    __shared__ float sW2[D * D];
    __shared__ float sb[D];
    __shared__ float sx[4][IND];
    __shared__ float sp[4][D];
    const int tid = threadIdx.x;
    for (int i = tid; i < IND * D; i += 256) sW1[i] = w_in[i];
    for (int i = tid; i < D * D; i += 256) sW2[i] = w_h[i];
    if (tid < D) sb[tid] = b_in[tid] + b_h[tid];
    const int j = tid & 63, r = tid >> 6;
    for (int n0 = blockIdx.x * 4; n0 < NN; n0 += gridDim.x * 4) {
        __syncthreads();
        const int n = n0 + r;
        if (n < NN) {
            sp[r][j] = prev_h[n * D + j];
            if (j < IND) sx[r][j] = x[n * IND + j];
        }
        __syncthreads();
        if (n < NN) {
            float acc = sb[j];
#pragma unroll
            for (int k = 0; k < IND; ++k) acc += sx[r][k] * sW1[k * D + j];
#pragma unroll 8
            for (int k = 0; k < D; ++k) acc += sp[r][k] * sW2[k * D + j];
            const float v = fmaxf(acc, 0.0f);
            h[n * D + j] = v;
            hb[n * D + j] = f2u(v);
        }
    }
}

// ---------------------------------------------------------------------------
// y = cat(hb[dst], hb[src], ea) @ W + b  — BARRIER-FREE per-wave MFMA.
// Each wave owns groups of 16 sorted edges; A-fragments loaded b128 straight
// from global (lane fn=edge, quad=k-chunk); B-fragments register-resident.
// ---------------------------------------------------------------------------
__global__ __launch_bounds__(256, 3) void k_msg1(
    const ushort* __restrict__ hb, const uint* __restrict__ sd, const uint2* __restrict__ eab,
    const float* __restrict__ W, const float* __restrict__ b,
    ushort* __restrict__ y, float* __restrict__ st)
{
    __shared__ __align__(16) ushort wst[64][160];
    __shared__ float sred[4][2][64];
    const int tid = threadIdx.x;
    const int lane = tid & 63, w = tid >> 6;
    const int fn = lane & 15, quad = lane >> 4;

    // stage W^T (K padded 132->160 with zeros)
    for (int i = tid; i < 64 * 160; i += 256) ((ushort*)wst)[i] = 0;
    __syncthreads();
    for (int i = tid; i < K1 * D; i += 256) {
        const int k = i >> 6, n = i & 63;
        wst[n][k] = f2u(W[i]);
    }
    __syncthreads();
    bf16x8 Bf[5][4];
#pragma unroll
    for (int s = 0; s < 5; ++s)
#pragma unroll
        for (int c = 0; c < 4; ++c)
            Bf[s][c] = *(const bf16x8*)&wst[c * 16 + fn][s * 32 + quad * 8];
    float bj[4];
#pragma unroll
    for (int c = 0; c < 4; ++c) bj[c] = b[c * 16 + fn];
    __syncthreads();

    const int ngroups = NE / 16;           // 31250, exact
    const int nw = gridDim.x * 4;
    int g = blockIdx.x * 4 + w;

    const int gc0 = min(g, ngroups - 1);
    uint sdc = sd[gc0 * 16 + fn];
    uint sdn = sd[min(g + nw, ngroups - 1) * 16 + fn];
    bf16x8 f0, f1, f2, f3;
    uint2 pe;
    {
        const int di = (int)(sdc >> 16), si = (int)(sdc & 0xffffu);
        f0 = *(const bf16x8*)&hb[(size_t)di * D + quad * 8];
        f1 = *(const bf16x8*)&hb[(size_t)di * D + 32 + quad * 8];
        f2 = *(const bf16x8*)&hb[(size_t)si * D + quad * 8];
        f3 = *(const bf16x8*)&hb[(size_t)si * D + 32 + quad * 8];
        pe = eab[gc0 * 16 + fn];
    }

    float ps[4] = {0, 0, 0, 0}, pq[4] = {0, 0, 0, 0};

    for (; g < ngroups; g += nw) {
        // in-loop LDS clobber: forces Bf to stay in VGPRs (no LDS re-reads)
        ((ushort*)wst)[lane] = (ushort)g;

        const int gn = g + nw;
        const int gnc = min(gn, ngroups - 1);
        // prefetch next group's fragments (overlaps MFMA below)
        bf16x8 n0, n1, n2, n3;
        uint2 pen;
        {
            const int di = (int)(sdn >> 16), si = (int)(sdn & 0xffffu);
            n0 = *(const bf16x8*)&hb[(size_t)di * D + quad * 8];
            n1 = *(const bf16x8*)&hb[(size_t)di * D + 32 + quad * 8];
            n2 = *(const bf16x8*)&hb[(size_t)si * D + quad * 8];
            n3 = *(const bf16x8*)&hb[(size_t)si * D + 32 + quad * 8];
            pen = eab[gnc * 16 + fn];
        }
        const uint sdn2 = sd[min(gn + nw, ngroups - 1) * 16 + fn];

        // ea fragment: k=128..135 live on quad 0 only (rest zero-padded)
        uint4 a4u;
        a4u.x = (quad == 0) ? pe.x : 0u;
        a4u.y = (quad == 0) ? pe.y : 0u;
        a4u.z = 0u; a4u.w = 0u;
        const bf16x8 a4 = __builtin_bit_cast(bf16x8, a4u);

        f32x4 acc[4];
#pragma unroll
        for (int c = 0; c < 4; ++c) acc[c] = (f32x4){bj[c], bj[c], bj[c], bj[c]};
#pragma unroll
        for (int c = 0; c < 4; ++c) acc[c] = __builtin_amdgcn_mfma_f32_16x16x32_bf16(f0, Bf[0][c], acc[c], 0, 0, 0);
#pragma unroll
        for (int c = 0; c < 4; ++c) acc[c] = __builtin_amdgcn_mfma_f32_16x16x32_bf16(f1, Bf[1][c], acc[c], 0, 0, 0);
#pragma unroll
        for (int c = 0; c < 4; ++c) acc[c] = __builtin_amdgcn_mfma_f32_16x16x32_bf16(f2, Bf[2][c], acc[c], 0, 0, 0);
#pragma unroll
        for (int c = 0; c < 4; ++c) acc[c] = __builtin_amdgcn_mfma_f32_16x16x32_bf16(f3, Bf[3][c], acc[c], 0, 0, 0);
#pragma unroll
        for (int c = 0; c < 4; ++c) acc[c] = __builtin_amdgcn_mfma_f32_16x16x32_bf16(a4, Bf[4][c], acc[c], 0, 0, 0);

        const int row0 = g * 16 + quad * 4;
#pragma unroll
        for (int reg = 0; reg < 4; ++reg) {
#pragma unroll
            for (int c = 0; c < 4; ++c) {
                const ushort ub = f2u(acc[c][reg]);
                y[(size_t)(row0 + reg) * D + c * 16 + fn] = ub;
                const float f = u2f(ub);
                ps[c] += f; pq[c] += f * f;
            }
        }
        f0 = n0; f1 = n1; f2 = n2; f3 = n3; pe = pen; sdn = sdn2;
    }
    __syncthreads();
#pragma unroll
    for (int c = 0; c < 4; ++c) {
        ps[c] += __shfl_xor(ps[c], 16, 64); ps[c] += __shfl_xor(ps[c], 32, 64);
        pq[c] += __shfl_xor(pq[c], 16, 64); pq[c] += __shfl_xor(pq[c], 32, 64);
    }
    if (quad == 0) {
#pragma unroll
        for (int c = 0; c < 4; ++c) {
            sred[w][0][c * 16 + fn] = ps[c];
            sred[w][1][c * 16 + fn] = pq[c];
        }
    }
    __syncthreads();
    if (tid < 128) {
        const int col = tid & 63, which = tid >> 6;
        const float s = sred[0][which][col] + sred[1][which][col] +
                        sred[2][which][col] + sred[3][which][col];
        atomicAdd(&st[which * 64 + col], s);
    }
}

// ---------------------------------------------------------------------------
// yout = relu(BN(yin)) @ W + b — BARRIER-FREE per-wave MFMA (in-place safe:
// each wave reads exactly the rows it overwrites, after the read).
// ---------------------------------------------------------------------------
__global__ __launch_bounds__(256, 4) void k_mlp2b(
    const ushort* __restrict__ yin, ushort* __restrict__ yout,
    const float* __restrict__ W, const float* __restrict__ b,
    const float* __restrict__ gg, const float* __restrict__ be,
    const float* __restrict__ st_in, float* __restrict__ st_out,
    const int nrows, const float inv_rows)
{
    __shared__ __align__(16) ushort wst[64][64];
    __shared__ float sal[64], sbe[64];
    __shared__ float sred[4][2][64];
    const int tid = threadIdx.x;
    const int lane = tid & 63, w = tid >> 6;
    const int fn = lane & 15, quad = lane >> 4;

    if (tid < 64) {
        const float m = st_in[tid] * inv_rows;
        const float v = st_in[64 + tid] * inv_rows - m * m;
        const float a = rsqrtf(v + EPSB) * gg[tid];
        sal[tid] = a;
        sbe[tid] = be[tid] - m * a;
    }
    for (int i = tid; i < D * D; i += 256) {
        const int k = i >> 6, n = i & 63;
        wst[n][k] = f2u(W[i]);
    }
    __syncthreads();

    bf16x8 Bf[2][4];
#pragma unroll
    for (int s = 0; s < 2; ++s)
#pragma unroll
        for (int c = 0; c < 4; ++c)
            Bf[s][c] = *(const bf16x8*)&wst[c * 16 + fn][s * 32 + quad * 8];
    float bj[4];
#pragma unroll
    for (int c = 0; c < 4; ++c) bj[c] = b[c * 16 + fn];
    // per-lane BN coefficients: channel = (i>>3)*32 + quad*8 + (i&7)
    float al[16], bt[16];
#pragma unroll
    for (int i = 0; i < 16; ++i) {
        const int ch = (i >> 3) * 32 + quad * 8 + (i & 7);
        al[i] = sal[ch]; bt[i] = sbe[ch];
    }
    __syncthreads();

    const int ngroups = nrows / 16;        // NE/16=31250, NN/16=3125: exact
    const int nw = gridDim.x * 4;
    int g = blockIdx.x * 4 + w;

    size_t base = ((size_t)(min(g, ngroups - 1) * 16 + fn)) * D + quad * 8;
    uint4 u0 = *(const uint4*)&yin[base];
    uint4 u1 = *(const uint4*)&yin[base + 32];

    float ps[4] = {0, 0, 0, 0}, pq[4] = {0, 0, 0, 0};

    for (; g < ngroups; g += nw) {
        ((ushort*)wst)[lane] = (ushort)g;   // force Bf register residency

        const int gn = g + nw;
        const size_t nbase = ((size_t)(min(gn, ngroups - 1) * 16 + fn)) * D + quad * 8;
        const uint4 v0 = *(const uint4*)&yin[nbase];
        const uint4 v1 = *(const uint4*)&yin[nbase + 32];

        uint4 p0, p1;
        p0.x = bnpack(u0.x, al[0], bt[0], al[1], bt[1]);
        p0.y = bnpack(u0.y, al[2], bt[2], al[3], bt[3]);
        p0.z = bnpack(u0.z, al[4], bt[4], al[5], bt[5]);
        p0.w = bnpack(u0.w, al[6], bt[6], al[7], bt[7]);
        p1.x = bnpack(u1.x, al[8], bt[8], al[9], bt[9]);
        p1.y = bnpack(u1.y, al[10], bt[10], al[11], bt[11]);
        p1.z = bnpack(u1.z, al[12], bt[12], al[13], bt[13]);
        p1.w = bnpack(u1.w, al[14], bt[14], al[15], bt[15]);
        const bf16x8 a0 = __builtin_bit_cast(bf16x8, p0);
        const bf16x8 a1 = __builtin_bit_cast(bf16x8, p1);

        f32x4 acc[4];
#pragma unroll
        for (int c = 0; c < 4; ++c) acc[c] = (f32x4){bj[c], bj[c], bj[c], bj[c]};
#pragma unroll
        for (int c = 0; c < 4; ++c) acc[c] = __builtin_amdgcn_mfma_f32_16x16x32_bf16(a0, Bf[0][c], acc[c], 0, 0, 0);
#pragma unroll
        for (int c = 0; c < 4; ++c) acc[c] = __builtin_amdgcn_mfma_f32_16x16x32_bf16(a1, Bf[1][c], acc[c], 0, 0, 0);

        const int row0 = g * 16 + quad * 4;
#pragma unroll
        for (int reg = 0; reg < 4; ++reg) {
#pragma unroll
            for (int c = 0; c < 4; ++c) {
                const ushort ub = f2u(acc[c][reg]);
                yout[(size_t)(row0 + reg) * D + c * 16 + fn] = ub;
                const float f = u2f(ub);
                ps[c] += f; pq[c] += f * f;
            }
        }
        u0 = v0; u1 = v1;
    }
    __syncthreads();
#pragma unroll
    for (int c = 0; c < 4; ++c) {
        ps[c] += __shfl_xor(ps[c], 16, 64); ps[c] += __shfl_xor(ps[c], 32, 64);
        pq[c] += __shfl_xor(pq[c], 16, 64); pq[c] += __shfl_xor(pq[c], 32, 64);
    }
    if (quad == 0) {
#pragma unroll
        for (int c = 0; c < 4; ++c) {
            sred[w][0][c * 16 + fn] = ps[c];
            sred[w][1][c * 16 + fn] = pq[c];
        }
    }
    __syncthreads();
    if (tid < 128) {
        const int col = tid & 63, which = tid >> 6;
        const float s = sred[0][which][col] + sred[1][which][col] +
                        sred[2][which][col] + sred[3][which][col];
        atomicAdd(&st_out[which * 64 + col], s);
    }
}

// ---------------------------------------------------------------------------
// aggr (fp32, pre-zeroed) += segment sums of relu(BN2(y))  (unchanged)
// ---------------------------------------------------------------------------
__global__ __launch_bounds__(256) void k_aggr3(
    const ushort* __restrict__ y, const int* __restrict__ rowstart,
    const uint* __restrict__ sd,
    const float* __restrict__ gg, const float* __restrict__ be,
    const float* __restrict__ st, float* __restrict__ aggr)
{
    __shared__ float ys[64][68];
    __shared__ float sal[D], sbe[D];
    const int tid = threadIdx.x;
    if (tid < D) {
        const float m = st[tid] * (1.f / NE);
        const float v = st[D + tid] * (1.f / NE) - m * m;
        const float a = rsqrtf(v + EPSB) * gg[tid];
        sal[tid] = a;
        sbe[tid] = be[tid] - m * a;
    }
    __syncthreads();

    const int e0 = blockIdx.x << 6;
    const int e1 = min(e0 + 64, NE);

    const int r = tid >> 2, c0 = (tid & 3) << 4;
    const int e = e0 + r;
    if (e < NE) {
        const uint4 u0 = *(const uint4*)&y[(size_t)e * D + c0];
        const uint4 u1 = *(const uint4*)&y[(size_t)e * D + c0 + 8];
#pragma unroll
        for (int p = 0; p < 4; ++p) {
            const uint uu = ((const uint*)&u0)[p];
            const int cc = c0 + 2 * p;
            ys[r][cc]     = fmaxf(fmaf(u2f((ushort)(uu & 0xffffu)), sal[cc], sbe[cc]), 0.f);
            ys[r][cc + 1] = fmaxf(fmaf(u2f((ushort)(uu >> 16)), sal[cc + 1], sbe[cc + 1]), 0.f);
        }
#pragma unroll
        for (int p = 0; p < 4; ++p) {
            const uint uu = ((const uint*)&u1)[p];
            const int cc = c0 + 8 + 2 * p;
            ys[r][cc]     = fmaxf(fmaf(u2f((ushort)(uu & 0xffffu)), sal[cc], sbe[cc]), 0.f);
            ys[r][cc + 1] = fmaxf(fmaf(u2f((ushort)(uu >> 16)), sal[cc + 1], sbe[cc + 1]), 0.f);
        }
    }
    __syncthreads();

    const int lane = tid & 63, w = tid >> 6;
    int n = (int)(sd[e0] >> 16) + w;
    while (n < NN) {
        const int rs = rowstart[n];
        if (rs >= e1) break;
        const int re = rowstart[n + 1];
        const int j0 = max(rs, e0), j1 = min(re, e1);
        if (j1 > j0) {
            float s = 0.f;
            for (int j = j0; j < j1; ++j) s += ys[j - e0][lane];
            atomicAdd(&aggr[(size_t)n * D + lane], s);
        }
        n += 4;
    }
}

// ---------------------------------------------------------------------------
// z = cat(hb, aggr_f32) @ W + b — BARRIER-FREE per-wave MFMA
// ---------------------------------------------------------------------------
__global__ __launch_bounds__(256, 3) void k_upd1(
    const ushort* __restrict__ hb, const float* __restrict__ aggr,
    const float* __restrict__ W, const float* __restrict__ b,
    ushort* __restrict__ z, float* __restrict__ st)
{
    __shared__ __align__(16) ushort wst[64][128];
    __shared__ float sred[4][2][64];
    const int tid = threadIdx.x;
    const int lane = tid & 63, w = tid >> 6;
    const int fn = lane & 15, quad = lane >> 4;

    for (int i = tid; i < KU * D; i += 256) {
        const int k = i >> 6, n = i & 63;
        wst[n][k] = f2u(W[i]);
    }
    __syncthreads();
    bf16x8 Bf[4][4];
#pragma unroll
    for (int s = 0; s < 4; ++s)
#pragma unroll
        for (int c = 0; c < 4; ++c)
            Bf[s][c] = *(const bf16x8*)&wst[c * 16 + fn][s * 32 + quad * 8];
    float bj[4];
#pragma unroll
    for (int c = 0; c < 4; ++c) bj[c] = b[c * 16 + fn];
    __syncthreads();

    const int ngroups = NN / 16;           // 3125, exact
    const int nw = gridDim.x * 4;
    int g = blockIdx.x * 4 + w;

    size_t hbase = ((size_t)(min(g, ngroups - 1) * 16 + fn)) * D + quad * 8;
    bf16x8 h0 = *(const bf16x8*)&hb[hbase];
    bf16x8 h1 = *(const bf16x8*)&hb[hbase + 32];
    float4 q0 = *(const float4*)&aggr[hbase];
    float4 q1 = *(const float4*)&aggr[hbase + 4];
    float4 q2 = *(const float4*)&aggr[hbase + 32];
    float4 q3 = *(const float4*)&aggr[hbase + 36];

    float ps[4] = {0, 0, 0, 0}, pq[4] = {0, 0, 0, 0};

    for (; g < ngroups; g += nw) {
        ((ushort*)wst)[lane] = (ushort)g;   // force Bf register residency

        const int gn = g + nw;
        const size_t nb = ((size_t)(min(gn, ngroups - 1) * 16 + fn)) * D + quad * 8;
        const bf16x8 m0 = *(const bf16x8*)&hb[nb];
        const bf16x8 m1 = *(const bf16x8*)&hb[nb + 32];
        const float4 r0 = *(const float4*)&aggr[nb];
        const float4 r1 = *(const float4*)&aggr[nb + 4];
        const float4 r2 = *(const float4*)&aggr[nb + 32];
        const float4 r3 = *(const float4*)&aggr[nb + 36];

        const bf16x8 a2 = packf8(q0, q1);
        const bf16x8 a3 = packf8(q2, q3);

        f32x4 acc[4];
#pragma unroll
        for (int c = 0; c < 4; ++c) acc[c] = (f32x4){bj[c], bj[c], bj[c], bj[c]};
#pragma unroll
        for (int c = 0; c < 4; ++c) acc[c] = __builtin_amdgcn_mfma_f32_16x16x32_bf16(h0, Bf[0][c], acc[c], 0, 0, 0);
#pragma unroll
        for (int c = 0; c < 4; ++c) acc[c] = __builtin_amdgcn_mfma_f32_16x16x32_bf16(h1, Bf[1][c], acc[c], 0, 0, 0);
#pragma unroll
        for (int c = 0; c < 4; ++c) acc[c] = __builtin_amdgcn_mfma_f32_16x16x32_bf16(a2, Bf[2][c], acc[c], 0, 0, 0);
#pragma unroll
        for (int c = 0; c < 4; ++c) acc[c] = __builtin_amdgcn_mfma_f32_16x16x32_bf16(a3, Bf[3][c], acc[c], 0, 0, 0);

        const int row0 = g * 16 + quad * 4;
#pragma unroll
        for (int reg = 0; reg < 4; ++reg) {
#pragma unroll
            for (int c = 0; c < 4; ++c) {
                const ushort ub = f2u(acc[c][reg]);
                z[(size_t)(row0 + reg) * D + c * 16 + fn] = ub;
                const float f = u2f(ub);
                ps[c] += f; pq[c] += f * f;
            }
        }
        h0 = m0; h1 = m1; q0 = r0; q1 = r1; q2 = r2; q3 = r3;
    }
    __syncthreads();
#pragma unroll
    for (int c = 0; c < 4; ++c) {
        ps[c] += __shfl_xor(ps[c], 16, 64); ps[c] += __shfl_xor(ps[c], 32, 64);
        pq[c] += __shfl_xor(pq[c], 16, 64); pq[c] += __shfl_xor(pq[c], 32, 64);
    }
    if (quad == 0) {
#pragma unroll
        for (int c = 0; c < 4; ++c) {
            sred[w][0][c * 16 + fn] = ps[c];
            sred[w][1][c * 16 + fn] = pq[c];
        }
    }
    __syncthreads();
    if (tid < 128) {
        const int col = tid & 63, which = tid >> 6;
        const float s = sred[0][which][col] + sred[1][which][col] +
                        sred[2][which][col] + sred[3][which][col];
        atomicAdd(&st[which * 64 + col], s);
    }
}

// ---------------------------------------------------------------------------
// h += relu(BN(z)) ; hb = bf16(h)
// ---------------------------------------------------------------------------
__global__ __launch_bounds__(256) void k_upd3(
    const ushort* __restrict__ z, const float* __restrict__ gg, const float* __restrict__ be,
    const float* __restrict__ st, float* __restrict__ h, ushort* __restrict__ hb)
{
    __shared__ float sal[D], sbe[D];
    const int tid = threadIdx.x;
    if (tid < D) {
        const float m = st[tid] * (1.f / NN);
        const float v = st[D + tid] * (1.f / NN) - m * m;
        const float a = rsqrtf(v + EPSB) * gg[tid];
        sal[tid] = a;
        sbe[tid] = be[tid] - m * a;
    }
    __syncthreads();
    const int j = tid & 63;
    const float al = sal[j], bt = sbe[j];
    for (int i = blockIdx.x * 256 + tid; i < NN * D; i += gridDim.x * 256) {
        const float v = h[i] + fmaxf(fmaf(u2f(z[i]), al, bt), 0.f);
        h[i] = v;
        hb[i] = f2u(v);
    }
}

// ---------------------------------------------------------------------------
// node_out = h @ node_w + node_b ; hsum += column sums of h ; copy h to d_out
// ---------------------------------------------------------------------------
__global__ __launch_bounds__(256) void k_nodeout(
    const float* __restrict__ h, const float* __restrict__ nw, const float* __restrict__ nb,
    float* __restrict__ node_out, float* __restrict__ h_out, float* __restrict__ hsum)
{
    __shared__ float hs[64][65];
    __shared__ float snw[D * NOD];
    __shared__ float snb[NOD];
    __shared__ float red[4][D];
    const int tid = threadIdx.x;
    for (int i = tid; i < D * NOD; i += 256) snw[i] = nw[i];
    if (tid < NOD) snb[tid] = nb[tid];
    const int j = tid & 63, g = tid >> 6;
    float cs = 0.f;
    for (int n0 = blockIdx.x * 64; n0 < NN; n0 += gridDim.x * 64) {
        __syncthreads();
        for (int r = g; r < 64; r += 4) {
            const int n = n0 + r;
            float v = 0.f;
            if (n < NN) { v = h[n * D + j]; h_out[n * D + j] = v; }
            hs[r][j] = v;
        }
        __syncthreads();
        for (int r = g; r < 64; r += 4) cs += hs[r][j];
        for (int it = tid; it < 64 * NOD; it += 256) {
            const int r = it / NOD, c = it - r * NOD;
            const int n = n0 + r;
            if (n < NN) {
                float a = snb[c];
#pragma unroll 16
                for (int k = 0; k < D; ++k) a += hs[r][k] * snw[k * NOD + c];
                node_out[n * NOD + c] = a;
            }
        }
    }
    red[g][j] = cs;
    __syncthreads();
    if (tid < D) atomicAdd(&hsum[tid], red[0][tid] + red[1][tid] + red[2][tid] + red[3][tid]);
}

__global__ void k_graphout(const float* __restrict__ hsum, const float* __restrict__ gw,
                           const float* __restrict__ gb, float* __restrict__ out)
{
    const int j = threadIdx.x;  // 64 threads
    float v = hsum[j] * (1.f / NN) * gw[j];
#pragma unroll
    for (int off = 32; off > 0; off >>= 1) v += __shfl_down(v, off, 64);
    if (j == 0) out[0] = v + gb[0];
}

// ---------------------------------------------------------------------------
extern "C" void kernel_launch(void* const* d_in, const int* in_sizes, int n_in,
                              void* d_out, int out_size, void* d_ws, size_t ws_size,
                              hipStream_t stream)
{
    (void)in_sizes; (void)n_in; (void)out_size; (void)ws_size;
    const float* x        = (const float*)d_in[0];
    const int*   ei       = (const int*)  d_in[1];
    const float* ea       = (const float*)d_in[2];
    const float* prev_h   = (const float*)d_in[3];
    const float* lin_in_w = (const float*)d_in[4];
    const float* lin_in_b = (const float*)d_in[5];
    const float* hist_w   = (const float*)d_in[6];
    const float* hist_b   = (const float*)d_in[7];
    const float* msg_w1   = (const float*)d_in[8];
    const float* msg_b1   = (const float*)d_in[9];
    const float* msg_g1   = (const float*)d_in[10];
    const float* msg_be1  = (const float*)d_in[11];
    const float* msg_w2   = (const float*)d_in[12];
    const float* msg_b2   = (const float*)d_in[13];
    const float* msg_g2   = (const float*)d_in[14];
    const float* msg_be2  = (const float*)d_in[15];
    const float* upd_w1   = (const float*)d_in[16];
    const float* upd_b1   = (const float*)d_in[17];
    const float* upd_g1   = (const float*)d_in[18];
    const float* upd_be1  = (const float*)d_in[19];
    const float* upd_w2   = (const float*)d_in[20];
    const float* upd_b2   = (const float*)d_in[21];
    const float* upd_g2   = (const float*)d_in[22];
    const float* upd_be2  = (const float*)d_in[23];
    const float* graph_w  = (const float*)d_in[24];
    const float* graph_b  = (const float*)d_in[25];
    const float* node_w   = (const float*)d_in[26];
    const float* node_b   = (const float*)d_in[27];

    const int* src = ei;        // edge_index[0]
    const int* dst = ei + NE;   // edge_index[1]

    float* out       = (float*)d_out;
    float* graph_out = out;                  // [1]
    float* node_out  = out + 1;              // [N*NO]
    float* h_out     = out + 1 + NN * NOD;   // [N*D]

    char* ws = (char*)d_ws;
    size_t off = 0;
    ushort* y     = (ushort*)(ws + off); off += (size_t)NE * D * sizeof(ushort);  // 64 MB
    ushort* z     = y;   // aliases y: z's lifetime (upd1..upd3) disjoint from y's (msg1..aggr3)
    float*  aggr  = (float*) (ws + off); off += (size_t)NN * D * sizeof(float);   // 12.8 MB
    float*  h     = (float*) (ws + off); off += (size_t)NN * D * sizeof(float);   // 12.8 MB
    ushort* hb    = (ushort*)(ws + off); off += (size_t)NN * D * sizeof(ushort);  // 6.4 MB
    uint*   sd    = (uint*)  (ws + off); off += (size_t)NE * sizeof(uint);        // 2 MB
    uint2*  eab   = (uint2*) (ws + off); off += (size_t)NE * sizeof(uint2);       // 4 MB
    int* rowstart = (int*)   (ws + off); off += (size_t)(NN + 1) * sizeof(int);
    int* cnt      = (int*)   (ws + off); off += (size_t)NN * sizeof(int);         // reused as cursor
    int* bsum     = (int*)   (ws + off); off += (size_t)256 * sizeof(int);
    float* stats  = (float*) (ws + off); off += (size_t)(NL * 4 * 2 * D) * sizeof(float);
    float* hsum   = (float*) (ws + off); off += (size_t)D * sizeof(float);
    int* cursor   = cnt;

    hipMemsetAsync(cnt, 0, (size_t)NN * sizeof(int), stream);
    hipMemsetAsync(stats, 0, (size_t)(NL * 4 * 2 * D + D) * sizeof(float), stream);

    // edge sort (reused across all layers)
    k_hist<<<(NE + 255) / 256, 256, 0, stream>>>(dst, cnt);
    k_scan1<<<NBLK1, 256, 0, stream>>>(cnt, rowstart, bsum);
    k_scan2<<<1, 256, 0, stream>>>(bsum);
    k_scan3<<<NBLK1, 256, 0, stream>>>(rowstart, bsum, cursor);
    k_scatter<<<(NE + 255) / 256, 256, 0, stream>>>(src, dst, ea, cursor, sd, eab);

    k_input<<<512, 256, 0, stream>>>(x, prev_h, lin_in_w, lin_in_b, hist_w, hist_b, h, hb);

    for (int l = 0; l < NL; ++l) {
        float* st_m1 = stats + (l * 4 + 0) * 2 * D;
        float* st_m2 = stats + (l * 4 + 1) * 2 * D;
        float* st_u1 = stats + (l * 4 + 2) * 2 * D;
        float* st_u2 = stats + (l * 4 + 3) * 2 * D;
        k_msg1<<<768, 256, 0, stream>>>(hb, sd, eab,
                                        msg_w1 + (size_t)l * K1 * D, msg_b1 + l * D, y, st_m1);
        k_mlp2b<<<1024, 256, 0, stream>>>(y, y,
                                          msg_w2 + (size_t)l * D * D, msg_b2 + l * D,
                                          msg_g1 + l * D, msg_be1 + l * D,
                                          st_m1, st_m2, NE, 1.f / NE);
        hipMemsetAsync(aggr, 0, (size_t)NN * D * sizeof(float), stream);
        k_aggr3<<<(NE + 63) / 64, 256, 0, stream>>>(y, rowstart, sd,
                                                    msg_g2 + l * D, msg_be2 + l * D,
                                                    st_m2, aggr);
        k_upd1<<<768, 256, 0, stream>>>(hb, aggr,
                                        upd_w1 + (size_t)l * KU * D, upd_b1 + l * D, z, st_u1);
        k_mlp2b<<<782, 256, 0, stream>>>(z, z,
                                         upd_w2 + (size_t)l * D * D, upd_b2 + l * D,
                                         upd_g1 + l * D, upd_be1 + l * D,
                                         st_u1, st_u2, NN, 1.f / NN);
        k_upd3<<<1024, 256, 0, stream>>>(z, upd_g2 + l * D, upd_be2 + l * D, st_u2, h, hb);
    }

    k_nodeout<<<782, 256, 0, stream>>>(h, node_w, node_b, node_out, h_out, hsum);
    k_graphout<<<1, 64, 0, stream>>>(hsum, graph_w, graph_b, graph_out);
}

// Round 10
// 1020.596 us; speedup vs baseline: 1.3296x; 1.0570x over previous
//
#include <hip/hip_runtime.h>
#include <hip/hip_bf16.h>

#define NN 50000
#define NE 500000
#define D 64
#define IND 11
#define EDD 4
#define NOD 5
#define NL 4
#define K1 132   // 2D + ED
#define KU 128   // 2D
#define EPSB 1e-5f

#define NBLK1 196  // ceil(50000/256) scan chunks

typedef __hip_bfloat16 bf16;
typedef __attribute__((ext_vector_type(8))) __bf16 bf16x8;
typedef __attribute__((ext_vector_type(4))) float f32x4;

__device__ __forceinline__ ushort f2u(float f) {
    __hip_bfloat16 h = __float2bfloat16(f);
    return __builtin_bit_cast(ushort, h);
}
__device__ __forceinline__ float u2f(ushort u) {
    uint v = (uint)u << 16;
    return __builtin_bit_cast(float, v);
}
// BN+relu two packed bf16 -> packed bf16
__device__ __forceinline__ uint bnpack(uint uu, float a0, float b0, float a1, float b1) {
    const float f0 = fmaxf(fmaf(u2f((ushort)(uu & 0xffffu)), a0, b0), 0.f);
    const float f1 = fmaxf(fmaf(u2f((ushort)(uu >> 16)), a1, b1), 0.f);
    return (uint)f2u(f0) | ((uint)f2u(f1) << 16);
}
__device__ __forceinline__ bf16x8 packf8(float4 lo, float4 hi) {
    uint4 u;
    u.x = (uint)f2u(lo.x) | ((uint)f2u(lo.y) << 16);
    u.y = (uint)f2u(lo.z) | ((uint)f2u(lo.w) << 16);
    u.z = (uint)f2u(hi.x) | ((uint)f2u(hi.y) << 16);
    u.w = (uint)f2u(hi.z) | ((uint)f2u(hi.w) << 16);
    return __builtin_bit_cast(bf16x8, u);
}

// ---------------------------------------------------------------------------
// Edge sort by dst: histogram -> scan -> scatter (reused by all 4 layers)
// ---------------------------------------------------------------------------
__global__ __launch_bounds__(256) void k_hist(const int* __restrict__ dst, int* __restrict__ cnt)
{
    const int e = blockIdx.x * 256 + threadIdx.x;
    if (e < NE) atomicAdd(&cnt[dst[e]], 1);
}

__global__ __launch_bounds__(256) void k_scan1(const int* __restrict__ cnt,
                                               int* __restrict__ rowstart, int* __restrict__ bsum)
{
    __shared__ int s[256];
    const int tid = threadIdx.x;
    const int i = blockIdx.x * 256 + tid;
    const int v = (i < NN) ? cnt[i] : 0;
    s[tid] = v;
    __syncthreads();
    for (int off = 1; off < 256; off <<= 1) {
        const int t = (tid >= off) ? s[tid - off] : 0;
        __syncthreads();
        s[tid] += t;
        __syncthreads();
    }
    if (i < NN) rowstart[i] = s[tid] - v;
    if (tid == 255) bsum[blockIdx.x] = s[255];
}

__global__ __launch_bounds__(256) void k_scan2(int* __restrict__ bsum)
{
    __shared__ int s[256];
    const int tid = threadIdx.x;
    const int v = (tid < NBLK1) ? bsum[tid] : 0;
    s[tid] = v;
    __syncthreads();
    for (int off = 1; off < 256; off <<= 1) {
        const int t = (tid >= off) ? s[tid - off] : 0;
        __syncthreads();
        s[tid] += t;
        __syncthreads();
    }
    if (tid < NBLK1) bsum[tid] = s[tid] - v;
}

__global__ __launch_bounds__(256) void k_scan3(int* __restrict__ rowstart,
                                               const int* __restrict__ bsum,
                                               int* __restrict__ cursor)
{
    const int i = blockIdx.x * 256 + threadIdx.x;
    if (i < NN) {
        const int rs = rowstart[i] + bsum[i >> 8];
        rowstart[i] = rs;
        cursor[i] = rs;
    }
    if (i == 0) rowstart[NN] = NE;
}

__global__ __launch_bounds__(256) void k_scatter(
    const int* __restrict__ src, const int* __restrict__ dst, const float* __restrict__ ea,
    int* __restrict__ cursor, uint* __restrict__ sd, uint2* __restrict__ eab)
{
    const int e = blockIdx.x * 256 + threadIdx.x;
    if (e < NE) {
        const int d = dst[e];
        const int p = atomicAdd(&cursor[d], 1);
        sd[p] = (uint)src[e] | ((uint)d << 16);   // N=50000 < 2^16: packs
        const float4 t = *(const float4*)&ea[(size_t)e * EDD];
        uint2 pk;
        pk.x = (uint)f2u(t.x) | ((uint)f2u(t.y) << 16);
        pk.y = (uint)f2u(t.z) | ((uint)f2u(t.w) << 16);
        eab[p] = pk;
    }
}

// ---------------------------------------------------------------------------
// h = relu(x @ lin_in_w + b + prev_h @ hist_w + b) ; hb = bf16(h)
// ---------------------------------------------------------------------------
__global__ __launch_bounds__(256) void k_input(
    const float* __restrict__ x, const float* __restrict__ prev_h,
    const float* __restrict__ w_in, const float* __restrict__ b_in,
    const float* __restrict__ w_h, const float* __restrict__ b_h,
    float* __restrict__ h, ushort* __restrict__ hb)
{
    __shared__ float sW1[IND * D];
    __shared__ float sW2[D * D];
    __shared__ float sb[D];
    __shared__ float sx[4][IND];
    __shared__ float sp[4][D];
    const int tid = threadIdx.x;
    for (int i = tid; i < IND * D; i += 256) sW1[i] = w_in[i];
    for (int i = tid; i < D * D; i += 256) sW2[i] = w_h[i];
    if (tid < D) sb[tid] = b_in[tid] + b_h[tid];
    const int j = tid & 63, r = tid >> 6;
    for (int n0 = blockIdx.x * 4; n0 < NN; n0 += gridDim.x * 4) {
        __syncthreads();
        const int n = n0 + r;
        if (n < NN) {
            sp[r][j] = prev_h[n * D + j];
            if (j < IND) sx[r][j] = x[n * IND + j];
        }
        __syncthreads();
        if (n < NN) {
            float acc = sb[j];
#pragma unroll
            for (int k = 0; k < IND; ++k) acc += sx[r][k] * sW1[k * D + j];
#pragma unroll 8
            for (int k = 0; k < D; ++k) acc += sp[r][k] * sW2[k * D + j];
            const float v = fmaxf(acc, 0.0f);
            h[n * D + j] = v;
            hb[n * D + j] = f2u(v);
        }
    }
}

// ---------------------------------------------------------------------------
// y = cat(hb[dst], hb[src], ea) @ W + b  — BARRIER-FREE per-wave MFMA.
// Each wave owns groups of 16 sorted edges; A-fragments loaded b128 straight
// from global (lane fn=edge, quad=k-chunk); B-fragments register-resident.
// ---------------------------------------------------------------------------
__global__ __launch_bounds__(256, 3) void k_msg1(
    const ushort* __restrict__ hb, const uint* __restrict__ sd, const uint2* __restrict__ eab,
    const float* __restrict__ W, const float* __restrict__ b,
    ushort* __restrict__ y, float* __restrict__ st)
{
    __shared__ __align__(16) ushort wst[64][160];
    __shared__ float sred[4][2][64];
    const int tid = threadIdx.x;
    const int lane = tid & 63, w = tid >> 6;
    const int fn = lane & 15, quad = lane >> 4;

    // stage W^T (K padded 132->160 with zeros)
    for (int i = tid; i < 64 * 160; i += 256) ((ushort*)wst)[i] = 0;
    __syncthreads();
    for (int i = tid; i < K1 * D; i += 256) {
        const int k = i >> 6, n = i & 63;
        wst[n][k] = f2u(W[i]);
    }
    __syncthreads();
    bf16x8 Bf[5][4];
#pragma unroll
    for (int s = 0; s < 5; ++s)
#pragma unroll
        for (int c = 0; c < 4; ++c)
            Bf[s][c] = *(const bf16x8*)&wst[c * 16 + fn][s * 32 + quad * 8];
    float bj[4];
#pragma unroll
    for (int c = 0; c < 4; ++c) bj[c] = b[c * 16 + fn];
    __syncthreads();

    const int ngroups = NE / 16;           // 31250, exact
    const int nw = gridDim.x * 4;
    int g = blockIdx.x * 4 + w;

    const int gc0 = min(g, ngroups - 1);
    uint sdc = sd[gc0 * 16 + fn];
    uint sdn = sd[min(g + nw, ngroups - 1) * 16 + fn];
    bf16x8 f0, f1, f2, f3;
    uint2 pe;
    {
        const int di = (int)(sdc >> 16), si = (int)(sdc & 0xffffu);
        f0 = *(const bf16x8*)&hb[(size_t)di * D + quad * 8];
        f1 = *(const bf16x8*)&hb[(size_t)di * D + 32 + quad * 8];
        f2 = *(const bf16x8*)&hb[(size_t)si * D + quad * 8];
        f3 = *(const bf16x8*)&hb[(size_t)si * D + 32 + quad * 8];
        pe = eab[gc0 * 16 + fn];
    }

    float ps[4] = {0, 0, 0, 0}, pq[4] = {0, 0, 0, 0};

    for (; g < ngroups; g += nw) {
        // in-loop LDS clobber: forces Bf to stay in VGPRs (no LDS re-reads)
        ((ushort*)wst)[lane] = (ushort)g;

        const int gn = g + nw;
        const int gnc = min(gn, ngroups - 1);
        // prefetch next group's fragments (overlaps MFMA below)
        bf16x8 n0, n1, n2, n3;
        uint2 pen;
        {
            const int di = (int)(sdn >> 16), si = (int)(sdn & 0xffffu);
            n0 = *(const bf16x8*)&hb[(size_t)di * D + quad * 8];
            n1 = *(const bf16x8*)&hb[(size_t)di * D + 32 + quad * 8];
            n2 = *(const bf16x8*)&hb[(size_t)si * D + quad * 8];
            n3 = *(const bf16x8*)&hb[(size_t)si * D + 32 + quad * 8];
            pen = eab[gnc * 16 + fn];
        }
        const uint sdn2 = sd[min(gn + nw, ngroups - 1) * 16 + fn];

        // ea fragment: k=128..135 live on quad 0 only (rest zero-padded)
        uint4 a4u;
        a4u.x = (quad == 0) ? pe.x : 0u;
        a4u.y = (quad == 0) ? pe.y : 0u;
        a4u.z = 0u; a4u.w = 0u;
        const bf16x8 a4 = __builtin_bit_cast(bf16x8, a4u);

        f32x4 acc[4];
#pragma unroll
        for (int c = 0; c < 4; ++c) acc[c] = (f32x4){bj[c], bj[c], bj[c], bj[c]};
#pragma unroll
        for (int c = 0; c < 4; ++c) acc[c] = __builtin_amdgcn_mfma_f32_16x16x32_bf16(f0, Bf[0][c], acc[c], 0, 0, 0);
#pragma unroll
        for (int c = 0; c < 4; ++c) acc[c] = __builtin_amdgcn_mfma_f32_16x16x32_bf16(f1, Bf[1][c], acc[c], 0, 0, 0);
#pragma unroll
        for (int c = 0; c < 4; ++c) acc[c] = __builtin_amdgcn_mfma_f32_16x16x32_bf16(f2, Bf[2][c], acc[c], 0, 0, 0);
#pragma unroll
        for (int c = 0; c < 4; ++c) acc[c] = __builtin_amdgcn_mfma_f32_16x16x32_bf16(f3, Bf[3][c], acc[c], 0, 0, 0);
#pragma unroll
        for (int c = 0; c < 4; ++c) acc[c] = __builtin_amdgcn_mfma_f32_16x16x32_bf16(a4, Bf[4][c], acc[c], 0, 0, 0);

        const int row0 = g * 16 + quad * 4;
#pragma unroll
        for (int reg = 0; reg < 4; ++reg) {
#pragma unroll
            for (int c = 0; c < 4; ++c) {
                const ushort ub = f2u(acc[c][reg]);
                y[(size_t)(row0 + reg) * D + c * 16 + fn] = ub;
                const float f = u2f(ub);
                ps[c] += f; pq[c] += f * f;
            }
        }
        f0 = n0; f1 = n1; f2 = n2; f3 = n3; pe = pen; sdn = sdn2;
    }
    __syncthreads();
#pragma unroll
    for (int c = 0; c < 4; ++c) {
        ps[c] += __shfl_xor(ps[c], 16, 64); ps[c] += __shfl_xor(ps[c], 32, 64);
        pq[c] += __shfl_xor(pq[c], 16, 64); pq[c] += __shfl_xor(pq[c], 32, 64);
    }
    if (quad == 0) {
#pragma unroll
        for (int c = 0; c < 4; ++c) {
            sred[w][0][c * 16 + fn] = ps[c];
            sred[w][1][c * 16 + fn] = pq[c];
        }
    }
    __syncthreads();
    if (tid < 128) {
        const int col = tid & 63, which = tid >> 6;
        const float s = sred[0][which][col] + sred[1][which][col] +
                        sred[2][which][col] + sred[3][which][col];
        atomicAdd(&st[which * 64 + col], s);
    }
}

// ---------------------------------------------------------------------------
// yout = relu(BN(yin)) @ W + b — BARRIER-FREE per-wave MFMA (in-place safe:
// each wave reads exactly the rows it overwrites, after the read).
// ---------------------------------------------------------------------------
__global__ __launch_bounds__(256, 4) void k_mlp2b(
    const ushort* __restrict__ yin, ushort* __restrict__ yout,
    const float* __restrict__ W, const float* __restrict__ b,
    const float* __restrict__ gg, const float* __restrict__ be,
    const float* __restrict__ st_in, float* __restrict__ st_out,
    const int nrows, const float inv_rows)
{
    __shared__ __align__(16) ushort wst[64][64];
    __shared__ float sal[64], sbe[64];
    __shared__ float sred[4][2][64];
    const int tid = threadIdx.x;
    const int lane = tid & 63, w = tid >> 6;
    const int fn = lane & 15, quad = lane >> 4;

    if (tid < 64) {
        const float m = st_in[tid] * inv_rows;
        const float v = st_in[64 + tid] * inv_rows - m * m;
        const float a = rsqrtf(v + EPSB) * gg[tid];
        sal[tid] = a;
        sbe[tid] = be[tid] - m * a;
    }
    for (int i = tid; i < D * D; i += 256) {
        const int k = i >> 6, n = i & 63;
        wst[n][k] = f2u(W[i]);
    }
    __syncthreads();

    bf16x8 Bf[2][4];
#pragma unroll
    for (int s = 0; s < 2; ++s)
#pragma unroll
        for (int c = 0; c < 4; ++c)
            Bf[s][c] = *(const bf16x8*)&wst[c * 16 + fn][s * 32 + quad * 8];
    float bj[4];
#pragma unroll
    for (int c = 0; c < 4; ++c) bj[c] = b[c * 16 + fn];
    // per-lane BN coefficients: channel = (i>>3)*32 + quad*8 + (i&7)
    float al[16], bt[16];
#pragma unroll
    for (int i = 0; i < 16; ++i) {
        const int ch = (i >> 3) * 32 + quad * 8 + (i & 7);
        al[i] = sal[ch]; bt[i] = sbe[ch];
    }
    __syncthreads();

    const int ngroups = nrows / 16;        // NE/16=31250, NN/16=3125: exact
    const int nw = gridDim.x * 4;
    int g = blockIdx.x * 4 + w;

    size_t base = ((size_t)(min(g, ngroups - 1) * 16 + fn)) * D + quad * 8;
    uint4 u0 = *(const uint4*)&yin[base];
    uint4 u1 = *(const uint4*)&yin[base + 32];

    float ps[4] = {0, 0, 0, 0}, pq[4] = {0, 0, 0, 0};

    for (; g < ngroups; g += nw) {
        ((ushort*)wst)[lane] = (ushort)g;   // force Bf register residency

        const int gn = g + nw;
        const size_t nbase = ((size_t)(min(gn, ngroups - 1) * 16 + fn)) * D + quad * 8;
        const uint4 v0 = *(const uint4*)&yin[nbase];
        const uint4 v1 = *(const uint4*)&yin[nbase + 32];

        uint4 p0, p1;
        p0.x = bnpack(u0.x, al[0], bt[0], al[1], bt[1]);
        p0.y = bnpack(u0.y, al[2], bt[2], al[3], bt[3]);
        p0.z = bnpack(u0.z, al[4], bt[4], al[5], bt[5]);
        p0.w = bnpack(u0.w, al[6], bt[6], al[7], bt[7]);
        p1.x = bnpack(u1.x, al[8], bt[8], al[9], bt[9]);
        p1.y = bnpack(u1.y, al[10], bt[10], al[11], bt[11]);
        p1.z = bnpack(u1.z, al[12], bt[12], al[13], bt[13]);
        p1.w = bnpack(u1.w, al[14], bt[14], al[15], bt[15]);
        const bf16x8 a0 = __builtin_bit_cast(bf16x8, p0);
        const bf16x8 a1 = __builtin_bit_cast(bf16x8, p1);

        f32x4 acc[4];
#pragma unroll
        for (int c = 0; c < 4; ++c) acc[c] = (f32x4){bj[c], bj[c], bj[c], bj[c]};
#pragma unroll
        for (int c = 0; c < 4; ++c) acc[c] = __builtin_amdgcn_mfma_f32_16x16x32_bf16(a0, Bf[0][c], acc[c], 0, 0, 0);
#pragma unroll
        for (int c = 0; c < 4; ++c) acc[c] = __builtin_amdgcn_mfma_f32_16x16x32_bf16(a1, Bf[1][c], acc[c], 0, 0, 0);

        const int row0 = g * 16 + quad * 4;
#pragma unroll
        for (int reg = 0; reg < 4; ++reg) {
#pragma unroll
            for (int c = 0; c < 4; ++c) {
                const ushort ub = f2u(acc[c][reg]);
                yout[(size_t)(row0 + reg) * D + c * 16 + fn] = ub;
                const float f = u2f(ub);
                ps[c] += f; pq[c] += f * f;
            }
        }
        u0 = v0; u1 = v1;
    }
    __syncthreads();
#pragma unroll
    for (int c = 0; c < 4; ++c) {
        ps[c] += __shfl_xor(ps[c], 16, 64); ps[c] += __shfl_xor(ps[c], 32, 64);
        pq[c] += __shfl_xor(pq[c], 16, 64); pq[c] += __shfl_xor(pq[c], 32, 64);
    }
    if (quad == 0) {
#pragma unroll
        for (int c = 0; c < 4; ++c) {
            sred[w][0][c * 16 + fn] = ps[c];
            sred[w][1][c * 16 + fn] = pq[c];
        }
    }
    __syncthreads();
    if (tid < 128) {
        const int col = tid & 63, which = tid >> 6;
        const float s = sred[0][which][col] + sred[1][which][col] +
                        sred[2][which][col] + sred[3][which][col];
        atomicAdd(&st_out[which * 64 + col], s);
    }
}

// ---------------------------------------------------------------------------
// aggr (fp32, pre-zeroed) += segment sums of relu(BN2(y))  (unchanged)
// ---------------------------------------------------------------------------
__global__ __launch_bounds__(256) void k_aggr3(
    const ushort* __restrict__ y, const int* __restrict__ rowstart,
    const uint* __restrict__ sd,
    const float* __restrict__ gg, const float* __restrict__ be,
    const float* __restrict__ st, float* __restrict__ aggr)
{
    __shared__ float ys[64][68];
    __shared__ float sal[D], sbe[D];
    const int tid = threadIdx.x;
    if (tid < D) {
        const float m = st[tid] * (1.f / NE);
        const float v = st[D + tid] * (1.f / NE) - m * m;
        const float a = rsqrtf(v + EPSB) * gg[tid];
        sal[tid] = a;
        sbe[tid] = be[tid] - m * a;
    }
    __syncthreads();

    const int e0 = blockIdx.x << 6;
    const int e1 = min(e0 + 64, NE);

    const int r = tid >> 2, c0 = (tid & 3) << 4;
    const int e = e0 + r;
    if (e < NE) {
        const uint4 u0 = *(const uint4*)&y[(size_t)e * D + c0];
        const uint4 u1 = *(const uint4*)&y[(size_t)e * D + c0 + 8];
#pragma unroll
        for (int p = 0; p < 4; ++p) {
            const uint uu = ((const uint*)&u0)[p];
            const int cc = c0 + 2 * p;
            ys[r][cc]     = fmaxf(fmaf(u2f((ushort)(uu & 0xffffu)), sal[cc], sbe[cc]), 0.f);
            ys[r][cc + 1] = fmaxf(fmaf(u2f((ushort)(uu >> 16)), sal[cc + 1], sbe[cc + 1]), 0.f);
        }
#pragma unroll
        for (int p = 0; p < 4; ++p) {
            const uint uu = ((const uint*)&u1)[p];
            const int cc = c0 + 8 + 2 * p;
            ys[r][cc]     = fmaxf(fmaf(u2f((ushort)(uu & 0xffffu)), sal[cc], sbe[cc]), 0.f);
            ys[r][cc + 1] = fmaxf(fmaf(u2f((ushort)(uu >> 16)), sal[cc + 1], sbe[cc + 1]), 0.f);
        }
    }
    __syncthreads();

    const int lane = tid & 63, w = tid >> 6;
    int n = (int)(sd[e0] >> 16) + w;
    while (n < NN) {
        const int rs = rowstart[n];
        if (rs >= e1) break;
        const int re = rowstart[n + 1];
        const int j0 = max(rs, e0), j1 = min(re, e1);
        if (j1 > j0) {
            float s = 0.f;
            for (int j = j0; j < j1; ++j) s += ys[j - e0][lane];
            atomicAdd(&aggr[(size_t)n * D + lane], s);
        }
        n += 4;
    }
}

// ---------------------------------------------------------------------------
// z = cat(hb, aggr_f32) @ W + b — BARRIER-FREE per-wave MFMA
// ---------------------------------------------------------------------------
__global__ __launch_bounds__(256, 3) void k_upd1(
    const ushort* __restrict__ hb, const float* __restrict__ aggr,
    const float* __restrict__ W, const float* __restrict__ b,
    ushort* __restrict__ z, float* __restrict__ st)
{
    __shared__ __align__(16) ushort wst[64][128];
    __shared__ float sred[4][2][64];
    const int tid = threadIdx.x;
    const int lane = tid & 63, w = tid >> 6;
    const int fn = lane & 15, quad = lane >> 4;

    for (int i = tid; i < KU * D; i += 256) {
        const int k = i >> 6, n = i & 63;
        wst[n][k] = f2u(W[i]);
    }
    __syncthreads();
    bf16x8 Bf[4][4];
#pragma unroll
    for (int s = 0; s < 4; ++s)
#pragma unroll
        for (int c = 0; c < 4; ++c)
            Bf[s][c] = *(const bf16x8*)&wst[c * 16 + fn][s * 32 + quad * 8];
    float bj[4];
#pragma unroll
    for (int c = 0; c < 4; ++c) bj[c] = b[c * 16 + fn];
    __syncthreads();

    const int ngroups = NN / 16;           // 3125, exact
    const int nw = gridDim.x * 4;
    int g = blockIdx.x * 4 + w;

    size_t hbase = ((size_t)(min(g, ngroups - 1) * 16 + fn)) * D + quad * 8;
    bf16x8 h0 = *(const bf16x8*)&hb[hbase];
    bf16x8 h1 = *(const bf16x8*)&hb[hbase + 32];
    float4 q0 = *(const float4*)&aggr[hbase];
    float4 q1 = *(const float4*)&aggr[hbase + 4];
    float4 q2 = *(const float4*)&aggr[hbase + 32];
    float4 q3 = *(const float4*)&aggr[hbase + 36];

    float ps[4] = {0, 0, 0, 0}, pq[4] = {0, 0, 0, 0};

    for (; g < ngroups; g += nw) {
        ((ushort*)wst)[lane] = (ushort)g;   // force Bf register residency

        const int gn = g + nw;
        const size_t nb = ((size_t)(min(gn, ngroups - 1) * 16 + fn)) * D + quad * 8;
        const bf16x8 m0 = *(const bf16x8*)&hb[nb];
        const bf16x8 m1 = *(const bf16x8*)&hb[nb + 32];
        const float4 r0 = *(const float4*)&aggr[nb];
        const float4 r1 = *(const float4*)&aggr[nb + 4];
        const float4 r2 = *(const float4*)&aggr[nb + 32];
        const float4 r3 = *(const float4*)&aggr[nb + 36];

        const bf16x8 a2 = packf8(q0, q1);
        const bf16x8 a3 = packf8(q2, q3);

        f32x4 acc[4];
#pragma unroll
        for (int c = 0; c < 4; ++c) acc[c] = (f32x4){bj[c], bj[c], bj[c], bj[c]};
#pragma unroll
        for (int c = 0; c < 4; ++c) acc[c] = __builtin_amdgcn_mfma_f32_16x16x32_bf16(h0, Bf[0][c], acc[c], 0, 0, 0);
#pragma unroll
        for (int c = 0; c < 4; ++c) acc[c] = __builtin_amdgcn_mfma_f32_16x16x32_bf16(h1, Bf[1][c], acc[c], 0, 0, 0);
#pragma unroll
        for (int c = 0; c < 4; ++c) acc[c] = __builtin_amdgcn_mfma_f32_16x16x32_bf16(a2, Bf[2][c], acc[c], 0, 0, 0);
#pragma unroll
        for (int c = 0; c < 4; ++c) acc[c] = __builtin_amdgcn_mfma_f32_16x16x32_bf16(a3, Bf[3][c], acc[c], 0, 0, 0);

        const int row0 = g * 16 + quad * 4;
#pragma unroll
        for (int reg = 0; reg < 4; ++reg) {
#pragma unroll
            for (int c = 0; c < 4; ++c) {
                const ushort ub = f2u(acc[c][reg]);
                z[(size_t)(row0 + reg) * D + c * 16 + fn] = ub;
                const float f = u2f(ub);
                ps[c] += f; pq[c] += f * f;
            }
        }
        h0 = m0; h1 = m1; q0 = r0; q1 = r1; q2 = r2; q3 = r3;
    }
    __syncthreads();
#pragma unroll
    for (int c = 0; c < 4; ++c) {
        ps[c] += __shfl_xor(ps[c], 16, 64); ps[c] += __shfl_xor(ps[c], 32, 64);
        pq[c] += __shfl_xor(pq[c], 16, 64); pq[c] += __shfl_xor(pq[c], 32, 64);
    }
    if (quad == 0) {
#pragma unroll
        for (int c = 0; c < 4; ++c) {
            sred[w][0][c * 16 + fn] = ps[c];
            sred[w][1][c * 16 + fn] = pq[c];
        }
    }
    __syncthreads();
    if (tid < 128) {
        const int col = tid & 63, which = tid >> 6;
        const float s = sred[0][which][col] + sred[1][which][col] +
                        sred[2][which][col] + sred[3][which][col];
        atomicAdd(&st[which * 64 + col], s);
    }
}

// ---------------------------------------------------------------------------
// h += relu(BN(z)) ; hb = bf16(h)
// ---------------------------------------------------------------------------
__global__ __launch_bounds__(256) void k_upd3(
    const ushort* __restrict__ z, const float* __restrict__ gg, const float* __restrict__ be,
    const float* __restrict__ st, float* __restrict__ h, ushort* __restrict__ hb)
{
    __shared__ float sal[D], sbe[D];
    const int tid = threadIdx.x;
    if (tid < D) {
        const float m = st[tid] * (1.f / NN);
        const float v = st[D + tid] * (1.f / NN) - m * m;
        const float a = rsqrtf(v + EPSB) * gg[tid];
        sal[tid] = a;
        sbe[tid] = be[tid] - m * a;
    }
    __syncthreads();
    const int j = tid & 63;
    const float al = sal[j], bt = sbe[j];
    for (int i = blockIdx.x * 256 + tid; i < NN * D; i += gridDim.x * 256) {
        const float v = h[i] + fmaxf(fmaf(u2f(z[i]), al, bt), 0.f);
        h[i] = v;
        hb[i] = f2u(v);
    }
}

// ---------------------------------------------------------------------------
// node_out = h @ node_w + node_b ; hsum += column sums of h ; copy h to d_out
// ---------------------------------------------------------------------------
__global__ __launch_bounds__(256) void k_nodeout(
    const float* __restrict__ h, const float* __restrict__ nw, const float* __restrict__ nb,
    float* __restrict__ node_out, float* __restrict__ h_out, float* __restrict__ hsum)
{
    __shared__ float hs[64][65];
    __shared__ float snw[D * NOD];
    __shared__ float snb[NOD];
    __shared__ float red[4][D];
    const int tid = threadIdx.x;
    for (int i = tid; i < D * NOD; i += 256) snw[i] = nw[i];
    if (tid < NOD) snb[tid] = nb[tid];
    const int j = tid & 63, g = tid >> 6;
    float cs = 0.f;
    for (int n0 = blockIdx.x * 64; n0 < NN; n0 += gridDim.x * 64) {
        __syncthreads();
        for (int r = g; r < 64; r += 4) {
            const int n = n0 + r;
            float v = 0.f;
            if (n < NN) { v = h[n * D + j]; h_out[n * D + j] = v; }
            hs[r][j] = v;
        }
        __syncthreads();
        for (int r = g; r < 64; r += 4) cs += hs[r][j];
        for (int it = tid; it < 64 * NOD; it += 256) {
            const int r = it / NOD, c = it - r * NOD;
            const int n = n0 + r;
            if (n < NN) {
                float a = snb[c];
#pragma unroll 16
                for (int k = 0; k < D; ++k) a += hs[r][k] * snw[k * NOD + c];
                node_out[n * NOD + c] = a;
            }
        }
    }
    red[g][j] = cs;
    __syncthreads();
    if (tid < D) atomicAdd(&hsum[tid], red[0][tid] + red[1][tid] + red[2][tid] + red[3][tid]);
}

__global__ void k_graphout(const float* __restrict__ hsum, const float* __restrict__ gw,
                           const float* __restrict__ gb, float* __restrict__ out)
{
    const int j = threadIdx.x;  // 64 threads
    float v = hsum[j] * (1.f / NN) * gw[j];
#pragma unroll
    for (int off = 32; off > 0; off >>= 1) v += __shfl_down(v, off, 64);
    if (j == 0) out[0] = v + gb[0];
}

// ---------------------------------------------------------------------------
extern "C" void kernel_launch(void* const* d_in, const int* in_sizes, int n_in,
                              void* d_out, int out_size, void* d_ws, size_t ws_size,
                              hipStream_t stream)
{
    (void)in_sizes; (void)n_in; (void)out_size; (void)ws_size;
    const float* x        = (const float*)d_in[0];
    const int*   ei       = (const int*)  d_in[1];
    const float* ea       = (const float*)d_in[2];
    const float* prev_h   = (const float*)d_in[3];
    const float* lin_in_w = (const float*)d_in[4];
    const float* lin_in_b = (const float*)d_in[5];
    const float* hist_w   = (const float*)d_in[6];
    const float* hist_b   = (const float*)d_in[7];
    const float* msg_w1   = (const float*)d_in[8];
    const float* msg_b1   = (const float*)d_in[9];
    const float* msg_g1   = (const float*)d_in[10];
    const float* msg_be1  = (const float*)d_in[11];
    const float* msg_w2   = (const float*)d_in[12];
    const float* msg_b2   = (const float*)d_in[13];
    const float* msg_g2   = (const float*)d_in[14];
    const float* msg_be2  = (const float*)d_in[15];
    const float* upd_w1   = (const float*)d_in[16];
    const float* upd_b1   = (const float*)d_in[17];
    const float* upd_g1   = (const float*)d_in[18];
    const float* upd_be1  = (const float*)d_in[19];
    const float* upd_w2   = (const float*)d_in[20];
    const float* upd_b2   = (const float*)d_in[21];
    const float* upd_g2   = (const float*)d_in[22];
    const float* upd_be2  = (const float*)d_in[23];
    const float* graph_w  = (const float*)d_in[24];
    const float* graph_b  = (const float*)d_in[25];
    const float* node_w   = (const float*)d_in[26];
    const float* node_b   = (const float*)d_in[27];

    const int* src = ei;        // edge_index[0]
    const int* dst = ei + NE;   // edge_index[1]

    float* out       = (float*)d_out;
    float* graph_out = out;                  // [1]
    float* node_out  = out + 1;              // [N*NO]
    float* h_out     = out + 1 + NN * NOD;   // [N*D]

    char* ws = (char*)d_ws;
    size_t off = 0;
    ushort* y     = (ushort*)(ws + off); off += (size_t)NE * D * sizeof(ushort);  // 64 MB
    ushort* z     = y;   // aliases y: z's lifetime (upd1..upd3) disjoint from y's (msg1..aggr3)
    float*  aggr  = (float*) (ws + off); off += (size_t)NN * D * sizeof(float);   // 12.8 MB
    float*  h     = (float*) (ws + off); off += (size_t)NN * D * sizeof(float);   // 12.8 MB
    ushort* hb    = (ushort*)(ws + off); off += (size_t)NN * D * sizeof(ushort);  // 6.4 MB
    uint*   sd    = (uint*)  (ws + off); off += (size_t)NE * sizeof(uint);        // 2 MB
    uint2*  eab   = (uint2*) (ws + off); off += (size_t)NE * sizeof(uint2);       // 4 MB
    int* rowstart = (int*)   (ws + off); off += (size_t)(NN + 1) * sizeof(int);
    int* cnt      = (int*)   (ws + off); off += (size_t)NN * sizeof(int);         // reused as cursor
    int* bsum     = (int*)   (ws + off); off += (size_t)256 * sizeof(int);
    float* stats  = (float*) (ws + off); off += (size_t)(NL * 4 * 2 * D) * sizeof(float);
    float* hsum   = (float*) (ws + off); off += (size_t)D * sizeof(float);
    int* cursor   = cnt;

    hipMemsetAsync(cnt, 0, (size_t)NN * sizeof(int), stream);
    hipMemsetAsync(stats, 0, (size_t)(NL * 4 * 2 * D + D) * sizeof(float), stream);

    // edge sort (reused across all layers)
    k_hist<<<(NE + 255) / 256, 256, 0, stream>>>(dst, cnt);
    k_scan1<<<NBLK1, 256, 0, stream>>>(cnt, rowstart, bsum);
    k_scan2<<<1, 256, 0, stream>>>(bsum);
    k_scan3<<<NBLK1, 256, 0, stream>>>(rowstart, bsum, cursor);
    k_scatter<<<(NE + 255) / 256, 256, 0, stream>>>(src, dst, ea, cursor, sd, eab);

    k_input<<<512, 256, 0, stream>>>(x, prev_h, lin_in_w, lin_in_b, hist_w, hist_b, h, hb);

    for (int l = 0; l < NL; ++l) {
        float* st_m1 = stats + (l * 4 + 0) * 2 * D;
        float* st_m2 = stats + (l * 4 + 1) * 2 * D;
        float* st_u1 = stats + (l * 4 + 2) * 2 * D;
        float* st_u2 = stats + (l * 4 + 3) * 2 * D;
        k_msg1<<<768, 256, 0, stream>>>(hb, sd, eab,
                                        msg_w1 + (size_t)l * K1 * D, msg_b1 + l * D, y, st_m1);
        k_mlp2b<<<1024, 256, 0, stream>>>(y, y,
                                          msg_w2 + (size_t)l * D * D, msg_b2 + l * D,
                                          msg_g1 + l * D, msg_be1 + l * D,
                                          st_m1, st_m2, NE, 1.f / NE);
        hipMemsetAsync(aggr, 0, (size_t)NN * D * sizeof(float), stream);
        k_aggr3<<<(NE + 63) / 64, 256, 0, stream>>>(y, rowstart, sd,
                                                    msg_g2 + l * D, msg_be2 + l * D,
                                                    st_m2, aggr);
        k_upd1<<<768, 256, 0, stream>>>(hb, aggr,
                                        upd_w1 + (size_t)l * KU * D, upd_b1 + l * D, z, st_u1);
        k_mlp2b<<<391, 256, 0, stream>>>(z, z,
                                         upd_w2 + (size_t)l * D * D, upd_b2 + l * D,
                                         upd_g1 + l * D, upd_be1 + l * D,
                                         st_u1, st_u2, NN, 1.f / NN);
        k_upd3<<<1024, 256, 0, stream>>>(z, upd_g2 + l * D, upd_be2 + l * D, st_u2, h, hb);
    }

    k_nodeout<<<782, 256, 0, stream>>>(h, node_w, node_b, node_out, h_out, hsum);
    k_graphout<<<1, 64, 0, stream>>>(hsum, graph_w, graph_b, graph_out);
}

// Round 11
// 983.900 us; speedup vs baseline: 1.3792x; 1.0373x over previous
//
#include <hip/hip_runtime.h>
#include <hip/hip_bf16.h>

#define NN 50000
#define NE 500000
#define D 64
#define IND 11
#define EDD 4
#define NOD 5
#define NL 4
#define K1 132   // 2D + ED
#define KU 128   // 2D
#define EPSB 1e-5f

#define NBLK1 196  // ceil(50000/256) scan chunks

typedef __hip_bfloat16 bf16;
typedef __attribute__((ext_vector_type(8))) __bf16 bf16x8;
typedef __attribute__((ext_vector_type(4))) float f32x4;

__device__ __forceinline__ ushort f2u(float f) {
    __hip_bfloat16 h = __float2bfloat16(f);
    return __builtin_bit_cast(ushort, h);
}
__device__ __forceinline__ float u2f(ushort u) {
    uint v = (uint)u << 16;
    return __builtin_bit_cast(float, v);
}
// BN+relu two packed bf16 -> packed bf16
__device__ __forceinline__ uint bnpack(uint uu, float a0, float b0, float a1, float b1) {
    const float f0 = fmaxf(fmaf(u2f((ushort)(uu & 0xffffu)), a0, b0), 0.f);
    const float f1 = fmaxf(fmaf(u2f((ushort)(uu >> 16)), a1, b1), 0.f);
    return (uint)f2u(f0) | ((uint)f2u(f1) << 16);
}
__device__ __forceinline__ bf16x8 packf8(float4 lo, float4 hi) {
    uint4 u;
    u.x = (uint)f2u(lo.x) | ((uint)f2u(lo.y) << 16);
    u.y = (uint)f2u(lo.z) | ((uint)f2u(lo.w) << 16);
    u.z = (uint)f2u(hi.x) | ((uint)f2u(hi.y) << 16);
    u.w = (uint)f2u(hi.z) | ((uint)f2u(hi.w) << 16);
    return __builtin_bit_cast(bf16x8, u);
}

// ---------------------------------------------------------------------------
// Edge sort by dst: histogram -> scan -> scatter (reused by all 4 layers)
// ---------------------------------------------------------------------------
__global__ __launch_bounds__(256) void k_hist(const int* __restrict__ dst, int* __restrict__ cnt)
{
    const int e = blockIdx.x * 256 + threadIdx.x;
    if (e < NE) atomicAdd(&cnt[dst[e]], 1);
}

__global__ __launch_bounds__(256) void k_scan1(const int* __restrict__ cnt,
                                               int* __restrict__ rowstart, int* __restrict__ bsum)
{
    __shared__ int s[256];
    const int tid = threadIdx.x;
    const int i = blockIdx.x * 256 + tid;
    const int v = (i < NN) ? cnt[i] : 0;
    s[tid] = v;
    __syncthreads();
    for (int off = 1; off < 256; off <<= 1) {
        const int t = (tid >= off) ? s[tid - off] : 0;
        __syncthreads();
        s[tid] += t;
        __syncthreads();
    }
    if (i < NN) rowstart[i] = s[tid] - v;
    if (tid == 255) bsum[blockIdx.x] = s[255];
}

__global__ __launch_bounds__(256) void k_scan2(int* __restrict__ bsum)
{
    __shared__ int s[256];
    const int tid = threadIdx.x;
    const int v = (tid < NBLK1) ? bsum[tid] : 0;
    s[tid] = v;
    __syncthreads();
    for (int off = 1; off < 256; off <<= 1) {
        const int t = (tid >= off) ? s[tid - off] : 0;
        __syncthreads();
        s[tid] += t;
        __syncthreads();
    }
    if (tid < NBLK1) bsum[tid] = s[tid] - v;
}

__global__ __launch_bounds__(256) void k_scan3(int* __restrict__ rowstart,
                                               const int* __restrict__ bsum,
                                               int* __restrict__ cursor)
{
    const int i = blockIdx.x * 256 + threadIdx.x;
    if (i < NN) {
        const int rs = rowstart[i] + bsum[i >> 8];
        rowstart[i] = rs;
        cursor[i] = rs;
    }
    if (i == 0) rowstart[NN] = NE;
}

__global__ __launch_bounds__(256) void k_scatter(
    const int* __restrict__ src, const int* __restrict__ dst, const float* __restrict__ ea,
    int* __restrict__ cursor, uint* __restrict__ sd, uint2* __restrict__ eab)
{
    const int e = blockIdx.x * 256 + threadIdx.x;
    if (e < NE) {
        const int d = dst[e];
        const int p = atomicAdd(&cursor[d], 1);
        sd[p] = (uint)src[e] | ((uint)d << 16);   // N=50000 < 2^16: packs
        const float4 t = *(const float4*)&ea[(size_t)e * EDD];
        uint2 pk;
        pk.x = (uint)f2u(t.x) | ((uint)f2u(t.y) << 16);
        pk.y = (uint)f2u(t.z) | ((uint)f2u(t.w) << 16);
        eab[p] = pk;
    }
}

// ---------------------------------------------------------------------------
// h = relu(x @ lin_in_w + b + prev_h @ hist_w + b) ; hb = bf16(h)
// single-pass grid 12500 (was latency-bound serial loop at grid 512)
// ---------------------------------------------------------------------------
__global__ __launch_bounds__(256) void k_input(
    const float* __restrict__ x, const float* __restrict__ prev_h,
    const float* __restrict__ w_in, const float* __restrict__ b_in,
    const float* __restrict__ w_h, const float* __restrict__ b_h,
    float* __restrict__ h, ushort* __restrict__ hb)
{
    __shared__ float sW1[IND * D];
    __shared__ float sW2[D * D];
    __shared__ float sb[D];
    __shared__ float sx[4][IND];
    __shared__ float sp[4][D];
    const int tid = threadIdx.x;
    for (int i = tid; i < IND * D; i += 256) sW1[i] = w_in[i];
    for (int i = tid; i < D * D; i += 256) sW2[i] = w_h[i];
    if (tid < D) sb[tid] = b_in[tid] + b_h[tid];
    const int j = tid & 63, r = tid >> 6;
    const int n = blockIdx.x * 4 + r;
    __syncthreads();
    if (n < NN) {
        sp[r][j] = prev_h[n * D + j];
        if (j < IND) sx[r][j] = x[n * IND + j];
    }
    __syncthreads();
    if (n < NN) {
        float acc = sb[j];
#pragma unroll
        for (int k = 0; k < IND; ++k) acc += sx[r][k] * sW1[k * D + j];
#pragma unroll 8
        for (int k = 0; k < D; ++k) acc += sp[r][k] * sW2[k * D + j];
        const float v = fmaxf(acc, 0.0f);
        h[n * D + j] = v;
        hb[n * D + j] = f2u(v);
    }
}

// ---------------------------------------------------------------------------
// y = cat(hb[dst], hb[src], ea) @ W + b  — barrier-free per-wave MFMA.
// wst stride 168 (non-pow2): B-fragment re-reads spread across banks.
// ---------------------------------------------------------------------------
__global__ __launch_bounds__(256, 3) void k_msg1(
    const ushort* __restrict__ hb, const uint* __restrict__ sd, const uint2* __restrict__ eab,
    const float* __restrict__ W, const float* __restrict__ b,
    ushort* __restrict__ y, float* __restrict__ st)
{
    __shared__ __align__(16) ushort wst[64][168];
    __shared__ float sred[4][2][64];
    const int tid = threadIdx.x;
    const int lane = tid & 63, w = tid >> 6;
    const int fn = lane & 15, quad = lane >> 4;

    // stage W^T (K padded 132->160 with zeros; rows stride 168)
    for (int i = tid; i < 64 * 168; i += 256) ((ushort*)wst)[i] = 0;
    __syncthreads();
    for (int i = tid; i < K1 * D; i += 256) {
        const int k = i >> 6, n = i & 63;
        wst[n][k] = f2u(W[i]);
    }
    __syncthreads();
    bf16x8 Bf[5][4];
#pragma unroll
    for (int s = 0; s < 5; ++s)
#pragma unroll
        for (int c = 0; c < 4; ++c)
            Bf[s][c] = *(const bf16x8*)&wst[c * 16 + fn][s * 32 + quad * 8];
    float bj[4];
#pragma unroll
    for (int c = 0; c < 4; ++c) bj[c] = b[c * 16 + fn];
    __syncthreads();

    const int ngroups = NE / 16;           // 31250, exact
    const int nw = gridDim.x * 4;
    int g = blockIdx.x * 4 + w;

    const int gc0 = min(g, ngroups - 1);
    uint sdc = sd[gc0 * 16 + fn];
    uint sdn = sd[min(g + nw, ngroups - 1) * 16 + fn];
    bf16x8 f0, f1, f2, f3;
    uint2 pe;
    {
        const int di = (int)(sdc >> 16), si = (int)(sdc & 0xffffu);
        f0 = *(const bf16x8*)&hb[(size_t)di * D + quad * 8];
        f1 = *(const bf16x8*)&hb[(size_t)di * D + 32 + quad * 8];
        f2 = *(const bf16x8*)&hb[(size_t)si * D + quad * 8];
        f3 = *(const bf16x8*)&hb[(size_t)si * D + 32 + quad * 8];
        pe = eab[gc0 * 16 + fn];
    }

    float ps[4] = {0, 0, 0, 0}, pq[4] = {0, 0, 0, 0};

    for (; g < ngroups; g += nw) {
        // in-loop LDS clobber: forces Bf to stay in VGPRs (no LDS re-reads)
        ((ushort*)wst)[lane] = (ushort)g;

        const int gn = g + nw;
        const int gnc = min(gn, ngroups - 1);
        // prefetch next group's fragments (overlaps MFMA below)
        bf16x8 n0, n1, n2, n3;
        uint2 pen;
        {
            const int di = (int)(sdn >> 16), si = (int)(sdn & 0xffffu);
            n0 = *(const bf16x8*)&hb[(size_t)di * D + quad * 8];
            n1 = *(const bf16x8*)&hb[(size_t)di * D + 32 + quad * 8];
            n2 = *(const bf16x8*)&hb[(size_t)si * D + quad * 8];
            n3 = *(const bf16x8*)&hb[(size_t)si * D + 32 + quad * 8];
            pen = eab[gnc * 16 + fn];
        }
        const uint sdn2 = sd[min(gn + nw, ngroups - 1) * 16 + fn];

        // ea fragment: k=128..135 live on quad 0 only (rest zero-padded)
        uint4 a4u;
        a4u.x = (quad == 0) ? pe.x : 0u;
        a4u.y = (quad == 0) ? pe.y : 0u;
        a4u.z = 0u; a4u.w = 0u;
        const bf16x8 a4 = __builtin_bit_cast(bf16x8, a4u);

        f32x4 acc[4];
#pragma unroll
        for (int c = 0; c < 4; ++c) acc[c] = (f32x4){bj[c], bj[c], bj[c], bj[c]};
#pragma unroll
        for (int c = 0; c < 4; ++c) acc[c] = __builtin_amdgcn_mfma_f32_16x16x32_bf16(f0, Bf[0][c], acc[c], 0, 0, 0);
#pragma unroll
        for (int c = 0; c < 4; ++c) acc[c] = __builtin_amdgcn_mfma_f32_16x16x32_bf16(f1, Bf[1][c], acc[c], 0, 0, 0);
#pragma unroll
        for (int c = 0; c < 4; ++c) acc[c] = __builtin_amdgcn_mfma_f32_16x16x32_bf16(f2, Bf[2][c], acc[c], 0, 0, 0);
#pragma unroll
        for (int c = 0; c < 4; ++c) acc[c] = __builtin_amdgcn_mfma_f32_16x16x32_bf16(f3, Bf[3][c], acc[c], 0, 0, 0);
#pragma unroll
        for (int c = 0; c < 4; ++c) acc[c] = __builtin_amdgcn_mfma_f32_16x16x32_bf16(a4, Bf[4][c], acc[c], 0, 0, 0);

        const int row0 = g * 16 + quad * 4;
#pragma unroll
        for (int reg = 0; reg < 4; ++reg) {
#pragma unroll
            for (int c = 0; c < 4; ++c) {
                const ushort ub = f2u(acc[c][reg]);
                y[(size_t)(row0 + reg) * D + c * 16 + fn] = ub;
                const float f = u2f(ub);
                ps[c] += f; pq[c] += f * f;
            }
        }
        f0 = n0; f1 = n1; f2 = n2; f3 = n3; pe = pen; sdn = sdn2;
    }
    __syncthreads();
#pragma unroll
    for (int c = 0; c < 4; ++c) {
        ps[c] += __shfl_xor(ps[c], 16, 64); ps[c] += __shfl_xor(ps[c], 32, 64);
        pq[c] += __shfl_xor(pq[c], 16, 64); pq[c] += __shfl_xor(pq[c], 32, 64);
    }
    if (quad == 0) {
#pragma unroll
        for (int c = 0; c < 4; ++c) {
            sred[w][0][c * 16 + fn] = ps[c];
            sred[w][1][c * 16 + fn] = pq[c];
        }
    }
    __syncthreads();
    if (tid < 128) {
        const int col = tid & 63, which = tid >> 6;
        const float s = sred[0][which][col] + sred[1][which][col] +
                        sred[2][which][col] + sred[3][which][col];
        atomicAdd(&st[which * 64 + col], s);
    }
}

// ---------------------------------------------------------------------------
// yout = relu(BN(yin)) @ W + b — barrier-free per-wave MFMA (in-place safe).
// wst stride 68 (non-pow2) to break bank-aligned fragment re-reads.
// ---------------------------------------------------------------------------
__global__ __launch_bounds__(256, 4) void k_mlp2b(
    const ushort* __restrict__ yin, ushort* __restrict__ yout,
    const float* __restrict__ W, const float* __restrict__ b,
    const float* __restrict__ gg, const float* __restrict__ be,
    const float* __restrict__ st_in, float* __restrict__ st_out,
    const int nrows, const float inv_rows)
{
    __shared__ __align__(16) ushort wst[64][68];
    __shared__ float sal[64], sbe[64];
    __shared__ float sred[4][2][64];
    const int tid = threadIdx.x;
    const int lane = tid & 63, w = tid >> 6;
    const int fn = lane & 15, quad = lane >> 4;

    if (tid < 64) {
        const float m = st_in[tid] * inv_rows;
        const float v = st_in[64 + tid] * inv_rows - m * m;
        const float a = rsqrtf(v + EPSB) * gg[tid];
        sal[tid] = a;
        sbe[tid] = be[tid] - m * a;
    }
    for (int i = tid; i < D * D; i += 256) {
        const int k = i >> 6, n = i & 63;
        wst[n][k] = f2u(W[i]);
    }
    __syncthreads();

    bf16x8 Bf[2][4];
#pragma unroll
    for (int s = 0; s < 2; ++s)
#pragma unroll
        for (int c = 0; c < 4; ++c)
            Bf[s][c] = *(const bf16x8*)&wst[c * 16 + fn][s * 32 + quad * 8];
    float bj[4];
#pragma unroll
    for (int c = 0; c < 4; ++c) bj[c] = b[c * 16 + fn];
    // per-lane BN coefficients: channel = (i>>3)*32 + quad*8 + (i&7)
    float al[16], bt[16];
#pragma unroll
    for (int i = 0; i < 16; ++i) {
        const int ch = (i >> 3) * 32 + quad * 8 + (i & 7);
        al[i] = sal[ch]; bt[i] = sbe[ch];
    }
    __syncthreads();

    const int ngroups = nrows / 16;        // NE/16=31250, NN/16=3125: exact
    const int nw = gridDim.x * 4;
    int g = blockIdx.x * 4 + w;

    size_t base = ((size_t)(min(g, ngroups - 1) * 16 + fn)) * D + quad * 8;
    uint4 u0 = *(const uint4*)&yin[base];
    uint4 u1 = *(const uint4*)&yin[base + 32];

    float ps[4] = {0, 0, 0, 0}, pq[4] = {0, 0, 0, 0};

    for (; g < ngroups; g += nw) {
        ((ushort*)wst)[lane] = (ushort)g;   // force Bf register residency

        const int gn = g + nw;
        const size_t nbase = ((size_t)(min(gn, ngroups - 1) * 16 + fn)) * D + quad * 8;
        const uint4 v0 = *(const uint4*)&yin[nbase];
        const uint4 v1 = *(const uint4*)&yin[nbase + 32];

        uint4 p0, p1;
        p0.x = bnpack(u0.x, al[0], bt[0], al[1], bt[1]);
        p0.y = bnpack(u0.y, al[2], bt[2], al[3], bt[3]);
        p0.z = bnpack(u0.z, al[4], bt[4], al[5], bt[5]);
        p0.w = bnpack(u0.w, al[6], bt[6], al[7], bt[7]);
        p1.x = bnpack(u1.x, al[8], bt[8], al[9], bt[9]);
        p1.y = bnpack(u1.y, al[10], bt[10], al[11], bt[11]);
        p1.z = bnpack(u1.z, al[12], bt[12], al[13], bt[13]);
        p1.w = bnpack(u1.w, al[14], bt[14], al[15], bt[15]);
        const bf16x8 a0 = __builtin_bit_cast(bf16x8, p0);
        const bf16x8 a1 = __builtin_bit_cast(bf16x8, p1);

        f32x4 acc[4];
#pragma unroll
        for (int c = 0; c < 4; ++c) acc[c] = (f32x4){bj[c], bj[c], bj[c], bj[c]};
#pragma unroll
        for (int c = 0; c < 4; ++c) acc[c] = __builtin_amdgcn_mfma_f32_16x16x32_bf16(a0, Bf[0][c], acc[c], 0, 0, 0);
#pragma unroll
        for (int c = 0; c < 4; ++c) acc[c] = __builtin_amdgcn_mfma_f32_16x16x32_bf16(a1, Bf[1][c], acc[c], 0, 0, 0);

        const int row0 = g * 16 + quad * 4;
#pragma unroll
        for (int reg = 0; reg < 4; ++reg) {
#pragma unroll
            for (int c = 0; c < 4; ++c) {
                const ushort ub = f2u(acc[c][reg]);
                yout[(size_t)(row0 + reg) * D + c * 16 + fn] = ub;
                const float f = u2f(ub);
                ps[c] += f; pq[c] += f * f;
            }
        }
        u0 = v0; u1 = v1;
    }
    __syncthreads();
#pragma unroll
    for (int c = 0; c < 4; ++c) {
        ps[c] += __shfl_xor(ps[c], 16, 64); ps[c] += __shfl_xor(ps[c], 32, 64);
        pq[c] += __shfl_xor(pq[c], 16, 64); pq[c] += __shfl_xor(pq[c], 32, 64);
    }
    if (quad == 0) {
#pragma unroll
        for (int c = 0; c < 4; ++c) {
            sred[w][0][c * 16 + fn] = ps[c];
            sred[w][1][c * 16 + fn] = pq[c];
        }
    }
    __syncthreads();
    if (tid < 128) {
        const int col = tid & 63, which = tid >> 6;
        const float s = sred[0][which][col] + sred[1][which][col] +
                        sred[2][which][col] + sred[3][which][col];
        atomicAdd(&st_out[which * 64 + col], s);
    }
}

// ---------------------------------------------------------------------------
// aggr (fp32, pre-zeroed) += segment sums of relu(BN2(y))
// ---------------------------------------------------------------------------
__global__ __launch_bounds__(256) void k_aggr3(
    const ushort* __restrict__ y, const int* __restrict__ rowstart,
    const uint* __restrict__ sd,
    const float* __restrict__ gg, const float* __restrict__ be,
    const float* __restrict__ st, float* __restrict__ aggr)
{
    __shared__ float ys[64][68];
    __shared__ float sal[D], sbe[D];
    const int tid = threadIdx.x;
    if (tid < D) {
        const float m = st[tid] * (1.f / NE);
        const float v = st[D + tid] * (1.f / NE) - m * m;
        const float a = rsqrtf(v + EPSB) * gg[tid];
        sal[tid] = a;
        sbe[tid] = be[tid] - m * a;
    }
    __syncthreads();

    const int e0 = blockIdx.x << 6;
    const int e1 = min(e0 + 64, NE);

    const int r = tid >> 2, c0 = (tid & 3) << 4;
    const int e = e0 + r;
    if (e < NE) {
        const uint4 u0 = *(const uint4*)&y[(size_t)e * D + c0];
        const uint4 u1 = *(const uint4*)&y[(size_t)e * D + c0 + 8];
#pragma unroll
        for (int p = 0; p < 4; ++p) {
            const uint uu = ((const uint*)&u0)[p];
            const int cc = c0 + 2 * p;
            ys[r][cc]     = fmaxf(fmaf(u2f((ushort)(uu & 0xffffu)), sal[cc], sbe[cc]), 0.f);
            ys[r][cc + 1] = fmaxf(fmaf(u2f((ushort)(uu >> 16)), sal[cc + 1], sbe[cc + 1]), 0.f);
        }
#pragma unroll
        for (int p = 0; p < 4; ++p) {
            const uint uu = ((const uint*)&u1)[p];
            const int cc = c0 + 8 + 2 * p;
            ys[r][cc]     = fmaxf(fmaf(u2f((ushort)(uu & 0xffffu)), sal[cc], sbe[cc]), 0.f);
            ys[r][cc + 1] = fmaxf(fmaf(u2f((ushort)(uu >> 16)), sal[cc + 1], sbe[cc + 1]), 0.f);
        }
    }
    __syncthreads();

    const int lane = tid & 63, w = tid >> 6;
    int n = (int)(sd[e0] >> 16) + w;
    while (n < NN) {
        const int rs = rowstart[n];
        if (rs >= e1) break;
        const int re = rowstart[n + 1];
        const int j0 = max(rs, e0), j1 = min(re, e1);
        if (j1 > j0) {
            float s = 0.f;
            for (int j = j0; j < j1; ++j) s += ys[j - e0][lane];
            atomicAdd(&aggr[(size_t)n * D + lane], s);
        }
        n += 4;
    }
}

// ---------------------------------------------------------------------------
// z = cat(hb, aggr_f32) @ W + b — barrier-free per-wave MFMA
// wst stride 136 (non-pow2).
// ---------------------------------------------------------------------------
__global__ __launch_bounds__(256, 3) void k_upd1(
    const ushort* __restrict__ hb, const float* __restrict__ aggr,
    const float* __restrict__ W, const float* __restrict__ b,
    ushort* __restrict__ z, float* __restrict__ st)
{
    __shared__ __align__(16) ushort wst[64][136];
    __shared__ float sred[4][2][64];
    const int tid = threadIdx.x;
    const int lane = tid & 63, w = tid >> 6;
    const int fn = lane & 15, quad = lane >> 4;

    for (int i = tid; i < KU * D; i += 256) {
        const int k = i >> 6, n = i & 63;
        wst[n][k] = f2u(W[i]);
    }
    __syncthreads();
    bf16x8 Bf[4][4];
#pragma unroll
    for (int s = 0; s < 4; ++s)
#pragma unroll
        for (int c = 0; c < 4; ++c)
            Bf[s][c] = *(const bf16x8*)&wst[c * 16 + fn][s * 32 + quad * 8];
    float bj[4];
#pragma unroll
    for (int c = 0; c < 4; ++c) bj[c] = b[c * 16 + fn];
    __syncthreads();

    const int ngroups = NN / 16;           // 3125, exact
    const int nw = gridDim.x * 4;
    int g = blockIdx.x * 4 + w;

    size_t hbase = ((size_t)(min(g, ngroups - 1) * 16 + fn)) * D + quad * 8;
    bf16x8 h0 = *(const bf16x8*)&hb[hbase];
    bf16x8 h1 = *(const bf16x8*)&hb[hbase + 32];
    float4 q0 = *(const float4*)&aggr[hbase];
    float4 q1 = *(const float4*)&aggr[hbase + 4];
    float4 q2 = *(const float4*)&aggr[hbase + 32];
    float4 q3 = *(const float4*)&aggr[hbase + 36];

    float ps[4] = {0, 0, 0, 0}, pq[4] = {0, 0, 0, 0};

    for (; g < ngroups; g += nw) {
        ((ushort*)wst)[lane] = (ushort)g;   // force Bf register residency

        const int gn = g + nw;
        const size_t nb = ((size_t)(min(gn, ngroups - 1) * 16 + fn)) * D + quad * 8;
        const bf16x8 m0 = *(const bf16x8*)&hb[nb];
        const bf16x8 m1 = *(const bf16x8*)&hb[nb + 32];
        const float4 r0 = *(const float4*)&aggr[nb];
        const float4 r1 = *(const float4*)&aggr[nb + 4];
        const float4 r2 = *(const float4*)&aggr[nb + 32];
        const float4 r3 = *(const float4*)&aggr[nb + 36];

        const bf16x8 a2 = packf8(q0, q1);
        const bf16x8 a3 = packf8(q2, q3);

        f32x4 acc[4];
#pragma unroll
        for (int c = 0; c < 4; ++c) acc[c] = (f32x4){bj[c], bj[c], bj[c], bj[c]};
#pragma unroll
        for (int c = 0; c < 4; ++c) acc[c] = __builtin_amdgcn_mfma_f32_16x16x32_bf16(h0, Bf[0][c], acc[c], 0, 0, 0);
#pragma unroll
        for (int c = 0; c < 4; ++c) acc[c] = __builtin_amdgcn_mfma_f32_16x16x32_bf16(h1, Bf[1][c], acc[c], 0, 0, 0);
#pragma unroll
        for (int c = 0; c < 4; ++c) acc[c] = __builtin_amdgcn_mfma_f32_16x16x32_bf16(a2, Bf[2][c], acc[c], 0, 0, 0);
#pragma unroll
        for (int c = 0; c < 4; ++c) acc[c] = __builtin_amdgcn_mfma_f32_16x16x32_bf16(a3, Bf[3][c], acc[c], 0, 0, 0);

        const int row0 = g * 16 + quad * 4;
#pragma unroll
        for (int reg = 0; reg < 4; ++reg) {
#pragma unroll
            for (int c = 0; c < 4; ++c) {
                const ushort ub = f2u(acc[c][reg]);
                z[(size_t)(row0 + reg) * D + c * 16 + fn] = ub;
                const float f = u2f(ub);
                ps[c] += f; pq[c] += f * f;
            }
        }
        h0 = m0; h1 = m1; q0 = r0; q1 = r1; q2 = r2; q3 = r3;
    }
    __syncthreads();
#pragma unroll
    for (int c = 0; c < 4; ++c) {
        ps[c] += __shfl_xor(ps[c], 16, 64); ps[c] += __shfl_xor(ps[c], 32, 64);
        pq[c] += __shfl_xor(pq[c], 16, 64); pq[c] += __shfl_xor(pq[c], 32, 64);
    }
    if (quad == 0) {
#pragma unroll
        for (int c = 0; c < 4; ++c) {
            sred[w][0][c * 16 + fn] = ps[c];
            sred[w][1][c * 16 + fn] = pq[c];
        }
    }
    __syncthreads();
    if (tid < 128) {
        const int col = tid & 63, which = tid >> 6;
        const float s = sred[0][which][col] + sred[1][which][col] +
                        sred[2][which][col] + sred[3][which][col];
        atomicAdd(&st[which * 64 + col], s);
    }
}

// ---------------------------------------------------------------------------
// h += relu(BN(z)) ; hb = bf16(h)
// ---------------------------------------------------------------------------
__global__ __launch_bounds__(256) void k_upd3(
    const ushort* __restrict__ z, const float* __restrict__ gg, const float* __restrict__ be,
    const float* __restrict__ st, float* __restrict__ h, ushort* __restrict__ hb)
{
    __shared__ float sal[D], sbe[D];
    const int tid = threadIdx.x;
    if (tid < D) {
        const float m = st[tid] * (1.f / NN);
        const float v = st[D + tid] * (1.f / NN) - m * m;
        const float a = rsqrtf(v + EPSB) * gg[tid];
        sal[tid] = a;
        sbe[tid] = be[tid] - m * a;
    }
    __syncthreads();
    const int j = tid & 63;
    const float al = sal[j], bt = sbe[j];
    for (int i = blockIdx.x * 256 + tid; i < NN * D; i += gridDim.x * 256) {
        const float v = h[i] + fmaxf(fmaf(u2f(z[i]), al, bt), 0.f);
        h[i] = v;
        hb[i] = f2u(v);
    }
}

// ---------------------------------------------------------------------------
// node_out = h @ node_w + node_b ; hsum += column sums of h ; copy h to d_out
// ---------------------------------------------------------------------------
__global__ __launch_bounds__(256) void k_nodeout(
    const float* __restrict__ h, const float* __restrict__ nw, const float* __restrict__ nb,
    float* __restrict__ node_out, float* __restrict__ h_out, float* __restrict__ hsum)
{
    __shared__ float hs[64][65];
    __shared__ float snw[D * NOD];
    __shared__ float snb[NOD];
    __shared__ float red[4][D];
    const int tid = threadIdx.x;
    for (int i = tid; i < D * NOD; i += 256) snw[i] = nw[i];
    if (tid < NOD) snb[tid] = nb[tid];
    const int j = tid & 63, g = tid >> 6;
    float cs = 0.f;
    for (int n0 = blockIdx.x * 64; n0 < NN; n0 += gridDim.x * 64) {
        __syncthreads();
        for (int r = g; r < 64; r += 4) {
            const int n = n0 + r;
            float v = 0.f;
            if (n < NN) { v = h[n * D + j]; h_out[n * D + j] = v; }
            hs[r][j] = v;
        }
        __syncthreads();
        for (int r = g; r < 64; r += 4) cs += hs[r][j];
        for (int it = tid; it < 64 * NOD; it += 256) {
            const int r = it / NOD, c = it - r * NOD;
            const int n = n0 + r;
            if (n < NN) {
                float a = snb[c];
#pragma unroll 16
                for (int k = 0; k < D; ++k) a += hs[r][k] * snw[k * NOD + c];
                node_out[n * NOD + c] = a;
            }
        }
    }
    red[g][j] = cs;
    __syncthreads();
    if (tid < D) atomicAdd(&hsum[tid], red[0][tid] + red[1][tid] + red[2][tid] + red[3][tid]);
}

__global__ void k_graphout(const float* __restrict__ hsum, const float* __restrict__ gw,
                           const float* __restrict__ gb, float* __restrict__ out)
{
    const int j = threadIdx.x;  // 64 threads
    float v = hsum[j] * (1.f / NN) * gw[j];
#pragma unroll
    for (int off = 32; off > 0; off >>= 1) v += __shfl_down(v, off, 64);
    if (j == 0) out[0] = v + gb[0];
}

// ---------------------------------------------------------------------------
extern "C" void kernel_launch(void* const* d_in, const int* in_sizes, int n_in,
                              void* d_out, int out_size, void* d_ws, size_t ws_size,
                              hipStream_t stream)
{
    (void)in_sizes; (void)n_in; (void)out_size; (void)ws_size;
    const float* x        = (const float*)d_in[0];
    const int*   ei       = (const int*)  d_in[1];
    const float* ea       = (const float*)d_in[2];
    const float* prev_h   = (const float*)d_in[3];
    const float* lin_in_w = (const float*)d_in[4];
    const float* lin_in_b = (const float*)d_in[5];
    const float* hist_w   = (const float*)d_in[6];
    const float* hist_b   = (const float*)d_in[7];
    const float* msg_w1   = (const float*)d_in[8];
    const float* msg_b1   = (const float*)d_in[9];
    const float* msg_g1   = (const float*)d_in[10];
    const float* msg_be1  = (const float*)d_in[11];
    const float* msg_w2   = (const float*)d_in[12];
    const float* msg_b2   = (const float*)d_in[13];
    const float* msg_g2   = (const float*)d_in[14];
    const float* msg_be2  = (const float*)d_in[15];
    const float* upd_w1   = (const float*)d_in[16];
    const float* upd_b1   = (const float*)d_in[17];
    const float* upd_g1   = (const float*)d_in[18];
    const float* upd_be1  = (const float*)d_in[19];
    const float* upd_w2   = (const float*)d_in[20];
    const float* upd_b2   = (const float*)d_in[21];
    const float* upd_g2   = (const float*)d_in[22];
    const float* upd_be2  = (const float*)d_in[23];
    const float* graph_w  = (const float*)d_in[24];
    const float* graph_b  = (const float*)d_in[25];
    const float* node_w   = (const float*)d_in[26];
    const float* node_b   = (const float*)d_in[27];

    const int* src = ei;        // edge_index[0]
    const int* dst = ei + NE;   // edge_index[1]

    float* out       = (float*)d_out;
    float* graph_out = out;                  // [1]
    float* node_out  = out + 1;              // [N*NO]
    float* h_out     = out + 1 + NN * NOD;   // [N*D]

    char* ws = (char*)d_ws;
    size_t off = 0;
    ushort* y     = (ushort*)(ws + off); off += (size_t)NE * D * sizeof(ushort);  // 64 MB
    ushort* z     = y;   // aliases y (disjoint lifetime)
    float*  aggr  = (float*) (ws + off); off += (size_t)NN * D * sizeof(float);   // 12.8 MB
    float*  h     = (float*) (ws + off); off += (size_t)NN * D * sizeof(float);   // 12.8 MB
    ushort* hb    = (ushort*)(ws + off); off += (size_t)NN * D * sizeof(ushort);  // 6.4 MB
    uint*   sd    = (uint*)  (ws + off); off += (size_t)NE * sizeof(uint);        // 2 MB
    uint2*  eab   = (uint2*) (ws + off); off += (size_t)NE * sizeof(uint2);       // 4 MB
    int* rowstart = (int*)   (ws + off); off += (size_t)(NN + 1) * sizeof(int);
    int* cnt      = (int*)   (ws + off); off += (size_t)NN * sizeof(int);
    int* bsum     = (int*)   (ws + off); off += (size_t)256 * sizeof(int);
    float* stats  = (float*) (ws + off); off += (size_t)(NL * 4 * 2 * D) * sizeof(float);
    float* hsum   = (float*) (ws + off); off += (size_t)D * sizeof(float);
    int* cursor   = cnt;

    hipMemsetAsync(cnt, 0, (size_t)NN * sizeof(int), stream);
    hipMemsetAsync(stats, 0, (size_t)(NL * 4 * 2 * D + D) * sizeof(float), stream);

    k_hist<<<(NE + 255) / 256, 256, 0, stream>>>(dst, cnt);
    k_scan1<<<NBLK1, 256, 0, stream>>>(cnt, rowstart, bsum);
    k_scan2<<<1, 256, 0, stream>>>(bsum);
    k_scan3<<<NBLK1, 256, 0, stream>>>(rowstart, bsum, cursor);
    k_scatter<<<(NE + 255) / 256, 256, 0, stream>>>(src, dst, ea, cursor, sd, eab);

    k_input<<<(NN + 3) / 4, 256, 0, stream>>>(x, prev_h, lin_in_w, lin_in_b, hist_w, hist_b, h, hb);

    for (int l = 0; l < NL; ++l) {
        float* st_m1 = stats + (l * 4 + 0) * 2 * D;
        float* st_m2 = stats + (l * 4 + 1) * 2 * D;
        float* st_u1 = stats + (l * 4 + 2) * 2 * D;
        float* st_u2 = stats + (l * 4 + 3) * 2 * D;
        k_msg1<<<768, 256, 0, stream>>>(hb, sd, eab,
                                        msg_w1 + (size_t)l * K1 * D, msg_b1 + l * D, y, st_m1);
        k_mlp2b<<<1024, 256, 0, stream>>>(y, y,
                                          msg_w2 + (size_t)l * D * D, msg_b2 + l * D,
                                          msg_g1 + l * D, msg_be1 + l * D,
                                          st_m1, st_m2, NE, 1.f / NE);
        hipMemsetAsync(aggr, 0, (size_t)NN * D * sizeof(float), stream);
        k_aggr3<<<(NE + 63) / 64, 256, 0, stream>>>(y, rowstart, sd,
                                                    msg_g2 + l * D, msg_be2 + l * D,
                                                    st_m2, aggr);
        k_upd1<<<768, 256, 0, stream>>>(hb, aggr,
                                        upd_w1 + (size_t)l * KU * D, upd_b1 + l * D, z, st_u1);
        k_mlp2b<<<391, 256, 0, stream>>>(z, z,
                                         upd_w2 + (size_t)l * D * D, upd_b2 + l * D,
                                         upd_g1 + l * D, upd_be1 + l * D,
                                         st_u1, st_u2, NN, 1.f / NN);
        k_upd3<<<1024, 256, 0, stream>>>(z, upd_g2 + l * D, upd_be2 + l * D, st_u2, h, hb);
    }

    k_nodeout<<<782, 256, 0, stream>>>(h, node_w, node_b, node_out, h_out, hsum);
    k_graphout<<<1, 64, 0, stream>>>(hsum, graph_w, graph_b, graph_out);
}